// Round 2
// baseline (540.023 us; speedup 1.0000x reference)
//
#include <hip/hip_runtime.h>
#include <hip/hip_bf16.h>
#include <math.h>

// ---------------------------------------------------------------------------
// GAT 3-layer forward on MI355X.
//   1. Dest-CSR via 2-pass bucketed counting sort (coalesced writes).
//      Self-loops are implicit in the aggregation kernels.
//   2. Layers 1-2: split-bf16 MFMA GEMM with alpha_src/dst FUSED into the
//      epilogue; writes bf16 C only. R10: whole-K-panel staging with a
//      SINGLE barrier + barrier-free fully-unrolled MFMA phase.
//      Layer 3: f32 vector GEMM (tiny).
//   3. R11: TWO-PASS aggregation. Pass 1 walks cols/asrc only (~40 B/edge)
//      computing exact per-head (m, 1/s) via the online recurrence. Pass 2
//      then has loop-invariant m/rs -> every 16-edge chunk is independent
//      (w = exp(v-m), no chunk-max shfl, no accumulator rescale, no serial
//      state) so all 16 feature gathers (256 B each) pipeline deeply.
//      R10's single-pass online version kept the 410 MB of feature gathers
//      stuck behind a ~2000-cycle serial chain per 8-edge chunk (43% HBM,
//      57% VALU, nothing saturated).
// ---------------------------------------------------------------------------

#define LEAKY(v) ((v) > 0.f ? (v) : 0.2f * (v))

typedef __bf16 bf16_t;
typedef __bf16 bf16x8 __attribute__((ext_vector_type(8)));
typedef __bf16 bf16x4 __attribute__((ext_vector_type(4)));
typedef float f32x4 __attribute__((ext_vector_type(4)));
typedef unsigned short u16x8 __attribute__((ext_vector_type(8)));

static __device__ __forceinline__ unsigned short bf_bits(float f) {
    bf16_t b = (bf16_t)f;
    return __builtin_bit_cast(unsigned short, b);
}
static __device__ __forceinline__ float bf_to_f(unsigned short u) {
    return __uint_as_float(((unsigned int)u) << 16);
}
static __device__ __forceinline__ float bperm_f(int byteaddr, float v) {
    return __uint_as_float((unsigned)__builtin_amdgcn_ds_bpermute(byteaddr, (int)__float_as_uint(v)));
}

// ---------------- CSR build: 2-pass bucket sort ----------------
constexpr int NB_MAX = 400;
constexpr int BCAP = 5120;  // capacity per bucket region; mean load 4096

__global__ void zero_k(int* a, int n) {
    int i = blockIdx.x * blockDim.x + threadIdx.x;
    if (i < n) a[i] = 0;
}

// Pass 1: partition edges into bucket regions with block-local grouping.
__global__ __launch_bounds__(256) void partition_k(
        const int* __restrict__ src, const int* __restrict__ dst, int E, int NB,
        int* __restrict__ bcur, unsigned* __restrict__ staged) {
    __shared__ int hist[NB_MAX];
    __shared__ int bstart[NB_MAX + 1];
    __shared__ int cur[NB_MAX];
    __shared__ int gbase[NB_MAX];
    __shared__ unsigned words[4096];
    __shared__ unsigned short bidl[4096];
    int tid = threadIdx.x;
    int e0 = blockIdx.x * 4096;
    int cnt = E - e0; if (cnt > 4096) cnt = 4096;
    if (cnt <= 0) return;

    for (int b = tid; b < NB; b += 256) hist[b] = 0;
    __syncthreads();
    for (int i = tid; i < cnt; i += 256) atomicAdd(&hist[dst[e0 + i] >> 8], 1);
    __syncthreads();
    if (tid == 0) {
        int run = 0;
        for (int b = 0; b < NB; b++) { bstart[b] = run; run += hist[b]; }
        bstart[NB] = run;
    }
    __syncthreads();
    for (int b = tid; b < NB; b += 256) {
        cur[b] = bstart[b];
        gbase[b] = hist[b] ? atomicAdd(&bcur[b], hist[b]) : 0;
    }
    __syncthreads();
    // group into LDS by bucket, remember bucket id per slot
    for (int i = tid; i < cnt; i += 256) {
        int s = src[e0 + i], d = dst[e0 + i];
        int b = d >> 8;
        unsigned w = (unsigned)s | ((unsigned)(d & 255) << 17);
        int p = atomicAdd(&cur[b], 1);
        words[p] = w;
        bidl[p] = (unsigned short)b;
    }
    __syncthreads();
    // linear sweep -> coalesced runs into global bucket regions
    for (int i = tid; i < cnt; i += 256) {
        int b = bidl[i];
        staged[(size_t)b * BCAP + gbase[b] + (i - bstart[b])] = words[i];
    }
}

// tiny exclusive scan over NB bucket counts (one wave)
__global__ void scan_nb_k(const int* __restrict__ bcur, int* __restrict__ ebase, int NB) {
    int lane = threadIdx.x;  // 64 threads
    int CH = (NB + 63) / 64;
    int b0 = lane * CH;
    int v[8]; int s = 0;
#pragma unroll 8
    for (int k = 0; k < CH; k++) { int b = b0 + k; int t = (b < NB) ? bcur[b] : 0; if (k < 8) v[k] = t; s += t; }
    int orig = s;
    for (int off = 1; off < 64; off <<= 1) {
        int t = __shfl_up(s, off, 64);
        if (lane >= off) s += t;
    }
    int run = s - orig;  // exclusive
    for (int k = 0; k < CH; k++) { int b = b0 + k; if (b < NB) { ebase[b] = run; run += v[k]; } }
    if (lane == 63) ebase[NB] = run;
}

// Pass 2: per-bucket node-level counting sort -> offs + cols (coalesced writes).
__global__ __launch_bounds__(256) void buildcsr_k(
        const unsigned* __restrict__ staged, const int* __restrict__ bcur,
        const int* __restrict__ ebase, int* __restrict__ offs, int* __restrict__ cols,
        int N, int NB) {
    __shared__ int h[256], hs[256], curl[256];
    __shared__ int colsl[BCAP];
    int b = blockIdx.x, tid = threadIdx.x;
    int n0 = b << 8;
    int ecnt = bcur[b];
    int base_g = ebase[b];
    const unsigned* sb = staged + (size_t)b * BCAP;

    h[tid] = 0;
    __syncthreads();
    for (int i = tid; i < ecnt; i += 256) atomicAdd(&h[sb[i] >> 17], 1);
    __syncthreads();
    int val = h[tid];
    hs[tid] = val; __syncthreads();
    for (int off = 1; off < 256; off <<= 1) {
        int t = (tid >= off) ? hs[tid - off] : 0;
        __syncthreads();
        hs[tid] += t;
        __syncthreads();
    }
    int excl = hs[tid] - val;
    curl[tid] = excl;
    if (n0 + tid < N) offs[n0 + tid] = base_g + excl;
    if (b == NB - 1 && tid == 0) offs[N] = base_g + ecnt;
    __syncthreads();
    for (int i = tid; i < ecnt; i += 256) {
        unsigned w = sb[i];
        int p = atomicAdd(&curl[w >> 17], 1);
        colsl[p] = (int)(w & 0x1FFFFu);
    }
    __syncthreads();
    for (int i = tid; i < ecnt; i += 256) cols[base_g + i] = colsl[i];
}

// ---------------- W pre-pack into MFMA B-fragment order (hi|lo) ----------------
__global__ void prep_w_k(const float* __restrict__ W, short* __restrict__ Bfs,
                         int K, int N, int NT, int total) {
    int idx = blockIdx.x * blockDim.x + threadIdx.x;
    if (idx >= total) return;  // total = (K/32)*NT*64
    int lane = idx & 63;
    int t = idx >> 6;
    int ntile = t % NT, kstep = t / NT;
    int quad = lane >> 4, nl = lane & 15;
    int n = ntile * 16 + nl;
    bf16_t* dst = (bf16_t*)Bfs + (size_t)idx * 16;
#pragma unroll
    for (int j = 0; j < 8; j++) {
        int k = kstep * 32 + quad * 8 + j;
        float v = W[k * N + n];
        bf16_t h = (bf16_t)v;
        bf16_t l = (bf16_t)(v - (float)h);
        dst[j] = h;
        dst[8 + j] = l;
    }
}

// ---------------- split-bf16 MFMA GEMM, fused alpha epilogue ----------------
// R10 structure: stage the FULL BM x K panel (split hi/lo for f32 A) with
// 16 independent 16B loads per thread -> one __syncthreads -> barrier-free
// fully-unrolled MFMA phase. NWM=1: waves own disjoint B tiles.
// Writes Cb (bf16) + alpha_src/alpha_dst [M, N/CHEAD] (f32, exact from acc).
template <int BM, int WMT, int WNT, int NWM, bool ABF16, int CHEAD, int K>
__global__ __launch_bounds__(256, 2) void mfma_gemm_k(
        const void* __restrict__ Av, const short* __restrict__ Bfs,
        unsigned short* __restrict__ Cb,
        const float* __restrict__ a_s, const float* __restrict__ a_d,
        float* __restrict__ out_as, float* __restrict__ out_ad,
        int M, int N, int NT) {
    constexpr int NWN = 4 / NWM;
    constexpr int BN = 16 * WNT * NWN;
    constexpr int KP = K + 8;  // +8 bf16: keeps b128 reads at free 2-way banks
    __shared__ __align__(16) bf16_t As_hi[BM * KP];
    __shared__ __align__(16) bf16_t As_lo[ABF16 ? 16 : BM * KP];
    const bf16_t* Bf = (const bf16_t*)Bfs;

    int tid = threadIdx.x;
    int wave = tid >> 6, lane = tid & 63;
    int quad = lane >> 4, l16 = lane & 15;
    int wm = wave % NWM, wn = wave / NWM;
    int row0 = blockIdx.x * BM;
    int ntile0 = blockIdx.y * (BN / 16) + wn * WNT;

    // ---- stage whole panel: all loads issued before any conversion ----
    if constexpr (!ABF16) {
        constexpr int CHUNKS = BM * K * 4 / (16 * 256);  // 16B chunks per thread
        const float* A = (const float*)Av;
        f32x4 tmp[CHUNKS];
#pragma unroll
        for (int c = 0; c < CHUNKS; c++) {
            int ci = c * 256 + tid;
            int fi = ci * 4;
            int row = fi / K, k = fi % K;
            int grow = row0 + row;
            tmp[c] = (f32x4){0.f, 0.f, 0.f, 0.f};
            if (grow < M) tmp[c] = *(const f32x4*)(A + (size_t)grow * K + k);
        }
#pragma unroll
        for (int c = 0; c < CHUNKS; c++) {
            int ci = c * 256 + tid;
            int fi = ci * 4;
            int row = fi / K, k = fi % K;
            bf16x4 h, l;
#pragma unroll
            for (int j = 0; j < 4; j++) {
                bf16_t hh = (bf16_t)tmp[c][j];
                h[j] = hh;
                l[j] = (bf16_t)(tmp[c][j] - (float)hh);
            }
            *(bf16x4*)&As_hi[row * KP + k] = h;
            *(bf16x4*)&As_lo[row * KP + k] = l;
        }
    } else {
        constexpr int CHUNKS = BM * K * 2 / (16 * 256);
        const unsigned short* A = (const unsigned short*)Av;
        u16x8 tmp[CHUNKS];
#pragma unroll
        for (int c = 0; c < CHUNKS; c++) {
            int ci = c * 256 + tid;
            int ei = ci * 8;
            int row = ei / K, k = ei % K;
            int grow = row0 + row;
            tmp[c] = (u16x8){0, 0, 0, 0, 0, 0, 0, 0};
            if (grow < M) tmp[c] = *(const u16x8*)(A + (size_t)grow * K + k);
        }
#pragma unroll
        for (int c = 0; c < CHUNKS; c++) {
            int ci = c * 256 + tid;
            int ei = ci * 8;
            int row = ei / K, k = ei % K;
            *(u16x8*)&As_hi[row * KP + k] = tmp[c];
        }
    }
    __syncthreads();

    // ---- barrier-free compute over all K steps ----
    f32x4 acc[WMT][WNT];
#pragma unroll
    for (int i = 0; i < WMT; i++)
#pragma unroll
        for (int j = 0; j < WNT; j++) acc[i][j] = (f32x4){0.f, 0.f, 0.f, 0.f};

#pragma unroll
    for (int ks = 0; ks < K / 32; ks++) {
        bf16x8 ah[WMT], al[WMT];
#pragma unroll
        for (int i = 0; i < WMT; i++) {
            int rowl = wm * (WMT * 16) + i * 16 + l16;
            ah[i] = *(const bf16x8*)&As_hi[rowl * KP + ks * 32 + quad * 8];
            if (!ABF16) al[i] = *(const bf16x8*)&As_lo[rowl * KP + ks * 32 + quad * 8];
        }
        bf16x8 bh[WNT], bl[WNT];
#pragma unroll
        for (int j = 0; j < WNT; j++) {
            size_t base = ((size_t)(ks * NT + ntile0 + j) * 64 + lane) * 16;
            bh[j] = *(const bf16x8*)&Bf[base];
            bl[j] = *(const bf16x8*)&Bf[base + 8];
        }
#pragma unroll
        for (int i = 0; i < WMT; i++)
#pragma unroll
            for (int j = 0; j < WNT; j++) {
                acc[i][j] = __builtin_amdgcn_mfma_f32_16x16x32_bf16(ah[i], bh[j], acc[i][j], 0, 0, 0);
                if (!ABF16)
                    acc[i][j] = __builtin_amdgcn_mfma_f32_16x16x32_bf16(al[i], bh[j], acc[i][j], 0, 0, 0);
                acc[i][j] = __builtin_amdgcn_mfma_f32_16x16x32_bf16(ah[i], bl[j], acc[i][j], 0, 0, 0);
            }
    }

    // bf16 C store: D[row = quad*4 + r][col = l16] per 16x16 tile
#pragma unroll
    for (int i = 0; i < WMT; i++) {
        int rbase = row0 + wm * (WMT * 16) + i * 16 + quad * 4;
#pragma unroll
        for (int j = 0; j < WNT; j++) {
            int gcol = (ntile0 + j) * 16 + l16;
#pragma unroll
            for (int r2 = 0; r2 < 4; r2++) {
                int grow = rbase + r2;
                if (grow < M) Cb[(size_t)grow * N + gcol] = bf_bits(acc[i][j][r2]);
            }
        }
    }

    // fused alpha: per tile j, coef = a_flat[gcol]; reduce over CHEAD-lane groups
    const int Hh = N / CHEAD;
#pragma unroll
    for (int j = 0; j < WNT; j++) {
        int gcol = (ntile0 + j) * 16 + l16;
        float cs = a_s[gcol], cd = a_d[gcol];
#pragma unroll
        for (int i = 0; i < WMT; i++) {
            float ps[4], pd[4];
#pragma unroll
            for (int r2 = 0; r2 < 4; r2++) {
                ps[r2] = acc[i][j][r2] * cs;
                pd[r2] = acc[i][j][r2] * cd;
            }
#pragma unroll
            for (int off = 1; off < CHEAD; off <<= 1) {
#pragma unroll
                for (int r2 = 0; r2 < 4; r2++) {
                    ps[r2] += __shfl_xor(ps[r2], off, 64);
                    pd[r2] += __shfl_xor(pd[r2], off, 64);
                }
            }
            if ((l16 & (CHEAD - 1)) == 0) {
                int hd = gcol / CHEAD;
                int rb = row0 + wm * (WMT * 16) + i * 16 + quad * 4;
#pragma unroll
                for (int r2 = 0; r2 < 4; r2++) {
                    int grow = rb + r2;
                    if (grow < M) {
                        out_as[(size_t)grow * Hh + hd] = ps[r2];
                        out_ad[(size_t)grow * Hh + hd] = pd[r2];
                    }
                }
            }
        }
    }
}

// ---------------- GEMM (f32 vector, bf16 A) — layer 3 only ----------------
template <int BM, int BN, int BK, int TM, int TN>
__global__ void gemm_k(const unsigned short* __restrict__ Ab, const float* __restrict__ B,
                       float* __restrict__ C, unsigned short* __restrict__ Cb,
                       int M, int Nc, int K) {
    __shared__ float As[BK][BM + 1];
    __shared__ float Bs[BK][BN + 1];
    int tx = threadIdx.x, ty = threadIdx.y;
    int tid = ty * blockDim.x + tx;
    const int nthreads = (BM / TM) * (BN / TN);
    int row0 = blockIdx.x * BM, col0 = blockIdx.y * BN;
    float acc[TM][TN];
#pragma unroll
    for (int i = 0; i < TM; i++)
#pragma unroll
        for (int j = 0; j < TN; j++) acc[i][j] = 0.f;

    for (int k0 = 0; k0 < K; k0 += BK) {
        for (int i = tid; i < BM * BK; i += nthreads) {
            int r = i / BK, kk = i % BK;
            int gr = row0 + r;
            As[kk][r] = (gr < M) ? bf_to_f(Ab[(size_t)gr * K + (k0 + kk)]) : 0.f;
        }
        for (int i = tid; i < BK * BN; i += nthreads) {
            int kk = i / BN, c = i % BN;
            int gc = col0 + c;
            Bs[kk][c] = (gc < Nc) ? B[(long)(k0 + kk) * Nc + gc] : 0.f;
        }
        __syncthreads();
#pragma unroll
        for (int kk = 0; kk < BK; ++kk) {
            float a[TM], b[TN];
#pragma unroll
            for (int i = 0; i < TM; i++) a[i] = As[kk][ty * TM + i];
#pragma unroll
            for (int j = 0; j < TN; j++) b[j] = Bs[kk][tx * TN + j];
#pragma unroll
            for (int i = 0; i < TM; i++)
#pragma unroll
                for (int j = 0; j < TN; j++) acc[i][j] = fmaf(a[i], b[j], acc[i][j]);
        }
        __syncthreads();
    }
#pragma unroll
    for (int i = 0; i < TM; i++) {
        int gr = row0 + ty * TM + i;
        if (gr >= M) continue;
#pragma unroll
        for (int j = 0; j < TN; j++) {
            int gc = col0 + tx * TN + j;
            if (gc < Nc) {
                C[(long)gr * Nc + gc] = acc[i][j];
                Cb[(long)gr * Nc + gc] = bf_bits(acc[i][j]);
            }
        }
    }
}

// ---------------- alpha (layer 3 only) ----------------
template <int H, int C>
__global__ void alpha_k(const float* __restrict__ xp, const float* __restrict__ a_s,
                        const float* __restrict__ a_d, float* __restrict__ out_s,
                        float* __restrict__ out_d, int NH) {
    int i = blockIdx.x * blockDim.x + threadIdx.x;
    if (i >= NH) return;
    int h = i % H;
    const float* v = xp + (long)i * C;
    float ss = 0.f, sd = 0.f;
#pragma unroll
    for (int c = 0; c < C; c++) {
        float x = v[c];
        ss = fmaf(x, a_s[h * C + c], ss);
        sd = fmaf(x, a_d[h * C + c], sd);
    }
    out_s[i] = ss;
    out_d[i] = sd;
}

// ---------------- two-pass aggregation, H=8 C=16 (layer 1) ----------------
// Pass 1: per-head (m, 1/s) from cols/asrc only. Pass 2: m/rs loop-invariant
// -> independent 16-edge chunks, 16 feature gathers in flight.
template <bool DO_ELU>
__global__ void agg16_k(const unsigned short* __restrict__ xpb,
                        const float* __restrict__ asrc, const float* __restrict__ adst,
                        const int* __restrict__ offs, const int* __restrict__ cols,
                        const float* __restrict__ bias, unsigned short* __restrict__ outb,
                        int N) {
    int gtid = blockIdx.x * blockDim.x + threadIdx.x;
    int n = gtid >> 6;
    if (n >= N) return;
    int lane = threadIdx.x & 63;
    int j = lane >> 3, h = lane & 7;
    const int jb = j << 2;  // bpermute byte addr of (j=0, h=j) lane
    int start = offs[n], end = offs[n + 1];
    const unsigned* xp32 = (const unsigned*)xpb;

    float ad_l = adst[n * 8 + h];
    float vs = asrc[n * 8 + h] + ad_l;
    vs = LEAKY(vs);

    // ---- pass 1: weights only (seeded with implicit self-loop) ----
    float m_w = vs;
    float s = (j == 0) ? 1.f : 0.f;
    for (int c0 = start; c0 < end; c0 += 16) {
        int e0 = c0 + j, e1 = c0 + 8 + j;
        bool ok0 = e0 < end, ok1 = e1 < end;
        int s0 = ok0 ? cols[e0] : 0;
        int s1 = ok1 ? cols[e1] : 0;
        float v0 = -1e30f, v1 = -1e30f;
        if (ok0) { v0 = asrc[s0 * 8 + h] + ad_l; v0 = LEAKY(v0); }
        if (ok1) { v1 = asrc[s1 * 8 + h] + ad_l; v1 = LEAKY(v1); }
        float cm = fmaxf(v0, v1);
        cm = fmaxf(cm, __shfl_xor(cm, 8, 64));
        cm = fmaxf(cm, __shfl_xor(cm, 16, 64));
        cm = fmaxf(cm, __shfl_xor(cm, 32, 64));
        float mw_new = fmaxf(m_w, cm);
        s = s * __expf(m_w - mw_new) + __expf(v0 - mw_new) + __expf(v1 - mw_new);
        m_w = mw_new;
    }
    s += __shfl_xor(s, 8, 64);
    s += __shfl_xor(s, 16, 64);
    s += __shfl_xor(s, 32, 64);
    float rs = 1.f / (s + 1e-16f);

    // feature-role (head j) constants
    float mF = bperm_f(jb, m_w);
    float rsF = bperm_f(jb, rs);

    // self contribution: weight exp(vs - m)
    unsigned uself = xp32[(size_t)n * 64 + lane];
    float wsF = __expf(bperm_f(jb, vs) - mF);
    float a0 = wsF * __uint_as_float(uself << 16);
    float a1 = wsF * __uint_as_float(uself & 0xffff0000u);

    // ---- pass 2: independent chunks, all gathers pipeline ----
    for (int c0 = start; c0 < end; c0 += 16) {
        int e0 = c0 + j, e1 = c0 + 8 + j;
        bool ok0 = e0 < end, ok1 = e1 < end;
        int sl0 = ok0 ? cols[e0] : 0;
        int sl1 = ok1 ? cols[e1] : 0;
        float v0 = -1e30f, v1 = -1e30f;
        if (ok0) { v0 = asrc[sl0 * 8 + h] + ad_l; v0 = LEAKY(v0); }
        if (ok1) { v1 = asrc[sl1 * 8 + h] + ad_l; v1 = LEAKY(v1); }
        float w0 = __expf(v0 - m_w);  // 0 for invalid slots
        float w1 = __expf(v1 - m_w);
#pragma unroll
        for (int j2 = 0; j2 < 8; j2++) {
            int srcj = __builtin_amdgcn_readlane(sl0, j2 * 8);
            float w = bperm_f(jb + j2 * 32, w0);
            unsigned u = xp32[(size_t)srcj * 64 + lane];
            a0 = fmaf(w, __uint_as_float(u << 16), a0);
            a1 = fmaf(w, __uint_as_float(u & 0xffff0000u), a1);
        }
#pragma unroll
        for (int j2 = 0; j2 < 8; j2++) {
            int srcj = __builtin_amdgcn_readlane(sl1, j2 * 8);
            float w = bperm_f(jb + j2 * 32, w1);
            unsigned u = xp32[(size_t)srcj * 64 + lane];
            a0 = fmaf(w, __uint_as_float(u << 16), a0);
            a1 = fmaf(w, __uint_as_float(u & 0xffff0000u), a1);
        }
    }
    float o0 = a0 * rsF + bias[2 * lane];
    float o1 = a1 * rsF + bias[2 * lane + 1];
    if (DO_ELU) {
        o0 = o0 > 0.f ? o0 : __expf(o0) - 1.f;
        o1 = o1 > 0.f ? o1 : __expf(o1) - 1.f;
    }
    unsigned packed = (unsigned)bf_bits(o0) | ((unsigned)bf_bits(o1) << 16);
    ((unsigned*)outb)[(size_t)n * 64 + lane] = packed;  // row = 128 shorts = 64 uints
}

// ---------------- two-pass aggregation, H=8 C=8 (layer 2) ----------------
template <bool DO_ELU>
__global__ void agg8c8_k(const unsigned short* __restrict__ xpb,
                         const float* __restrict__ asrc, const float* __restrict__ adst,
                         const int* __restrict__ offs, const int* __restrict__ cols,
                         const float* __restrict__ bias, unsigned short* __restrict__ outb,
                         int N) {
    int gtid = blockIdx.x * blockDim.x + threadIdx.x;
    int n = gtid >> 6;
    if (n >= N) return;
    int lane = threadIdx.x & 63;
    int j = lane >> 3, h = lane & 7;
    int start = offs[n], end = offs[n + 1];
    const unsigned* xp32 = (const unsigned*)xpb;

    int fp = lane & 31;      // feature pair {2fp, 2fp+1}
    int hF = fp >> 2;        // feature-role head
    int half = lane >> 5;
    int sbase = half * 32;

    float ad_l = adst[n * 8 + h];
    float vs = asrc[n * 8 + h] + ad_l;
    vs = LEAKY(vs);

    // ---- pass 1: weights only ----
    float m_w = vs;
    float s = (j == 0) ? 1.f : 0.f;
    for (int c0 = start; c0 < end; c0 += 16) {
        int e0 = c0 + j, e1 = c0 + 8 + j;
        bool ok0 = e0 < end, ok1 = e1 < end;
        int s0 = ok0 ? cols[e0] : 0;
        int s1 = ok1 ? cols[e1] : 0;
        float v0 = -1e30f, v1 = -1e30f;
        if (ok0) { v0 = asrc[s0 * 8 + h] + ad_l; v0 = LEAKY(v0); }
        if (ok1) { v1 = asrc[s1 * 8 + h] + ad_l; v1 = LEAKY(v1); }
        float cm = fmaxf(v0, v1);
        cm = fmaxf(cm, __shfl_xor(cm, 8, 64));
        cm = fmaxf(cm, __shfl_xor(cm, 16, 64));
        cm = fmaxf(cm, __shfl_xor(cm, 32, 64));
        float mw_new = fmaxf(m_w, cm);
        s = s * __expf(m_w - mw_new) + __expf(v0 - mw_new) + __expf(v1 - mw_new);
        m_w = mw_new;
    }
    s += __shfl_xor(s, 8, 64);
    s += __shfl_xor(s, 16, 64);
    s += __shfl_xor(s, 32, 64);
    float rs = 1.f / (s + 1e-16f);

    float mF = bperm_f(hF * 4, m_w);
    float rsF = bperm_f(hF * 4, rs);

    float a0 = 0.f, a1 = 0.f;
    if (half == 0) {  // self contribution in half 0 only
        float wsF = __expf(bperm_f(hF * 4, vs) - mF);
        unsigned u = xp32[(size_t)n * 32 + fp];
        a0 = wsF * __uint_as_float(u << 16);
        a1 = wsF * __uint_as_float(u & 0xffff0000u);
    }

    // ---- pass 2: independent chunks ----
    for (int c0 = start; c0 < end; c0 += 16) {
        int e0 = c0 + j, e1 = c0 + 8 + j;
        bool ok0 = e0 < end, ok1 = e1 < end;
        int sl0 = ok0 ? cols[e0] : 0;
        int sl1 = ok1 ? cols[e1] : 0;
        float v0 = -1e30f, v1 = -1e30f;
        if (ok0) { v0 = asrc[sl0 * 8 + h] + ad_l; v0 = LEAKY(v0); }
        if (ok1) { v1 = asrc[sl1 * 8 + h] + ad_l; v1 = LEAKY(v1); }
        float w0 = __expf(v0 - m_w);
        float w1 = __expf(v1 - m_w);
        // 4 pairs x 2 halves = 8 edges per group; invalid -> w=0
#pragma unroll
        for (int j2 = 0; j2 < 4; j2++) {
            int srcv = __builtin_amdgcn_ds_bpermute(sbase + j2 * 64, sl0);
            float w = bperm_f(sbase + hF * 4 + j2 * 64, w0);
            unsigned u = xp32[(size_t)srcv * 32 + fp];
            a0 = fmaf(w, __uint_as_float(u << 16), a0);
            a1 = fmaf(w, __uint_as_float(u & 0xffff0000u), a1);
        }
#pragma unroll
        for (int j2 = 0; j2 < 4; j2++) {
            int srcv = __builtin_amdgcn_ds_bpermute(sbase + j2 * 64, sl1);
            float w = bperm_f(sbase + hF * 4 + j2 * 64, w1);
            unsigned u = xp32[(size_t)srcv * 32 + fp];
            a0 = fmaf(w, __uint_as_float(u << 16), a0);
            a1 = fmaf(w, __uint_as_float(u & 0xffff0000u), a1);
        }
    }
    // combine halves (same m in both halves), then normalize
    a0 += __shfl_xor(a0, 32, 64);
    a1 += __shfl_xor(a1, 32, 64);
    if (half == 0) {
        float o0 = a0 * rsF + bias[2 * fp];
        float o1 = a1 * rsF + bias[2 * fp + 1];
        if (DO_ELU) {
            o0 = o0 > 0.f ? o0 : __expf(o0) - 1.f;
            o1 = o1 > 0.f ? o1 : __expf(o1) - 1.f;
        }
        unsigned packed = (unsigned)bf_bits(o0) | ((unsigned)bf_bits(o1) << 16);
        ((unsigned*)outb)[(size_t)n * 32 + fp] = packed;  // row = 64 shorts = 32 uints
    }
}

// ---------------- aggregation H=1 C=10 + fused log_softmax (layer 3) ----------------
__global__ void agg1h_k(const unsigned short* __restrict__ xpb,
                        const float* __restrict__ asrc, const float* __restrict__ adst,
                        const int* __restrict__ offs, const int* __restrict__ cols,
                        const float* __restrict__ bias, float* __restrict__ out, int N) {
    int gtid = blockIdx.x * blockDim.x + threadIdx.x;
    int n = gtid >> 6;
    if (n >= N) return;
    int lane = threadIdx.x & 63;
    int start = offs[n], end = offs[n + 1];
    float ad = adst[n];
    float vs = asrc[n] + ad;  // implicit self-loop
    vs = LEAKY(vs);

    float m, s;
    if (lane == 0) { m = vs; s = 1.f; } else { m = -1e30f; s = 0.f; }
    for (int e = start + lane; e < end; e += 64) {
        float v = asrc[cols[e]] + ad;
        v = LEAKY(v);
        float mo = fmaxf(m, v);
        s = s * __expf(m - mo) + __expf(v - mo);
        m = mo;
    }
#pragma unroll
    for (int off = 1; off <= 32; off <<= 1) {
        float mo = __shfl_xor(m, off, 64);
        float so = __shfl_xor(s, off, 64);
        float mn = fmaxf(m, mo);
        s = s * __expf(m - mn) + so * __expf(mo - mn);
        m = mn;
    }
    float rs = 1.f / (s + 1e-16f);
    float wself = __expf(vs - m) * rs;

    int j = lane / 10, c = lane - j * 10;
    float acc = 0.f;
    if (j == 0) acc = wself * bf_to_f(xpb[(size_t)n * 10 + c]);  // self term
    for (int c0 = start; c0 < end; c0 += 6) {
        int e = c0 + j;
        if (j < 6 && e < end) {
            int src = cols[e];
            float v = asrc[src] + ad;
            v = LEAKY(v);
            float w = __expf(v - m) * rs;
            acc = fmaf(w, bf_to_f(xpb[(size_t)src * 10 + c]), acc);
        }
    }
    float tot = acc;
#pragma unroll
    for (int k = 1; k < 6; k++) tot += __shfl(acc, lane + 10 * k, 64);

    // fused log_softmax over the 10 classes (valid in lanes 0-9)
    float z = tot + bias[lane < 10 ? lane : 0];
    float mx = -1e30f;
#pragma unroll
    for (int k = 0; k < 10; k++) mx = fmaxf(mx, __shfl(z, k, 64));
    float se = 0.f;
#pragma unroll
    for (int k = 0; k < 10; k++) se += __expf(__shfl(z, k, 64) - mx);
    if (lane < 10) out[(size_t)n * 10 + lane] = z - (__logf(se) + mx);
}

// ---------------- launch ----------------

static inline size_t alignup(size_t x) { return (x + 255) & ~(size_t)255; }

extern "C" void kernel_launch(void* const* d_in, const int* in_sizes, int n_in,
                              void* d_out, int out_size, void* d_ws, size_t ws_size,
                              hipStream_t stream) {
    const float* x   = (const float*)d_in[0];
    const int*   ei  = (const int*)d_in[1];
    const float* W1  = (const float*)d_in[2];
    const float* a1s = (const float*)d_in[3];
    const float* a1d = (const float*)d_in[4];
    const float* b1  = (const float*)d_in[5];
    const float* W2  = (const float*)d_in[6];
    const float* a2s = (const float*)d_in[7];
    const float* a2d = (const float*)d_in[8];
    const float* b2  = (const float*)d_in[9];
    const float* W3  = (const float*)d_in[10];
    const float* a3s = (const float*)d_in[11];
    const float* a3d = (const float*)d_in[12];
    const float* b3  = (const float*)d_in[13];
    float* out = (float*)d_out;

    const int N = in_sizes[0] / 256;
    const int E = in_sizes[1] / 2;
    const int* src = ei;
    const int* dst = ei + E;
    const int NB = (N + 255) >> 8;  // 391 for N=100000 (<= NB_MAX)

    char* p = (char*)d_ws;
    int* offs    = (int*)p; p += alignup(sizeof(int) * (size_t)(N + 1));
    int* bcur    = (int*)p; p += alignup(sizeof(int) * (size_t)(NB_MAX + 1));
    int* ebase   = (int*)p; p += alignup(sizeof(int) * (size_t)(NB_MAX + 1));
    int* cols    = (int*)p; p += alignup(sizeof(int) * (size_t)E);
    unsigned short* xpb   = (unsigned short*)p; p += alignup(2 * (size_t)N * 128);
    unsigned short* hbufb = (unsigned short*)p; p += alignup(2 * (size_t)N * 128);
    float* xp    = (float*)p; p += alignup(sizeof(float) * (size_t)N * 128);
    float* as_   = (float*)p; p += alignup(sizeof(float) * (size_t)N * 8);
    float* ad_   = (float*)p; p += alignup(sizeof(float) * (size_t)N * 8);
    short* Bf1   = (short*)p; p += alignup(sizeof(short) * 8 * 8 * 64 * 16);  // K=256,N=128
    short* Bf2   = (short*)p; p += alignup(sizeof(short) * 4 * 4 * 64 * 16);  // K=128,N=64
    // staged bucket regions alias xp: CSR build finishes before layer-3 writes xp.
    unsigned* staged = (unsigned*)xp;  // NB * BCAP * 4B = 8 MB << 51.2 MB

    const int TB = 256;

    // CSR build: bucketed counting sort (self-loops implicit in agg)
    zero_k<<<(NB + TB - 1) / TB, TB, 0, stream>>>(bcur, NB);
    partition_k<<<(E + 4095) / 4096, 256, 0, stream>>>(src, dst, E, NB, bcur, staged);
    scan_nb_k<<<1, 64, 0, stream>>>(bcur, ebase, NB);
    buildcsr_k<<<NB, 256, 0, stream>>>(staged, bcur, ebase, offs, cols, N, NB);

    // W pre-pack (fragment order, hi|lo)
    prep_w_k<<<(4096 + TB - 1) / TB, TB, 0, stream>>>(W1, Bf1, 256, 128, 8, 4096);
    prep_w_k<<<(1024 + TB - 1) / TB, TB, 0, stream>>>(W2, Bf2, 128, 64, 4, 1024);

    // ---- layer 1: 256 -> 128 (H=8, C=16), ELU
    mfma_gemm_k<64, 4, 2, 1, false, 16, 256><<<dim3((N + 63) / 64, 1), 256, 0, stream>>>(
        x, Bf1, xpb, a1s, a1d, as_, ad_, N, 128, 8);
    agg16_k<true><<<(N * 64 + TB - 1) / TB, TB, 0, stream>>>(
        xpb, as_, ad_, offs, cols, b1, hbufb, N);

    // ---- layer 2: 128 -> 64 (H=8, C=8), ELU  (A is bf16 agg output)
    mfma_gemm_k<64, 4, 1, 1, true, 8, 128><<<dim3((N + 63) / 64, 1), 256, 0, stream>>>(
        hbufb, Bf2, xpb, a2s, a2d, as_, ad_, N, 64, 4);
    agg8c8_k<true><<<(N * 64 + TB - 1) / TB, TB, 0, stream>>>(
        xpb, as_, ad_, offs, cols, b2, hbufb, N);

    // ---- layer 3: 64 -> 10 (H=1, C=10) + fused log_softmax
    gemm_k<64, 16, 16, 4, 1><<<dim3((N + 63) / 64, 1), dim3(16, 16), 0, stream>>>(
        hbufb, W3, xp, xpb, N, 10, 64);
    alpha_k<1, 10><<<(N + TB - 1) / TB, TB, 0, stream>>>(xp, a3s, a3d, as_, ad_, N);
    agg1h_k<<<(N * 64 + TB - 1) / TB, TB, 0, stream>>>(
        xpb, as_, ad_, offs, cols, b3, out, N);
}

// Round 3
// 526.273 us; speedup vs baseline: 1.0261x; 1.0261x over previous
//
#include <hip/hip_runtime.h>
#include <hip/hip_bf16.h>
#include <math.h>

// ---------------------------------------------------------------------------
// GAT 3-layer forward on MI355X.
//   1. Dest-CSR via 2-pass bucketed counting sort (coalesced writes).
//      Self-loops are implicit in the aggregation kernels.
//   2. Layers 1-2: split-bf16 MFMA MFMA GEMM with alpha_src/dst FUSED into
//      the epilogue; writes bf16 C only. R10: whole-K-panel staging with a
//      SINGLE barrier + barrier-free fully-unrolled MFMA phase.
//      Layer 3: f32 vector GEMM (tiny).
//   3. R12: single-pass online-softmax aggregation (R9 numerics) with
//      BATCHED gathers. Mean degree = 16 -> the per-node loop runs ~once,
//      so per-wave latency chain dominates (R11 two-pass doubled it: 86->108).
//      Chunk = 16 edges; all 16 row-gathers are issued right after the cols
//      load (addresses independent of the softmax chain), weight math
//      overlaps the gather flight time, fmas consume at the end.
// ---------------------------------------------------------------------------

#define LEAKY(v) ((v) > 0.f ? (v) : 0.2f * (v))

typedef __bf16 bf16_t;
typedef __bf16 bf16x8 __attribute__((ext_vector_type(8)));
typedef __bf16 bf16x4 __attribute__((ext_vector_type(4)));
typedef float f32x4 __attribute__((ext_vector_type(4)));
typedef unsigned short u16x8 __attribute__((ext_vector_type(8)));

static __device__ __forceinline__ unsigned short bf_bits(float f) {
    bf16_t b = (bf16_t)f;
    return __builtin_bit_cast(unsigned short, b);
}
static __device__ __forceinline__ float bf_to_f(unsigned short u) {
    return __uint_as_float(((unsigned int)u) << 16);
}
static __device__ __forceinline__ float bperm_f(int byteaddr, float v) {
    return __uint_as_float((unsigned)__builtin_amdgcn_ds_bpermute(byteaddr, (int)__float_as_uint(v)));
}

// ---------------- CSR build: 2-pass bucket sort ----------------
constexpr int NB_MAX = 400;
constexpr int BCAP = 5120;  // capacity per bucket region; mean load 4096

__global__ void zero_k(int* a, int n) {
    int i = blockIdx.x * blockDim.x + threadIdx.x;
    if (i < n) a[i] = 0;
}

// Pass 1: partition edges into bucket regions with block-local grouping.
__global__ __launch_bounds__(256) void partition_k(
        const int* __restrict__ src, const int* __restrict__ dst, int E, int NB,
        int* __restrict__ bcur, unsigned* __restrict__ staged) {
    __shared__ int hist[NB_MAX];
    __shared__ int bstart[NB_MAX + 1];
    __shared__ int cur[NB_MAX];
    __shared__ int gbase[NB_MAX];
    __shared__ unsigned words[4096];
    __shared__ unsigned short bidl[4096];
    int tid = threadIdx.x;
    int e0 = blockIdx.x * 4096;
    int cnt = E - e0; if (cnt > 4096) cnt = 4096;
    if (cnt <= 0) return;

    for (int b = tid; b < NB; b += 256) hist[b] = 0;
    __syncthreads();
    for (int i = tid; i < cnt; i += 256) atomicAdd(&hist[dst[e0 + i] >> 8], 1);
    __syncthreads();
    if (tid == 0) {
        int run = 0;
        for (int b = 0; b < NB; b++) { bstart[b] = run; run += hist[b]; }
        bstart[NB] = run;
    }
    __syncthreads();
    for (int b = tid; b < NB; b += 256) {
        cur[b] = bstart[b];
        gbase[b] = hist[b] ? atomicAdd(&bcur[b], hist[b]) : 0;
    }
    __syncthreads();
    // group into LDS by bucket, remember bucket id per slot
    for (int i = tid; i < cnt; i += 256) {
        int s = src[e0 + i], d = dst[e0 + i];
        int b = d >> 8;
        unsigned w = (unsigned)s | ((unsigned)(d & 255) << 17);
        int p = atomicAdd(&cur[b], 1);
        words[p] = w;
        bidl[p] = (unsigned short)b;
    }
    __syncthreads();
    // linear sweep -> coalesced runs into global bucket regions
    for (int i = tid; i < cnt; i += 256) {
        int b = bidl[i];
        staged[(size_t)b * BCAP + gbase[b] + (i - bstart[b])] = words[i];
    }
}

// tiny exclusive scan over NB bucket counts (one wave)
__global__ void scan_nb_k(const int* __restrict__ bcur, int* __restrict__ ebase, int NB) {
    int lane = threadIdx.x;  // 64 threads
    int CH = (NB + 63) / 64;
    int b0 = lane * CH;
    int v[8]; int s = 0;
#pragma unroll 8
    for (int k = 0; k < CH; k++) { int b = b0 + k; int t = (b < NB) ? bcur[b] : 0; if (k < 8) v[k] = t; s += t; }
    int orig = s;
    for (int off = 1; off < 64; off <<= 1) {
        int t = __shfl_up(s, off, 64);
        if (lane >= off) s += t;
    }
    int run = s - orig;  // exclusive
    for (int k = 0; k < CH; k++) { int b = b0 + k; if (b < NB) { ebase[b] = run; run += v[k]; } }
    if (lane == 63) ebase[NB] = run;
}

// Pass 2: per-bucket node-level counting sort -> offs + cols (coalesced writes).
__global__ __launch_bounds__(256) void buildcsr_k(
        const unsigned* __restrict__ staged, const int* __restrict__ bcur,
        const int* __restrict__ ebase, int* __restrict__ offs, int* __restrict__ cols,
        int N, int NB) {
    __shared__ int h[256], hs[256], curl[256];
    __shared__ int colsl[BCAP];
    int b = blockIdx.x, tid = threadIdx.x;
    int n0 = b << 8;
    int ecnt = bcur[b];
    int base_g = ebase[b];
    const unsigned* sb = staged + (size_t)b * BCAP;

    h[tid] = 0;
    __syncthreads();
    for (int i = tid; i < ecnt; i += 256) atomicAdd(&h[sb[i] >> 17], 1);
    __syncthreads();
    int val = h[tid];
    hs[tid] = val; __syncthreads();
    for (int off = 1; off < 256; off <<= 1) {
        int t = (tid >= off) ? hs[tid - off] : 0;
        __syncthreads();
        hs[tid] += t;
        __syncthreads();
    }
    int excl = hs[tid] - val;
    curl[tid] = excl;
    if (n0 + tid < N) offs[n0 + tid] = base_g + excl;
    if (b == NB - 1 && tid == 0) offs[N] = base_g + ecnt;
    __syncthreads();
    for (int i = tid; i < ecnt; i += 256) {
        unsigned w = sb[i];
        int p = atomicAdd(&curl[w >> 17], 1);
        colsl[p] = (int)(w & 0x1FFFFu);
    }
    __syncthreads();
    for (int i = tid; i < ecnt; i += 256) cols[base_g + i] = colsl[i];
}

// ---------------- W pre-pack into MFMA B-fragment order (hi|lo) ----------------
__global__ void prep_w_k(const float* __restrict__ W, short* __restrict__ Bfs,
                         int K, int N, int NT, int total) {
    int idx = blockIdx.x * blockDim.x + threadIdx.x;
    if (idx >= total) return;  // total = (K/32)*NT*64
    int lane = idx & 63;
    int t = idx >> 6;
    int ntile = t % NT, kstep = t / NT;
    int quad = lane >> 4, nl = lane & 15;
    int n = ntile * 16 + nl;
    bf16_t* dst = (bf16_t*)Bfs + (size_t)idx * 16;
#pragma unroll
    for (int j = 0; j < 8; j++) {
        int k = kstep * 32 + quad * 8 + j;
        float v = W[k * N + n];
        bf16_t h = (bf16_t)v;
        bf16_t l = (bf16_t)(v - (float)h);
        dst[j] = h;
        dst[8 + j] = l;
    }
}

// ---------------- split-bf16 MFMA GEMM, fused alpha epilogue ----------------
// R10 structure: stage the FULL BM x K panel (split hi/lo for f32 A) with
// 16 independent 16B loads per thread -> one __syncthreads -> barrier-free
// fully-unrolled MFMA phase. NWM=1: waves own disjoint B tiles.
// Writes Cb (bf16) + alpha_src/alpha_dst [M, N/CHEAD] (f32, exact from acc).
template <int BM, int WMT, int WNT, int NWM, bool ABF16, int CHEAD, int K>
__global__ __launch_bounds__(256, 2) void mfma_gemm_k(
        const void* __restrict__ Av, const short* __restrict__ Bfs,
        unsigned short* __restrict__ Cb,
        const float* __restrict__ a_s, const float* __restrict__ a_d,
        float* __restrict__ out_as, float* __restrict__ out_ad,
        int M, int N, int NT) {
    constexpr int NWN = 4 / NWM;
    constexpr int BN = 16 * WNT * NWN;
    constexpr int KP = K + 8;  // +8 bf16: keeps b128 reads at free 2-way banks
    __shared__ __align__(16) bf16_t As_hi[BM * KP];
    __shared__ __align__(16) bf16_t As_lo[ABF16 ? 16 : BM * KP];
    const bf16_t* Bf = (const bf16_t*)Bfs;

    int tid = threadIdx.x;
    int wave = tid >> 6, lane = tid & 63;
    int quad = lane >> 4, l16 = lane & 15;
    int wm = wave % NWM, wn = wave / NWM;
    int row0 = blockIdx.x * BM;
    int ntile0 = blockIdx.y * (BN / 16) + wn * WNT;

    // ---- stage whole panel: all loads issued before any conversion ----
    if constexpr (!ABF16) {
        constexpr int CHUNKS = BM * K * 4 / (16 * 256);  // 16B chunks per thread
        const float* A = (const float*)Av;
        f32x4 tmp[CHUNKS];
#pragma unroll
        for (int c = 0; c < CHUNKS; c++) {
            int ci = c * 256 + tid;
            int fi = ci * 4;
            int row = fi / K, k = fi % K;
            int grow = row0 + row;
            tmp[c] = (f32x4){0.f, 0.f, 0.f, 0.f};
            if (grow < M) tmp[c] = *(const f32x4*)(A + (size_t)grow * K + k);
        }
#pragma unroll
        for (int c = 0; c < CHUNKS; c++) {
            int ci = c * 256 + tid;
            int fi = ci * 4;
            int row = fi / K, k = fi % K;
            bf16x4 h, l;
#pragma unroll
            for (int j = 0; j < 4; j++) {
                bf16_t hh = (bf16_t)tmp[c][j];
                h[j] = hh;
                l[j] = (bf16_t)(tmp[c][j] - (float)hh);
            }
            *(bf16x4*)&As_hi[row * KP + k] = h;
            *(bf16x4*)&As_lo[row * KP + k] = l;
        }
    } else {
        constexpr int CHUNKS = BM * K * 2 / (16 * 256);
        const unsigned short* A = (const unsigned short*)Av;
        u16x8 tmp[CHUNKS];
#pragma unroll
        for (int c = 0; c < CHUNKS; c++) {
            int ci = c * 256 + tid;
            int ei = ci * 8;
            int row = ei / K, k = ei % K;
            int grow = row0 + row;
            tmp[c] = (u16x8){0, 0, 0, 0, 0, 0, 0, 0};
            if (grow < M) tmp[c] = *(const u16x8*)(A + (size_t)grow * K + k);
        }
#pragma unroll
        for (int c = 0; c < CHUNKS; c++) {
            int ci = c * 256 + tid;
            int ei = ci * 8;
            int row = ei / K, k = ei % K;
            *(u16x8*)&As_hi[row * KP + k] = tmp[c];
        }
    }
    __syncthreads();

    // ---- barrier-free compute over all K steps ----
    f32x4 acc[WMT][WNT];
#pragma unroll
    for (int i = 0; i < WMT; i++)
#pragma unroll
        for (int j = 0; j < WNT; j++) acc[i][j] = (f32x4){0.f, 0.f, 0.f, 0.f};

#pragma unroll
    for (int ks = 0; ks < K / 32; ks++) {
        bf16x8 ah[WMT], al[WMT];
#pragma unroll
        for (int i = 0; i < WMT; i++) {
            int rowl = wm * (WMT * 16) + i * 16 + l16;
            ah[i] = *(const bf16x8*)&As_hi[rowl * KP + ks * 32 + quad * 8];
            if (!ABF16) al[i] = *(const bf16x8*)&As_lo[rowl * KP + ks * 32 + quad * 8];
        }
        bf16x8 bh[WNT], bl[WNT];
#pragma unroll
        for (int j = 0; j < WNT; j++) {
            size_t base = ((size_t)(ks * NT + ntile0 + j) * 64 + lane) * 16;
            bh[j] = *(const bf16x8*)&Bf[base];
            bl[j] = *(const bf16x8*)&Bf[base + 8];
        }
#pragma unroll
        for (int i = 0; i < WMT; i++)
#pragma unroll
            for (int j = 0; j < WNT; j++) {
                acc[i][j] = __builtin_amdgcn_mfma_f32_16x16x32_bf16(ah[i], bh[j], acc[i][j], 0, 0, 0);
                if (!ABF16)
                    acc[i][j] = __builtin_amdgcn_mfma_f32_16x16x32_bf16(al[i], bh[j], acc[i][j], 0, 0, 0);
                acc[i][j] = __builtin_amdgcn_mfma_f32_16x16x32_bf16(ah[i], bl[j], acc[i][j], 0, 0, 0);
            }
    }

    // bf16 C store: D[row = quad*4 + r][col = l16] per 16x16 tile
#pragma unroll
    for (int i = 0; i < WMT; i++) {
        int rbase = row0 + wm * (WMT * 16) + i * 16 + quad * 4;
#pragma unroll
        for (int j = 0; j < WNT; j++) {
            int gcol = (ntile0 + j) * 16 + l16;
#pragma unroll
            for (int r2 = 0; r2 < 4; r2++) {
                int grow = rbase + r2;
                if (grow < M) Cb[(size_t)grow * N + gcol] = bf_bits(acc[i][j][r2]);
            }
        }
    }

    // fused alpha: per tile j, coef = a_flat[gcol]; reduce over CHEAD-lane groups
    const int Hh = N / CHEAD;
#pragma unroll
    for (int j = 0; j < WNT; j++) {
        int gcol = (ntile0 + j) * 16 + l16;
        float cs = a_s[gcol], cd = a_d[gcol];
#pragma unroll
        for (int i = 0; i < WMT; i++) {
            float ps[4], pd[4];
#pragma unroll
            for (int r2 = 0; r2 < 4; r2++) {
                ps[r2] = acc[i][j][r2] * cs;
                pd[r2] = acc[i][j][r2] * cd;
            }
#pragma unroll
            for (int off = 1; off < CHEAD; off <<= 1) {
#pragma unroll
                for (int r2 = 0; r2 < 4; r2++) {
                    ps[r2] += __shfl_xor(ps[r2], off, 64);
                    pd[r2] += __shfl_xor(pd[r2], off, 64);
                }
            }
            if ((l16 & (CHEAD - 1)) == 0) {
                int hd = gcol / CHEAD;
                int rb = row0 + wm * (WMT * 16) + i * 16 + quad * 4;
#pragma unroll
                for (int r2 = 0; r2 < 4; r2++) {
                    int grow = rb + r2;
                    if (grow < M) {
                        out_as[(size_t)grow * Hh + hd] = ps[r2];
                        out_ad[(size_t)grow * Hh + hd] = pd[r2];
                    }
                }
            }
        }
    }
}

// ---------------- GEMM (f32 vector, bf16 A) — layer 3 only ----------------
template <int BM, int BN, int BK, int TM, int TN>
__global__ void gemm_k(const unsigned short* __restrict__ Ab, const float* __restrict__ B,
                       float* __restrict__ C, unsigned short* __restrict__ Cb,
                       int M, int Nc, int K) {
    __shared__ float As[BK][BM + 1];
    __shared__ float Bs[BK][BN + 1];
    int tx = threadIdx.x, ty = threadIdx.y;
    int tid = ty * blockDim.x + tx;
    const int nthreads = (BM / TM) * (BN / TN);
    int row0 = blockIdx.x * BM, col0 = blockIdx.y * BN;
    float acc[TM][TN];
#pragma unroll
    for (int i = 0; i < TM; i++)
#pragma unroll
        for (int j = 0; j < TN; j++) acc[i][j] = 0.f;

    for (int k0 = 0; k0 < K; k0 += BK) {
        for (int i = tid; i < BM * BK; i += nthreads) {
            int r = i / BK, kk = i % BK;
            int gr = row0 + r;
            As[kk][r] = (gr < M) ? bf_to_f(Ab[(size_t)gr * K + (k0 + kk)]) : 0.f;
        }
        for (int i = tid; i < BK * BN; i += nthreads) {
            int kk = i / BN, c = i % BN;
            int gc = col0 + c;
            Bs[kk][c] = (gc < Nc) ? B[(long)(k0 + kk) * Nc + gc] : 0.f;
        }
        __syncthreads();
#pragma unroll
        for (int kk = 0; kk < BK; ++kk) {
            float a[TM], b[TN];
#pragma unroll
            for (int i = 0; i < TM; i++) a[i] = As[kk][ty * TM + i];
#pragma unroll
            for (int j = 0; j < TN; j++) b[j] = Bs[kk][tx * TN + j];
#pragma unroll
            for (int i = 0; i < TM; i++)
#pragma unroll
                for (int j = 0; j < TN; j++) acc[i][j] = fmaf(a[i], b[j], acc[i][j]);
        }
        __syncthreads();
    }
#pragma unroll
    for (int i = 0; i < TM; i++) {
        int gr = row0 + ty * TM + i;
        if (gr >= M) continue;
#pragma unroll
        for (int j = 0; j < TN; j++) {
            int gc = col0 + tx * TN + j;
            if (gc < Nc) {
                C[(long)gr * Nc + gc] = acc[i][j];
                Cb[(long)gr * Nc + gc] = bf_bits(acc[i][j]);
            }
        }
    }
}

// ---------------- alpha (layer 3 only) ----------------
template <int H, int C>
__global__ void alpha_k(const float* __restrict__ xp, const float* __restrict__ a_s,
                        const float* __restrict__ a_d, float* __restrict__ out_s,
                        float* __restrict__ out_d, int NH) {
    int i = blockIdx.x * blockDim.x + threadIdx.x;
    if (i >= NH) return;
    int h = i % H;
    const float* v = xp + (long)i * C;
    float ss = 0.f, sd = 0.f;
#pragma unroll
    for (int c = 0; c < C; c++) {
        float x = v[c];
        ss = fmaf(x, a_s[h * C + c], ss);
        sd = fmaf(x, a_d[h * C + c], sd);
    }
    out_s[i] = ss;
    out_d[i] = sd;
}

// ---------------- single-pass batched aggregation, H=8 C=16 (layer 1) ----------------
// Chunk = 16 edges. All 16 row-gathers issue right after cols (addresses
// independent of softmax chain); weight math overlaps gather flight.
template <bool DO_ELU>
__global__ void agg16_k(const unsigned short* __restrict__ xpb,
                        const float* __restrict__ asrc, const float* __restrict__ adst,
                        const int* __restrict__ offs, const int* __restrict__ cols,
                        const float* __restrict__ bias, unsigned short* __restrict__ outb,
                        int N) {
    int gtid = blockIdx.x * blockDim.x + threadIdx.x;
    int n = gtid >> 6;
    if (n >= N) return;
    int lane = threadIdx.x & 63;
    int j = lane >> 3, h = lane & 7;
    const int jb = j << 2;  // bpermute byte addr of (j=0, h=j) lane
    int start = offs[n], end = offs[n + 1];
    const unsigned* xp32 = (const unsigned*)xpb;

    // independent loads first
    unsigned uself = xp32[(size_t)n * 64 + lane];
    float ad_l = adst[n * 8 + h];
    float vs = asrc[n * 8 + h] + ad_l;
    vs = LEAKY(vs);

    // weight-role state (head h): seeded with implicit self-loop
    float m_w = vs;
    float s = (j == 0) ? 1.f : 0.f;
    // feature-role state (head j): acc = self row (weight exp(vs-vs)=1)
    float m_f = bperm_f(jb, vs);
    float a0 = __uint_as_float(uself << 16);
    float a1 = __uint_as_float(uself & 0xffff0000u);

    for (int c0 = start; c0 < end; c0 += 16) {
        int e0 = c0 + j, e1 = c0 + 8 + j;
        bool ok0 = e0 < end, ok1 = e1 < end;
        int sl0 = ok0 ? cols[e0] : 0;
        int sl1 = ok1 ? cols[e1] : 0;
        // ---- issue all 16 row gathers (dep only on cols) ----
        unsigned u[16];
#pragma unroll
        for (int t = 0; t < 8; t++) {
            int srcj = __builtin_amdgcn_readlane(sl0, t * 8);
            u[t] = xp32[(size_t)srcj * 64 + lane];
        }
#pragma unroll
        for (int t = 0; t < 8; t++) {
            int srcj = __builtin_amdgcn_readlane(sl1, t * 8);
            u[8 + t] = xp32[(size_t)srcj * 64 + lane];
        }
        // ---- weight math while gathers are in flight ----
        float v0 = -1e30f, v1 = -1e30f;
        if (ok0) { v0 = asrc[sl0 * 8 + h] + ad_l; v0 = LEAKY(v0); }
        if (ok1) { v1 = asrc[sl1 * 8 + h] + ad_l; v1 = LEAKY(v1); }
        float cm = fmaxf(v0, v1);
        cm = fmaxf(cm, __shfl_xor(cm, 8, 64));
        cm = fmaxf(cm, __shfl_xor(cm, 16, 64));
        cm = fmaxf(cm, __shfl_xor(cm, 32, 64));
        float mw_new = fmaxf(m_w, cm);
        float w0 = __expf(v0 - mw_new);  // 0 for invalid slots
        float w1 = __expf(v1 - mw_new);
        s = s * __expf(m_w - mw_new) + w0 + w1;
        m_w = mw_new;
        // feature-role rescale (head j)
        float cmF = bperm_f(jb, cm);
        float mf_new = fmaxf(m_f, cmF);
        float scF = __expf(m_f - mf_new);
        m_f = mf_new;
        a0 *= scF; a1 *= scF;
        float wl[16];
#pragma unroll
        for (int t = 0; t < 8; t++) wl[t] = bperm_f(jb + t * 32, w0);
#pragma unroll
        for (int t = 0; t < 8; t++) wl[8 + t] = bperm_f(jb + t * 32, w1);
        // ---- consume ----
#pragma unroll
        for (int t = 0; t < 16; t++) {
            a0 = fmaf(wl[t], __uint_as_float(u[t] << 16), a0);
            a1 = fmaf(wl[t], __uint_as_float(u[t] & 0xffff0000u), a1);
        }
    }
    // finalize: total s per head, then normalize
    s += __shfl_xor(s, 8, 64);
    s += __shfl_xor(s, 16, 64);
    s += __shfl_xor(s, 32, 64);
    float rs = 1.f / (s + 1e-16f);
    float rsF = bperm_f(jb, rs);
    float o0 = a0 * rsF + bias[2 * lane];
    float o1 = a1 * rsF + bias[2 * lane + 1];
    if (DO_ELU) {
        o0 = o0 > 0.f ? o0 : __expf(o0) - 1.f;
        o1 = o1 > 0.f ? o1 : __expf(o1) - 1.f;
    }
    unsigned packed = (unsigned)bf_bits(o0) | ((unsigned)bf_bits(o1) << 16);
    ((unsigned*)outb)[(size_t)n * 64 + lane] = packed;  // row = 128 shorts = 64 uints
}

// ---------------- single-pass batched aggregation, H=8 C=8 (layer 2) ----------------
template <bool DO_ELU>
__global__ void agg8c8_k(const unsigned short* __restrict__ xpb,
                         const float* __restrict__ asrc, const float* __restrict__ adst,
                         const int* __restrict__ offs, const int* __restrict__ cols,
                         const float* __restrict__ bias, unsigned short* __restrict__ outb,
                         int N) {
    int gtid = blockIdx.x * blockDim.x + threadIdx.x;
    int n = gtid >> 6;
    if (n >= N) return;
    int lane = threadIdx.x & 63;
    int j = lane >> 3, h = lane & 7;
    int start = offs[n], end = offs[n + 1];
    const unsigned* xp32 = (const unsigned*)xpb;

    int fp = lane & 31;      // feature pair {2fp, 2fp+1}
    int hF = fp >> 2;        // feature-role head
    int half = lane >> 5;
    int sbase = half * 32;

    float ad_l = adst[n * 8 + h];
    float vs = asrc[n * 8 + h] + ad_l;
    vs = LEAKY(vs);

    float m_w = vs;
    float s = (j == 0) ? 1.f : 0.f;
    float m_f = bperm_f(hF * 4, vs);
    float a0 = 0.f, a1 = 0.f;
    if (half == 0) {  // self contribution in half 0 only
        unsigned u = xp32[(size_t)n * 32 + fp];
        a0 = __uint_as_float(u << 16);
        a1 = __uint_as_float(u & 0xffff0000u);
    }

    for (int c0 = start; c0 < end; c0 += 16) {
        int e0 = c0 + j, e1 = c0 + 8 + j;
        bool ok0 = e0 < end, ok1 = e1 < end;
        int sl0 = ok0 ? cols[e0] : 0;
        int sl1 = ok1 ? cols[e1] : 0;
        // ---- issue all 8 row gathers per lane-half (dep only on cols) ----
        int sv[8];
#pragma unroll
        for (int t = 0; t < 4; t++) sv[t] = __builtin_amdgcn_ds_bpermute(sbase + t * 64, sl0);
#pragma unroll
        for (int t = 0; t < 4; t++) sv[4 + t] = __builtin_amdgcn_ds_bpermute(sbase + t * 64, sl1);
        unsigned u[8];
#pragma unroll
        for (int t = 0; t < 8; t++) u[t] = xp32[(size_t)sv[t] * 32 + fp];
        // ---- weight math while gathers are in flight ----
        float v0 = -1e30f, v1 = -1e30f;
        if (ok0) { v0 = asrc[sl0 * 8 + h] + ad_l; v0 = LEAKY(v0); }
        if (ok1) { v1 = asrc[sl1 * 8 + h] + ad_l; v1 = LEAKY(v1); }
        float cm = fmaxf(v0, v1);
        cm = fmaxf(cm, __shfl_xor(cm, 8, 64));
        cm = fmaxf(cm, __shfl_xor(cm, 16, 64));
        cm = fmaxf(cm, __shfl_xor(cm, 32, 64));
        float mw_new = fmaxf(m_w, cm);
        float w0 = __expf(v0 - mw_new);
        float w1 = __expf(v1 - mw_new);
        s = s * __expf(m_w - mw_new) + w0 + w1;
        m_w = mw_new;
        float cmF = bperm_f(hF * 4, cm);
        float mf_new = fmaxf(m_f, cmF);
        float scF = __expf(m_f - mf_new);
        m_f = mf_new;
        a0 *= scF; a1 *= scF;
        float wl[8];
#pragma unroll
        for (int t = 0; t < 4; t++) wl[t] = bperm_f(sbase + hF * 4 + t * 64, w0);
#pragma unroll
        for (int t = 0; t < 4; t++) wl[4 + t] = bperm_f(sbase + hF * 4 + t * 64, w1);
        // ---- consume ----
#pragma unroll
        for (int t = 0; t < 8; t++) {
            a0 = fmaf(wl[t], __uint_as_float(u[t] << 16), a0);
            a1 = fmaf(wl[t], __uint_as_float(u[t] & 0xffff0000u), a1);
        }
    }
    s += __shfl_xor(s, 8, 64);
    s += __shfl_xor(s, 16, 64);
    s += __shfl_xor(s, 32, 64);
    float rs = 1.f / (s + 1e-16f);
    float rsF = bperm_f(hF * 4, rs);
    // combine halves (same m_f in both halves), then normalize
    a0 += __shfl_xor(a0, 32, 64);
    a1 += __shfl_xor(a1, 32, 64);
    if (half == 0) {
        float o0 = a0 * rsF + bias[2 * fp];
        float o1 = a1 * rsF + bias[2 * fp + 1];
        if (DO_ELU) {
            o0 = o0 > 0.f ? o0 : __expf(o0) - 1.f;
            o1 = o1 > 0.f ? o1 : __expf(o1) - 1.f;
        }
        unsigned packed = (unsigned)bf_bits(o0) | ((unsigned)bf_bits(o1) << 16);
        ((unsigned*)outb)[(size_t)n * 32 + fp] = packed;  // row = 64 shorts = 32 uints
    }
}

// ---------------- aggregation H=1 C=10 + fused log_softmax (layer 3) ----------------
__global__ void agg1h_k(const unsigned short* __restrict__ xpb,
                        const float* __restrict__ asrc, const float* __restrict__ adst,
                        const int* __restrict__ offs, const int* __restrict__ cols,
                        const float* __restrict__ bias, float* __restrict__ out, int N) {
    int gtid = blockIdx.x * blockDim.x + threadIdx.x;
    int n = gtid >> 6;
    if (n >= N) return;
    int lane = threadIdx.x & 63;
    int start = offs[n], end = offs[n + 1];
    float ad = adst[n];
    float vs = asrc[n] + ad;  // implicit self-loop
    vs = LEAKY(vs);

    float m, s;
    if (lane == 0) { m = vs; s = 1.f; } else { m = -1e30f; s = 0.f; }
    for (int e = start + lane; e < end; e += 64) {
        float v = asrc[cols[e]] + ad;
        v = LEAKY(v);
        float mo = fmaxf(m, v);
        s = s * __expf(m - mo) + __expf(v - mo);
        m = mo;
    }
#pragma unroll
    for (int off = 1; off <= 32; off <<= 1) {
        float mo = __shfl_xor(m, off, 64);
        float so = __shfl_xor(s, off, 64);
        float mn = fmaxf(m, mo);
        s = s * __expf(m - mn) + so * __expf(mo - mn);
        m = mn;
    }
    float rs = 1.f / (s + 1e-16f);
    float wself = __expf(vs - m) * rs;

    int j = lane / 10, c = lane - j * 10;
    float acc = 0.f;
    if (j == 0) acc = wself * bf_to_f(xpb[(size_t)n * 10 + c]);  // self term
    for (int c0 = start; c0 < end; c0 += 6) {
        int e = c0 + j;
        if (j < 6 && e < end) {
            int src = cols[e];
            float v = asrc[src] + ad;
            v = LEAKY(v);
            float w = __expf(v - m) * rs;
            acc = fmaf(w, bf_to_f(xpb[(size_t)src * 10 + c]), acc);
        }
    }
    float tot = acc;
#pragma unroll
    for (int k = 1; k < 6; k++) tot += __shfl(acc, lane + 10 * k, 64);

    // fused log_softmax over the 10 classes (valid in lanes 0-9)
    float z = tot + bias[lane < 10 ? lane : 0];
    float mx = -1e30f;
#pragma unroll
    for (int k = 0; k < 10; k++) mx = fmaxf(mx, __shfl(z, k, 64));
    float se = 0.f;
#pragma unroll
    for (int k = 0; k < 10; k++) se += __expf(__shfl(z, k, 64) - mx);
    if (lane < 10) out[(size_t)n * 10 + lane] = z - (__logf(se) + mx);
}

// ---------------- launch ----------------

static inline size_t alignup(size_t x) { return (x + 255) & ~(size_t)255; }

extern "C" void kernel_launch(void* const* d_in, const int* in_sizes, int n_in,
                              void* d_out, int out_size, void* d_ws, size_t ws_size,
                              hipStream_t stream) {
    const float* x   = (const float*)d_in[0];
    const int*   ei  = (const int*)d_in[1];
    const float* W1  = (const float*)d_in[2];
    const float* a1s = (const float*)d_in[3];
    const float* a1d = (const float*)d_in[4];
    const float* b1  = (const float*)d_in[5];
    const float* W2  = (const float*)d_in[6];
    const float* a2s = (const float*)d_in[7];
    const float* a2d = (const float*)d_in[8];
    const float* b2  = (const float*)d_in[9];
    const float* W3  = (const float*)d_in[10];
    const float* a3s = (const float*)d_in[11];
    const float* a3d = (const float*)d_in[12];
    const float* b3  = (const float*)d_in[13];
    float* out = (float*)d_out;

    const int N = in_sizes[0] / 256;
    const int E = in_sizes[1] / 2;
    const int* src = ei;
    const int* dst = ei + E;
    const int NB = (N + 255) >> 8;  // 391 for N=100000 (<= NB_MAX)

    char* p = (char*)d_ws;
    int* offs    = (int*)p; p += alignup(sizeof(int) * (size_t)(N + 1));
    int* bcur    = (int*)p; p += alignup(sizeof(int) * (size_t)(NB_MAX + 1));
    int* ebase   = (int*)p; p += alignup(sizeof(int) * (size_t)(NB_MAX + 1));
    int* cols    = (int*)p; p += alignup(sizeof(int) * (size_t)E);
    unsigned short* xpb   = (unsigned short*)p; p += alignup(2 * (size_t)N * 128);
    unsigned short* hbufb = (unsigned short*)p; p += alignup(2 * (size_t)N * 128);
    float* xp    = (float*)p; p += alignup(sizeof(float) * (size_t)N * 128);
    float* as_   = (float*)p; p += alignup(sizeof(float) * (size_t)N * 8);
    float* ad_   = (float*)p; p += alignup(sizeof(float) * (size_t)N * 8);
    short* Bf1   = (short*)p; p += alignup(sizeof(short) * 8 * 8 * 64 * 16);  // K=256,N=128
    short* Bf2   = (short*)p; p += alignup(sizeof(short) * 4 * 4 * 64 * 16);  // K=128,N=64
    // staged bucket regions alias xp: CSR build finishes before layer-3 writes xp.
    unsigned* staged = (unsigned*)xp;  // NB * BCAP * 4B = 8 MB << 51.2 MB

    const int TB = 256;

    // CSR build: bucketed counting sort (self-loops implicit in agg)
    zero_k<<<(NB + TB - 1) / TB, TB, 0, stream>>>(bcur, NB);
    partition_k<<<(E + 4095) / 4096, 256, 0, stream>>>(src, dst, E, NB, bcur, staged);
    scan_nb_k<<<1, 64, 0, stream>>>(bcur, ebase, NB);
    buildcsr_k<<<NB, 256, 0, stream>>>(staged, bcur, ebase, offs, cols, N, NB);

    // W pre-pack (fragment order, hi|lo)
    prep_w_k<<<(4096 + TB - 1) / TB, TB, 0, stream>>>(W1, Bf1, 256, 128, 8, 4096);
    prep_w_k<<<(1024 + TB - 1) / TB, TB, 0, stream>>>(W2, Bf2, 128, 64, 4, 1024);

    // ---- layer 1: 256 -> 128 (H=8, C=16), ELU
    mfma_gemm_k<64, 4, 2, 1, false, 16, 256><<<dim3((N + 63) / 64, 1), 256, 0, stream>>>(
        x, Bf1, xpb, a1s, a1d, as_, ad_, N, 128, 8);
    agg16_k<true><<<(N * 64 + TB - 1) / TB, TB, 0, stream>>>(
        xpb, as_, ad_, offs, cols, b1, hbufb, N);

    // ---- layer 2: 128 -> 64 (H=8, C=8), ELU  (A is bf16 agg output)
    mfma_gemm_k<64, 4, 1, 1, true, 8, 128><<<dim3((N + 63) / 64, 1), 256, 0, stream>>>(
        hbufb, Bf2, xpb, a2s, a2d, as_, ad_, N, 64, 4);
    agg8c8_k<true><<<(N * 64 + TB - 1) / TB, TB, 0, stream>>>(
        xpb, as_, ad_, offs, cols, b2, hbufb, N);

    // ---- layer 3: 64 -> 10 (H=1, C=10) + fused log_softmax
    gemm_k<64, 16, 16, 4, 1><<<dim3((N + 63) / 64, 1), dim3(16, 16), 0, stream>>>(
        hbufb, W3, xp, xpb, N, 10, 64);
    alpha_k<1, 10><<<(N + TB - 1) / TB, TB, 0, stream>>>(xp, a3s, a3d, as_, ad_, N);
    agg1h_k<<<(N * 64 + TB - 1) / TB, TB, 0, stream>>>(
        xpb, as_, ad_, offs, cols, b3, out, N);
}

// Round 4
// 509.607 us; speedup vs baseline: 1.0597x; 1.0327x over previous
//
#include <hip/hip_runtime.h>
#include <hip/hip_bf16.h>
#include <math.h>

// ---------------------------------------------------------------------------
// GAT 3-layer forward on MI355X.
//   1. Dest-CSR via 2-pass bucketed counting sort (coalesced writes).
//      Self-loops are implicit in the aggregation kernels.
//   2. Layers 1-2: split-bf16 MFMA GEMM with alpha_src/dst FUSED into the
//      epilogue; writes bf16 C only. R10: whole-K-panel staging with a
//      SINGLE barrier + barrier-free fully-unrolled MFMA phase.
//   3. R13: layer 3 = gemm3_k, one MFMA kernel replacing the scalar-staged
//      f32 gemm_k + separate alpha_k. A (bf16) loads coalesced bf16x8
//      straight from global; W3 pre-packed zero-padded to 16 cols (hi|lo
//      split); alpha3 computed in-register (16-lane reduce). f32 xp array
//      is dead. zero_k launch replaced by hipMemsetAsync.
//   4. Aggregation: single-pass online-softmax, batched gathers (R12).
//      agg16 is AT the random-gather throughput wall (~5 TB/s line-level):
//      R9 interleave/R11 two-pass/R12 batch = 86/108/86 us, FETCH const
//      264 MB -> scheduling-invariant. Do not re-attack without shrinking
//      the gather table.
// ---------------------------------------------------------------------------

#define LEAKY(v) ((v) > 0.f ? (v) : 0.2f * (v))

typedef __bf16 bf16_t;
typedef __bf16 bf16x8 __attribute__((ext_vector_type(8)));
typedef __bf16 bf16x4 __attribute__((ext_vector_type(4)));
typedef float f32x4 __attribute__((ext_vector_type(4)));
typedef unsigned short u16x8 __attribute__((ext_vector_type(8)));

static __device__ __forceinline__ unsigned short bf_bits(float f) {
    bf16_t b = (bf16_t)f;
    return __builtin_bit_cast(unsigned short, b);
}
static __device__ __forceinline__ float bf_to_f(unsigned short u) {
    return __uint_as_float(((unsigned int)u) << 16);
}
static __device__ __forceinline__ float bperm_f(int byteaddr, float v) {
    return __uint_as_float((unsigned)__builtin_amdgcn_ds_bpermute(byteaddr, (int)__float_as_uint(v)));
}

// ---------------- CSR build: 2-pass bucket sort ----------------
constexpr int NB_MAX = 400;
constexpr int BCAP = 5120;  // capacity per bucket region; mean load 4096

// Pass 1: partition edges into bucket regions with block-local grouping.
__global__ __launch_bounds__(256) void partition_k(
        const int* __restrict__ src, const int* __restrict__ dst, int E, int NB,
        int* __restrict__ bcur, unsigned* __restrict__ staged) {
    __shared__ int hist[NB_MAX];
    __shared__ int bstart[NB_MAX + 1];
    __shared__ int cur[NB_MAX];
    __shared__ int gbase[NB_MAX];
    __shared__ unsigned words[4096];
    __shared__ unsigned short bidl[4096];
    int tid = threadIdx.x;
    int e0 = blockIdx.x * 4096;
    int cnt = E - e0; if (cnt > 4096) cnt = 4096;
    if (cnt <= 0) return;

    for (int b = tid; b < NB; b += 256) hist[b] = 0;
    __syncthreads();
    for (int i = tid; i < cnt; i += 256) atomicAdd(&hist[dst[e0 + i] >> 8], 1);
    __syncthreads();
    if (tid == 0) {
        int run = 0;
        for (int b = 0; b < NB; b++) { bstart[b] = run; run += hist[b]; }
        bstart[NB] = run;
    }
    __syncthreads();
    for (int b = tid; b < NB; b += 256) {
        cur[b] = bstart[b];
        gbase[b] = hist[b] ? atomicAdd(&bcur[b], hist[b]) : 0;
    }
    __syncthreads();
    // group into LDS by bucket, remember bucket id per slot
    for (int i = tid; i < cnt; i += 256) {
        int s = src[e0 + i], d = dst[e0 + i];
        int b = d >> 8;
        unsigned w = (unsigned)s | ((unsigned)(d & 255) << 17);
        int p = atomicAdd(&cur[b], 1);
        words[p] = w;
        bidl[p] = (unsigned short)b;
    }
    __syncthreads();
    // linear sweep -> coalesced runs into global bucket regions
    for (int i = tid; i < cnt; i += 256) {
        int b = bidl[i];
        staged[(size_t)b * BCAP + gbase[b] + (i - bstart[b])] = words[i];
    }
}

// tiny exclusive scan over NB bucket counts (one wave)
__global__ void scan_nb_k(const int* __restrict__ bcur, int* __restrict__ ebase, int NB) {
    int lane = threadIdx.x;  // 64 threads
    int CH = (NB + 63) / 64;
    int b0 = lane * CH;
    int v[8]; int s = 0;
#pragma unroll 8
    for (int k = 0; k < CH; k++) { int b = b0 + k; int t = (b < NB) ? bcur[b] : 0; if (k < 8) v[k] = t; s += t; }
    int orig = s;
    for (int off = 1; off < 64; off <<= 1) {
        int t = __shfl_up(s, off, 64);
        if (lane >= off) s += t;
    }
    int run = s - orig;  // exclusive
    for (int k = 0; k < CH; k++) { int b = b0 + k; if (b < NB) { ebase[b] = run; run += v[k]; } }
    if (lane == 63) ebase[NB] = run;
}

// Pass 2: per-bucket node-level counting sort -> offs + cols (coalesced writes).
__global__ __launch_bounds__(256) void buildcsr_k(
        const unsigned* __restrict__ staged, const int* __restrict__ bcur,
        const int* __restrict__ ebase, int* __restrict__ offs, int* __restrict__ cols,
        int N, int NB) {
    __shared__ int h[256], hs[256], curl[256];
    __shared__ int colsl[BCAP];
    int b = blockIdx.x, tid = threadIdx.x;
    int n0 = b << 8;
    int ecnt = bcur[b];
    int base_g = ebase[b];
    const unsigned* sb = staged + (size_t)b * BCAP;

    h[tid] = 0;
    __syncthreads();
    for (int i = tid; i < ecnt; i += 256) atomicAdd(&h[sb[i] >> 17], 1);
    __syncthreads();
    int val = h[tid];
    hs[tid] = val; __syncthreads();
    for (int off = 1; off < 256; off <<= 1) {
        int t = (tid >= off) ? hs[tid - off] : 0;
        __syncthreads();
        hs[tid] += t;
        __syncthreads();
    }
    int excl = hs[tid] - val;
    curl[tid] = excl;
    if (n0 + tid < N) offs[n0 + tid] = base_g + excl;
    if (b == NB - 1 && tid == 0) offs[N] = base_g + ecnt;
    __syncthreads();
    for (int i = tid; i < ecnt; i += 256) {
        unsigned w = sb[i];
        int p = atomicAdd(&curl[w >> 17], 1);
        colsl[p] = (int)(w & 0x1FFFFu);
    }
    __syncthreads();
    for (int i = tid; i < ecnt; i += 256) cols[base_g + i] = colsl[i];
}

// ---------------- W pre-pack into MFMA B-fragment order (hi|lo) ----------------
__global__ void prep_w_k(const float* __restrict__ W, short* __restrict__ Bfs,
                         int K, int N, int NT, int total) {
    int idx = blockIdx.x * blockDim.x + threadIdx.x;
    if (idx >= total) return;  // total = (K/32)*NT*64
    int lane = idx & 63;
    int t = idx >> 6;
    int ntile = t % NT, kstep = t / NT;
    int quad = lane >> 4, nl = lane & 15;
    int n = ntile * 16 + nl;
    bf16_t* dst = (bf16_t*)Bfs + (size_t)idx * 16;
#pragma unroll
    for (int j = 0; j < 8; j++) {
        int k = kstep * 32 + quad * 8 + j;
        float v = W[k * N + n];
        bf16_t h = (bf16_t)v;
        bf16_t l = (bf16_t)(v - (float)h);
        dst[j] = h;
        dst[8 + j] = l;
    }
}

// W3 pre-pack: K=64, Nc cols zero-padded to 16 (single N-tile).
__global__ void prep_w3_k(const float* __restrict__ W, short* __restrict__ Bfs, int Nc) {
    int idx = blockIdx.x * blockDim.x + threadIdx.x;  // 128 = 2 ks * 64 lanes
    if (idx >= 128) return;
    int lane = idx & 63, ks = idx >> 6;
    int quad = lane >> 4, nl = lane & 15;
    bf16_t* dst = (bf16_t*)Bfs + (size_t)idx * 16;
#pragma unroll
    for (int j = 0; j < 8; j++) {
        int k = ks * 32 + quad * 8 + j;
        float v = (nl < Nc) ? W[k * Nc + nl] : 0.f;
        bf16_t h = (bf16_t)v;
        bf16_t l = (bf16_t)(v - (float)h);
        dst[j] = h;
        dst[8 + j] = l;
    }
}

// ---------------- split-bf16 MFMA GEMM, fused alpha epilogue ----------------
// R10 structure: stage the FULL BM x K panel (split hi/lo for f32 A) with
// 16 independent 16B loads per thread -> one __syncthreads -> barrier-free
// fully-unrolled MFMA phase. NWM=1: waves own disjoint B tiles.
// Writes Cb (bf16) + alpha_src/alpha_dst [M, N/CHEAD] (f32, exact from acc).
template <int BM, int WMT, int WNT, int NWM, bool ABF16, int CHEAD, int K>
__global__ __launch_bounds__(256, 2) void mfma_gemm_k(
        const void* __restrict__ Av, const short* __restrict__ Bfs,
        unsigned short* __restrict__ Cb,
        const float* __restrict__ a_s, const float* __restrict__ a_d,
        float* __restrict__ out_as, float* __restrict__ out_ad,
        int M, int N, int NT) {
    constexpr int NWN = 4 / NWM;
    constexpr int BN = 16 * WNT * NWN;
    constexpr int KP = K + 8;  // +8 bf16: keeps b128 reads at free 2-way banks
    __shared__ __align__(16) bf16_t As_hi[BM * KP];
    __shared__ __align__(16) bf16_t As_lo[ABF16 ? 16 : BM * KP];
    const bf16_t* Bf = (const bf16_t*)Bfs;

    int tid = threadIdx.x;
    int wave = tid >> 6, lane = tid & 63;
    int quad = lane >> 4, l16 = lane & 15;
    int wm = wave % NWM, wn = wave / NWM;
    int row0 = blockIdx.x * BM;
    int ntile0 = blockIdx.y * (BN / 16) + wn * WNT;

    // ---- stage whole panel: all loads issued before any conversion ----
    if constexpr (!ABF16) {
        constexpr int CHUNKS = BM * K * 4 / (16 * 256);  // 16B chunks per thread
        const float* A = (const float*)Av;
        f32x4 tmp[CHUNKS];
#pragma unroll
        for (int c = 0; c < CHUNKS; c++) {
            int ci = c * 256 + tid;
            int fi = ci * 4;
            int row = fi / K, k = fi % K;
            int grow = row0 + row;
            tmp[c] = (f32x4){0.f, 0.f, 0.f, 0.f};
            if (grow < M) tmp[c] = *(const f32x4*)(A + (size_t)grow * K + k);
        }
#pragma unroll
        for (int c = 0; c < CHUNKS; c++) {
            int ci = c * 256 + tid;
            int fi = ci * 4;
            int row = fi / K, k = fi % K;
            bf16x4 h, l;
#pragma unroll
            for (int j = 0; j < 4; j++) {
                bf16_t hh = (bf16_t)tmp[c][j];
                h[j] = hh;
                l[j] = (bf16_t)(tmp[c][j] - (float)hh);
            }
            *(bf16x4*)&As_hi[row * KP + k] = h;
            *(bf16x4*)&As_lo[row * KP + k] = l;
        }
    } else {
        constexpr int CHUNKS = BM * K * 2 / (16 * 256);
        const unsigned short* A = (const unsigned short*)Av;
        u16x8 tmp[CHUNKS];
#pragma unroll
        for (int c = 0; c < CHUNKS; c++) {
            int ci = c * 256 + tid;
            int ei = ci * 8;
            int row = ei / K, k = ei % K;
            int grow = row0 + row;
            tmp[c] = (u16x8){0, 0, 0, 0, 0, 0, 0, 0};
            if (grow < M) tmp[c] = *(const u16x8*)(A + (size_t)grow * K + k);
        }
#pragma unroll
        for (int c = 0; c < CHUNKS; c++) {
            int ci = c * 256 + tid;
            int ei = ci * 8;
            int row = ei / K, k = ei % K;
            *(u16x8*)&As_hi[row * KP + k] = tmp[c];
        }
    }
    __syncthreads();

    // ---- barrier-free compute over all K steps ----
    f32x4 acc[WMT][WNT];
#pragma unroll
    for (int i = 0; i < WMT; i++)
#pragma unroll
        for (int j = 0; j < WNT; j++) acc[i][j] = (f32x4){0.f, 0.f, 0.f, 0.f};

#pragma unroll
    for (int ks = 0; ks < K / 32; ks++) {
        bf16x8 ah[WMT], al[WMT];
#pragma unroll
        for (int i = 0; i < WMT; i++) {
            int rowl = wm * (WMT * 16) + i * 16 + l16;
            ah[i] = *(const bf16x8*)&As_hi[rowl * KP + ks * 32 + quad * 8];
            if (!ABF16) al[i] = *(const bf16x8*)&As_lo[rowl * KP + ks * 32 + quad * 8];
        }
        bf16x8 bh[WNT], bl[WNT];
#pragma unroll
        for (int j = 0; j < WNT; j++) {
            size_t base = ((size_t)(ks * NT + ntile0 + j) * 64 + lane) * 16;
            bh[j] = *(const bf16x8*)&Bf[base];
            bl[j] = *(const bf16x8*)&Bf[base + 8];
        }
#pragma unroll
        for (int i = 0; i < WMT; i++)
#pragma unroll
            for (int j = 0; j < WNT; j++) {
                acc[i][j] = __builtin_amdgcn_mfma_f32_16x16x32_bf16(ah[i], bh[j], acc[i][j], 0, 0, 0);
                if (!ABF16)
                    acc[i][j] = __builtin_amdgcn_mfma_f32_16x16x32_bf16(al[i], bh[j], acc[i][j], 0, 0, 0);
                acc[i][j] = __builtin_amdgcn_mfma_f32_16x16x32_bf16(ah[i], bl[j], acc[i][j], 0, 0, 0);
            }
    }

    // bf16 C store: D[row = quad*4 + r][col = l16] per 16x16 tile
#pragma unroll
    for (int i = 0; i < WMT; i++) {
        int rbase = row0 + wm * (WMT * 16) + i * 16 + quad * 4;
#pragma unroll
        for (int j = 0; j < WNT; j++) {
            int gcol = (ntile0 + j) * 16 + l16;
#pragma unroll
            for (int r2 = 0; r2 < 4; r2++) {
                int grow = rbase + r2;
                if (grow < M) Cb[(size_t)grow * N + gcol] = bf_bits(acc[i][j][r2]);
            }
        }
    }

    // fused alpha: per tile j, coef = a_flat[gcol]; reduce over CHEAD-lane groups
    const int Hh = N / CHEAD;
#pragma unroll
    for (int j = 0; j < WNT; j++) {
        int gcol = (ntile0 + j) * 16 + l16;
        float cs = a_s[gcol], cd = a_d[gcol];
#pragma unroll
        for (int i = 0; i < WMT; i++) {
            float ps[4], pd[4];
#pragma unroll
            for (int r2 = 0; r2 < 4; r2++) {
                ps[r2] = acc[i][j][r2] * cs;
                pd[r2] = acc[i][j][r2] * cd;
            }
#pragma unroll
            for (int off = 1; off < CHEAD; off <<= 1) {
#pragma unroll
                for (int r2 = 0; r2 < 4; r2++) {
                    ps[r2] += __shfl_xor(ps[r2], off, 64);
                    pd[r2] += __shfl_xor(pd[r2], off, 64);
                }
            }
            if ((l16 & (CHEAD - 1)) == 0) {
                int hd = gcol / CHEAD;
                int rb = row0 + wm * (WMT * 16) + i * 16 + quad * 4;
#pragma unroll
                for (int r2 = 0; r2 < 4; r2++) {
                    int grow = rb + r2;
                    if (grow < M) {
                        out_as[(size_t)grow * Hh + hd] = ps[r2];
                        out_ad[(size_t)grow * Hh + hd] = pd[r2];
                    }
                }
            }
        }
    }
}

// ---------------- layer-3 MFMA GEMM + fused alpha (K=64, N=10 pad 16) ----------------
// A bf16 direct from global (coalesced bf16x8 per lane); 4 MFMAs per wave;
// writes bf16 C (stride 10) and alpha3 via 16-lane in-register reduce.
__global__ __launch_bounds__(256) void gemm3_k(
        const unsigned short* __restrict__ Ab, const short* __restrict__ Bfs,
        unsigned short* __restrict__ Cb,
        const float* __restrict__ a_s, const float* __restrict__ a_d,
        float* __restrict__ out_as, float* __restrict__ out_ad, int M) {
    const bf16_t* Bf = (const bf16_t*)Bfs;
    int tid = threadIdx.x;
    int wave = tid >> 6, lane = tid & 63;
    int quad = lane >> 4, l16 = lane & 15;
    int grow0 = blockIdx.x * 64 + wave * 16;

    bf16x8 bh[2], bl[2];
#pragma unroll
    for (int ks = 0; ks < 2; ks++) {
        size_t base = (size_t)(ks * 64 + lane) * 16;
        bh[ks] = *(const bf16x8*)&Bf[base];
        bl[ks] = *(const bf16x8*)&Bf[base + 8];
    }

    int arow = grow0 + l16; if (arow >= M) arow = M - 1;  // clamp; outputs guarded
    f32x4 acc = (f32x4){0.f, 0.f, 0.f, 0.f};
#pragma unroll
    for (int ks = 0; ks < 2; ks++) {
        bf16x8 a = *(const bf16x8*)(Ab + (size_t)arow * 64 + ks * 32 + quad * 8);
        acc = __builtin_amdgcn_mfma_f32_16x16x32_bf16(a, bh[ks], acc, 0, 0, 0);
        acc = __builtin_amdgcn_mfma_f32_16x16x32_bf16(a, bl[ks], acc, 0, 0, 0);
    }

    bool colv = l16 < 10;
    float cs = colv ? a_s[l16] : 0.f;
    float cd = colv ? a_d[l16] : 0.f;
    float ps[4], pd[4];
#pragma unroll
    for (int r = 0; r < 4; r++) { ps[r] = acc[r] * cs; pd[r] = acc[r] * cd; }
#pragma unroll
    for (int off = 1; off < 16; off <<= 1) {
#pragma unroll
        for (int r = 0; r < 4; r++) {
            ps[r] += __shfl_xor(ps[r], off, 64);
            pd[r] += __shfl_xor(pd[r], off, 64);
        }
    }
#pragma unroll
    for (int r = 0; r < 4; r++) {
        int grow = grow0 + quad * 4 + r;
        if (grow < M) {
            if (colv) Cb[(size_t)grow * 10 + l16] = bf_bits(acc[r]);
            if (l16 == 0) { out_as[grow] = ps[r]; out_ad[grow] = pd[r]; }
        }
    }
}

// ---------------- single-pass batched aggregation, H=8 C=16 (layer 1) ----------------
// AT the random-gather throughput wall (~5 TB/s line-level): scheduling-
// invariant 86 us across interleave/two-pass/batch variants. Keep.
template <bool DO_ELU>
__global__ void agg16_k(const unsigned short* __restrict__ xpb,
                        const float* __restrict__ asrc, const float* __restrict__ adst,
                        const int* __restrict__ offs, const int* __restrict__ cols,
                        const float* __restrict__ bias, unsigned short* __restrict__ outb,
                        int N) {
    int gtid = blockIdx.x * blockDim.x + threadIdx.x;
    int n = gtid >> 6;
    if (n >= N) return;
    int lane = threadIdx.x & 63;
    int j = lane >> 3, h = lane & 7;
    const int jb = j << 2;  // bpermute byte addr of (j=0, h=j) lane
    int start = offs[n], end = offs[n + 1];
    const unsigned* xp32 = (const unsigned*)xpb;

    // independent loads first
    unsigned uself = xp32[(size_t)n * 64 + lane];
    float ad_l = adst[n * 8 + h];
    float vs = asrc[n * 8 + h] + ad_l;
    vs = LEAKY(vs);

    // weight-role state (head h): seeded with implicit self-loop
    float m_w = vs;
    float s = (j == 0) ? 1.f : 0.f;
    // feature-role state (head j): acc = self row (weight exp(vs-vs)=1)
    float m_f = bperm_f(jb, vs);
    float a0 = __uint_as_float(uself << 16);
    float a1 = __uint_as_float(uself & 0xffff0000u);

    for (int c0 = start; c0 < end; c0 += 16) {
        int e0 = c0 + j, e1 = c0 + 8 + j;
        bool ok0 = e0 < end, ok1 = e1 < end;
        int sl0 = ok0 ? cols[e0] : 0;
        int sl1 = ok1 ? cols[e1] : 0;
        // ---- issue all 16 row gathers (dep only on cols) ----
        unsigned u[16];
#pragma unroll
        for (int t = 0; t < 8; t++) {
            int srcj = __builtin_amdgcn_readlane(sl0, t * 8);
            u[t] = xp32[(size_t)srcj * 64 + lane];
        }
#pragma unroll
        for (int t = 0; t < 8; t++) {
            int srcj = __builtin_amdgcn_readlane(sl1, t * 8);
            u[8 + t] = xp32[(size_t)srcj * 64 + lane];
        }
        // ---- weight math while gathers are in flight ----
        float v0 = -1e30f, v1 = -1e30f;
        if (ok0) { v0 = asrc[sl0 * 8 + h] + ad_l; v0 = LEAKY(v0); }
        if (ok1) { v1 = asrc[sl1 * 8 + h] + ad_l; v1 = LEAKY(v1); }
        float cm = fmaxf(v0, v1);
        cm = fmaxf(cm, __shfl_xor(cm, 8, 64));
        cm = fmaxf(cm, __shfl_xor(cm, 16, 64));
        cm = fmaxf(cm, __shfl_xor(cm, 32, 64));
        float mw_new = fmaxf(m_w, cm);
        float w0 = __expf(v0 - mw_new);  // 0 for invalid slots
        float w1 = __expf(v1 - mw_new);
        s = s * __expf(m_w - mw_new) + w0 + w1;
        m_w = mw_new;
        // feature-role rescale (head j)
        float cmF = bperm_f(jb, cm);
        float mf_new = fmaxf(m_f, cmF);
        float scF = __expf(m_f - mf_new);
        m_f = mf_new;
        a0 *= scF; a1 *= scF;
        float wl[16];
#pragma unroll
        for (int t = 0; t < 8; t++) wl[t] = bperm_f(jb + t * 32, w0);
#pragma unroll
        for (int t = 0; t < 8; t++) wl[8 + t] = bperm_f(jb + t * 32, w1);
        // ---- consume ----
#pragma unroll
        for (int t = 0; t < 16; t++) {
            a0 = fmaf(wl[t], __uint_as_float(u[t] << 16), a0);
            a1 = fmaf(wl[t], __uint_as_float(u[t] & 0xffff0000u), a1);
        }
    }
    // finalize: total s per head, then normalize
    s += __shfl_xor(s, 8, 64);
    s += __shfl_xor(s, 16, 64);
    s += __shfl_xor(s, 32, 64);
    float rs = 1.f / (s + 1e-16f);
    float rsF = bperm_f(jb, rs);
    float o0 = a0 * rsF + bias[2 * lane];
    float o1 = a1 * rsF + bias[2 * lane + 1];
    if (DO_ELU) {
        o0 = o0 > 0.f ? o0 : __expf(o0) - 1.f;
        o1 = o1 > 0.f ? o1 : __expf(o1) - 1.f;
    }
    unsigned packed = (unsigned)bf_bits(o0) | ((unsigned)bf_bits(o1) << 16);
    ((unsigned*)outb)[(size_t)n * 64 + lane] = packed;  // row = 128 shorts = 64 uints
}

// ---------------- single-pass batched aggregation, H=8 C=8 (layer 2) ----------------
template <bool DO_ELU>
__global__ void agg8c8_k(const unsigned short* __restrict__ xpb,
                         const float* __restrict__ asrc, const float* __restrict__ adst,
                         const int* __restrict__ offs, const int* __restrict__ cols,
                         const float* __restrict__ bias, unsigned short* __restrict__ outb,
                         int N) {
    int gtid = blockIdx.x * blockDim.x + threadIdx.x;
    int n = gtid >> 6;
    if (n >= N) return;
    int lane = threadIdx.x & 63;
    int j = lane >> 3, h = lane & 7;
    int start = offs[n], end = offs[n + 1];
    const unsigned* xp32 = (const unsigned*)xpb;

    int fp = lane & 31;      // feature pair {2fp, 2fp+1}
    int hF = fp >> 2;        // feature-role head
    int half = lane >> 5;
    int sbase = half * 32;

    float ad_l = adst[n * 8 + h];
    float vs = asrc[n * 8 + h] + ad_l;
    vs = LEAKY(vs);

    float m_w = vs;
    float s = (j == 0) ? 1.f : 0.f;
    float m_f = bperm_f(hF * 4, vs);
    float a0 = 0.f, a1 = 0.f;
    if (half == 0) {  // self contribution in half 0 only
        unsigned u = xp32[(size_t)n * 32 + fp];
        a0 = __uint_as_float(u << 16);
        a1 = __uint_as_float(u & 0xffff0000u);
    }

    for (int c0 = start; c0 < end; c0 += 16) {
        int e0 = c0 + j, e1 = c0 + 8 + j;
        bool ok0 = e0 < end, ok1 = e1 < end;
        int sl0 = ok0 ? cols[e0] : 0;
        int sl1 = ok1 ? cols[e1] : 0;
        // ---- issue all 8 row gathers per lane-half (dep only on cols) ----
        int sv[8];
#pragma unroll
        for (int t = 0; t < 4; t++) sv[t] = __builtin_amdgcn_ds_bpermute(sbase + t * 64, sl0);
#pragma unroll
        for (int t = 0; t < 4; t++) sv[4 + t] = __builtin_amdgcn_ds_bpermute(sbase + t * 64, sl1);
        unsigned u[8];
#pragma unroll
        for (int t = 0; t < 8; t++) u[t] = xp32[(size_t)sv[t] * 32 + fp];
        // ---- weight math while gathers are in flight ----
        float v0 = -1e30f, v1 = -1e30f;
        if (ok0) { v0 = asrc[sl0 * 8 + h] + ad_l; v0 = LEAKY(v0); }
        if (ok1) { v1 = asrc[sl1 * 8 + h] + ad_l; v1 = LEAKY(v1); }
        float cm = fmaxf(v0, v1);
        cm = fmaxf(cm, __shfl_xor(cm, 8, 64));
        cm = fmaxf(cm, __shfl_xor(cm, 16, 64));
        cm = fmaxf(cm, __shfl_xor(cm, 32, 64));
        float mw_new = fmaxf(m_w, cm);
        float w0 = __expf(v0 - mw_new);
        float w1 = __expf(v1 - mw_new);
        s = s * __expf(m_w - mw_new) + w0 + w1;
        m_w = mw_new;
        float cmF = bperm_f(hF * 4, cm);
        float mf_new = fmaxf(m_f, cmF);
        float scF = __expf(m_f - mf_new);
        m_f = mf_new;
        a0 *= scF; a1 *= scF;
        float wl[8];
#pragma unroll
        for (int t = 0; t < 4; t++) wl[t] = bperm_f(sbase + hF * 4 + t * 64, w0);
#pragma unroll
        for (int t = 0; t < 4; t++) wl[4 + t] = bperm_f(sbase + hF * 4 + t * 64, w1);
        // ---- consume ----
#pragma unroll
        for (int t = 0; t < 8; t++) {
            a0 = fmaf(wl[t], __uint_as_float(u[t] << 16), a0);
            a1 = fmaf(wl[t], __uint_as_float(u[t] & 0xffff0000u), a1);
        }
    }
    s += __shfl_xor(s, 8, 64);
    s += __shfl_xor(s, 16, 64);
    s += __shfl_xor(s, 32, 64);
    float rs = 1.f / (s + 1e-16f);
    float rsF = bperm_f(hF * 4, rs);
    // combine halves (same m_f in both halves), then normalize
    a0 += __shfl_xor(a0, 32, 64);
    a1 += __shfl_xor(a1, 32, 64);
    if (half == 0) {
        float o0 = a0 * rsF + bias[2 * fp];
        float o1 = a1 * rsF + bias[2 * fp + 1];
        if (DO_ELU) {
            o0 = o0 > 0.f ? o0 : __expf(o0) - 1.f;
            o1 = o1 > 0.f ? o1 : __expf(o1) - 1.f;
        }
        unsigned packed = (unsigned)bf_bits(o0) | ((unsigned)bf_bits(o1) << 16);
        ((unsigned*)outb)[(size_t)n * 32 + fp] = packed;  // row = 64 shorts = 32 uints
    }
}

// ---------------- aggregation H=1 C=10 + fused log_softmax (layer 3) ----------------
__global__ void agg1h_k(const unsigned short* __restrict__ xpb,
                        const float* __restrict__ asrc, const float* __restrict__ adst,
                        const int* __restrict__ offs, const int* __restrict__ cols,
                        const float* __restrict__ bias, float* __restrict__ out, int N) {
    int gtid = blockIdx.x * blockDim.x + threadIdx.x;
    int n = gtid >> 6;
    if (n >= N) return;
    int lane = threadIdx.x & 63;
    int start = offs[n], end = offs[n + 1];
    float ad = adst[n];
    float vs = asrc[n] + ad;  // implicit self-loop
    vs = LEAKY(vs);

    float m, s;
    if (lane == 0) { m = vs; s = 1.f; } else { m = -1e30f; s = 0.f; }
    for (int e = start + lane; e < end; e += 64) {
        float v = asrc[cols[e]] + ad;
        v = LEAKY(v);
        float mo = fmaxf(m, v);
        s = s * __expf(m - mo) + __expf(v - mo);
        m = mo;
    }
#pragma unroll
    for (int off = 1; off <= 32; off <<= 1) {
        float mo = __shfl_xor(m, off, 64);
        float so = __shfl_xor(s, off, 64);
        float mn = fmaxf(m, mo);
        s = s * __expf(m - mn) + so * __expf(mo - mn);
        m = mn;
    }
    float rs = 1.f / (s + 1e-16f);
    float wself = __expf(vs - m) * rs;

    int j = lane / 10, c = lane - j * 10;
    float acc = 0.f;
    if (j == 0) acc = wself * bf_to_f(xpb[(size_t)n * 10 + c]);  // self term
    for (int c0 = start; c0 < end; c0 += 6) {
        int e = c0 + j;
        if (j < 6 && e < end) {
            int src = cols[e];
            float v = asrc[src] + ad;
            v = LEAKY(v);
            float w = __expf(v - m) * rs;
            acc = fmaf(w, bf_to_f(xpb[(size_t)src * 10 + c]), acc);
        }
    }
    float tot = acc;
#pragma unroll
    for (int k = 1; k < 6; k++) tot += __shfl(acc, lane + 10 * k, 64);

    // fused log_softmax over the 10 classes (valid in lanes 0-9)
    float z = tot + bias[lane < 10 ? lane : 0];
    float mx = -1e30f;
#pragma unroll
    for (int k = 0; k < 10; k++) mx = fmaxf(mx, __shfl(z, k, 64));
    float se = 0.f;
#pragma unroll
    for (int k = 0; k < 10; k++) se += __expf(__shfl(z, k, 64) - mx);
    if (lane < 10) out[(size_t)n * 10 + lane] = z - (__logf(se) + mx);
}

// ---------------- launch ----------------

static inline size_t alignup(size_t x) { return (x + 255) & ~(size_t)255; }

extern "C" void kernel_launch(void* const* d_in, const int* in_sizes, int n_in,
                              void* d_out, int out_size, void* d_ws, size_t ws_size,
                              hipStream_t stream) {
    const float* x   = (const float*)d_in[0];
    const int*   ei  = (const int*)d_in[1];
    const float* W1  = (const float*)d_in[2];
    const float* a1s = (const float*)d_in[3];
    const float* a1d = (const float*)d_in[4];
    const float* b1  = (const float*)d_in[5];
    const float* W2  = (const float*)d_in[6];
    const float* a2s = (const float*)d_in[7];
    const float* a2d = (const float*)d_in[8];
    const float* b2  = (const float*)d_in[9];
    const float* W3  = (const float*)d_in[10];
    const float* a3s = (const float*)d_in[11];
    const float* a3d = (const float*)d_in[12];
    const float* b3  = (const float*)d_in[13];
    float* out = (float*)d_out;

    const int N = in_sizes[0] / 256;
    const int E = in_sizes[1] / 2;
    const int* src = ei;
    const int* dst = ei + E;
    const int NB = (N + 255) >> 8;  // 391 for N=100000 (<= NB_MAX)

    char* p = (char*)d_ws;
    int* offs    = (int*)p; p += alignup(sizeof(int) * (size_t)(N + 1));
    int* bcur    = (int*)p; p += alignup(sizeof(int) * (size_t)(NB_MAX + 1));
    int* ebase   = (int*)p; p += alignup(sizeof(int) * (size_t)(NB_MAX + 1));
    int* cols    = (int*)p; p += alignup(sizeof(int) * (size_t)E);
    unsigned short* xpb   = (unsigned short*)p; p += alignup(2 * (size_t)N * 128);
    unsigned short* hbufb = (unsigned short*)p; p += alignup(2 * (size_t)N * 128);
    float* xp    = (float*)p; p += alignup(sizeof(float) * (size_t)N * 128);
    float* as_   = (float*)p; p += alignup(sizeof(float) * (size_t)N * 8);
    float* ad_   = (float*)p; p += alignup(sizeof(float) * (size_t)N * 8);
    short* Bf1   = (short*)p; p += alignup(sizeof(short) * 8 * 8 * 64 * 16);  // K=256,N=128
    short* Bf2   = (short*)p; p += alignup(sizeof(short) * 4 * 4 * 64 * 16);  // K=128,N=64
    short* Bf3   = (short*)p; p += alignup(sizeof(short) * 2 * 1 * 64 * 16);  // K=64,N=16(pad)
    // staged bucket regions alias xp: CSR build finishes before anything writes xp
    // (xp itself is otherwise dead since R13's fused gemm3).
    unsigned* staged = (unsigned*)xp;  // NB * BCAP * 4B = 8 MB << 51.2 MB

    const int TB = 256;

    // CSR build: bucketed counting sort (self-loops implicit in agg)
    hipMemsetAsync(bcur, 0, sizeof(int) * (size_t)(NB + 1), stream);
    partition_k<<<(E + 4095) / 4096, 256, 0, stream>>>(src, dst, E, NB, bcur, staged);
    scan_nb_k<<<1, 64, 0, stream>>>(bcur, ebase, NB);
    buildcsr_k<<<NB, 256, 0, stream>>>(staged, bcur, ebase, offs, cols, N, NB);

    // W pre-pack (fragment order, hi|lo)
    prep_w_k<<<(4096 + TB - 1) / TB, TB, 0, stream>>>(W1, Bf1, 256, 128, 8, 4096);
    prep_w_k<<<(1024 + TB - 1) / TB, TB, 0, stream>>>(W2, Bf2, 128, 64, 4, 1024);
    prep_w3_k<<<1, 128, 0, stream>>>(W3, Bf3, 10);

    // ---- layer 1: 256 -> 128 (H=8, C=16), ELU
    mfma_gemm_k<64, 4, 2, 1, false, 16, 256><<<dim3((N + 63) / 64, 1), 256, 0, stream>>>(
        x, Bf1, xpb, a1s, a1d, as_, ad_, N, 128, 8);
    agg16_k<true><<<(N * 64 + TB - 1) / TB, TB, 0, stream>>>(
        xpb, as_, ad_, offs, cols, b1, hbufb, N);

    // ---- layer 2: 128 -> 64 (H=8, C=8), ELU  (A is bf16 agg output)
    mfma_gemm_k<64, 4, 1, 1, true, 8, 128><<<dim3((N + 63) / 64, 1), 256, 0, stream>>>(
        hbufb, Bf2, xpb, a2s, a2d, as_, ad_, N, 64, 4);
    agg8c8_k<true><<<(N * 64 + TB - 1) / TB, TB, 0, stream>>>(
        xpb, as_, ad_, offs, cols, b2, hbufb, N);

    // ---- layer 3: 64 -> 10 (H=1, C=10) MFMA + fused alpha, then agg + log_softmax
    gemm3_k<<<(N + 63) / 64, 256, 0, stream>>>(
        hbufb, Bf3, xpb, a3s, a3d, as_, ad_, N);
    agg1h_k<<<(N * 64 + TB - 1) / TB, TB, 0, stream>>>(
        xpb, as_, ad_, offs, cols, b3, out, N);
}

// Round 5
// 477.213 us; speedup vs baseline: 1.1316x; 1.0679x over previous
//
#include <hip/hip_runtime.h>
#include <hip/hip_bf16.h>
#include <math.h>

// ---------------------------------------------------------------------------
// GAT 3-layer forward on MI355X.
//   1. Dest-CSR via 2-pass bucketed counting sort. Self-loops implicit.
//      R14: partition_k scan wave-parallel; buildcsr computes its own base
//      (scan_nb_k launch dropped); prep_w fused to one launch.
//   2. Layers 1-2: split-bf16 MFMA GEMM, whole-K-panel staging (R10).
//      R14: epilogue v2 — acc -> LDS f32 C-tile, then (a) alpha via
//      contiguous LDS reads + serial fma (2 outputs/thread, wave-uniform
//      a_s -> scalar loads), (b) coalesced packed-bf16 C stores. Replaces
//      the 256-shfl_xor/thread reduction chain + 32 strided scalar stores
//      (suspected latency binder: L1 GEMM reads 102 MB L3-resident in
//      ~85 us = 1.2 TB/s, MFMA 8 us -> serialization, not BW/compute).
//   3. Layer 3 = gemm3_k MFMA + fused alpha (R13).
//   4. Aggregation: single-pass online-softmax, batched gathers (R12).
//      agg16 AT the random-gather wall (~86 us, scheduling-invariant).
// ---------------------------------------------------------------------------

#define LEAKY(v) ((v) > 0.f ? (v) : 0.2f * (v))

typedef __bf16 bf16_t;
typedef __bf16 bf16x8 __attribute__((ext_vector_type(8)));
typedef __bf16 bf16x4 __attribute__((ext_vector_type(4)));
typedef float f32x4 __attribute__((ext_vector_type(4)));
typedef unsigned short u16x8 __attribute__((ext_vector_type(8)));

static __device__ __forceinline__ unsigned short bf_bits(float f) {
    bf16_t b = (bf16_t)f;
    return __builtin_bit_cast(unsigned short, b);
}
static __device__ __forceinline__ float bf_to_f(unsigned short u) {
    return __uint_as_float(((unsigned int)u) << 16);
}
static __device__ __forceinline__ float bperm_f(int byteaddr, float v) {
    return __uint_as_float((unsigned)__builtin_amdgcn_ds_bpermute(byteaddr, (int)__float_as_uint(v)));
}

// ---------------- CSR build: 2-pass bucket sort ----------------
constexpr int NB_MAX = 400;
constexpr int BCAP = 5120;  // capacity per bucket region; mean load 4096

// Pass 1: partition edges into bucket regions with block-local grouping.
__global__ __launch_bounds__(256) void partition_k(
        const int* __restrict__ src, const int* __restrict__ dst, int E, int NB,
        int* __restrict__ bcur, unsigned* __restrict__ staged) {
    __shared__ int hist[NB_MAX];
    __shared__ int bstart[NB_MAX + 1];
    __shared__ int cur[NB_MAX];
    __shared__ int gbase[NB_MAX];
    __shared__ unsigned words[4096];
    __shared__ unsigned short bidl[4096];
    int tid = threadIdx.x;
    int e0 = blockIdx.x * 4096;
    int cnt = E - e0; if (cnt > 4096) cnt = 4096;
    if (cnt <= 0) return;

    for (int b = tid; b < NB; b += 256) hist[b] = 0;
    __syncthreads();
    for (int i = tid; i < cnt; i += 256) atomicAdd(&hist[dst[e0 + i] >> 8], 1);
    __syncthreads();
    // R14: wave-0 parallel exclusive scan over NB entries (was serial tid0)
    if (tid < 64) {
        int lane = tid;
        int run = 0;
        for (int b0 = 0; b0 < NB; b0 += 64) {
            int bb = b0 + lane;
            int v = (bb < NB) ? hist[bb] : 0;
            int sc = v;
            for (int off = 1; off < 64; off <<= 1) {
                int t2 = __shfl_up(sc, off, 64);
                if (lane >= off) sc += t2;
            }
            if (bb < NB) bstart[bb] = run + sc - v;
            run += __shfl(sc, 63, 64);
        }
        if (lane == 0) bstart[NB] = run;
    }
    __syncthreads();
    for (int b = tid; b < NB; b += 256) {
        cur[b] = bstart[b];
        gbase[b] = hist[b] ? atomicAdd(&bcur[b], hist[b]) : 0;
    }
    __syncthreads();
    // group into LDS by bucket, remember bucket id per slot
    for (int i = tid; i < cnt; i += 256) {
        int s = src[e0 + i], d = dst[e0 + i];
        int b = d >> 8;
        unsigned w = (unsigned)s | ((unsigned)(d & 255) << 17);
        int p = atomicAdd(&cur[b], 1);
        words[p] = w;
        bidl[p] = (unsigned short)b;
    }
    __syncthreads();
    // linear sweep -> coalesced runs into global bucket regions
    for (int i = tid; i < cnt; i += 256) {
        int b = bidl[i];
        staged[(size_t)b * BCAP + gbase[b] + (i - bstart[b])] = words[i];
    }
}

// Pass 2: per-bucket node-level counting sort -> offs + cols.
// R14: computes its own base_g = sum(bcur[0..b)) — scan_nb_k launch dropped.
__global__ __launch_bounds__(256) void buildcsr_k(
        const unsigned* __restrict__ staged, const int* __restrict__ bcur,
        int* __restrict__ offs, int* __restrict__ cols,
        int N, int NB) {
    __shared__ int h[256], hs[256], curl[256];
    __shared__ int colsl[BCAP];
    __shared__ int base_s;
    int b = blockIdx.x, tid = threadIdx.x;
    int n0 = b << 8;
    int ecnt = bcur[b];
    const unsigned* sb = staged + (size_t)b * BCAP;

    h[tid] = 0;
    if (tid < 64) {
        int acc2 = 0;
        for (int i = tid; i < b; i += 64) acc2 += bcur[i];
        for (int off = 1; off < 64; off <<= 1) acc2 += __shfl_xor(acc2, off, 64);
        if (tid == 0) base_s = acc2;
    }
    __syncthreads();
    int base_g = base_s;
    for (int i = tid; i < ecnt; i += 256) atomicAdd(&h[sb[i] >> 17], 1);
    __syncthreads();
    int val = h[tid];
    hs[tid] = val; __syncthreads();
    for (int off = 1; off < 256; off <<= 1) {
        int t = (tid >= off) ? hs[tid - off] : 0;
        __syncthreads();
        hs[tid] += t;
        __syncthreads();
    }
    int excl = hs[tid] - val;
    curl[tid] = excl;
    if (n0 + tid < N) offs[n0 + tid] = base_g + excl;
    if (b == NB - 1 && tid == 0) offs[N] = base_g + ecnt;
    __syncthreads();
    for (int i = tid; i < ecnt; i += 256) {
        unsigned w = sb[i];
        int p = atomicAdd(&curl[w >> 17], 1);
        colsl[p] = (int)(w & 0x1FFFFu);
    }
    __syncthreads();
    for (int i = tid; i < ecnt; i += 256) cols[base_g + i] = colsl[i];
}

// ---------------- W pre-pack (fused single launch) ----------------
static __device__ __forceinline__ void prep_w_dev(
        const float* __restrict__ W, short* __restrict__ Bfs,
        int K, int N, int NT, int idx) {
    int lane = idx & 63;
    int t = idx >> 6;
    int ntile = t % NT, kstep = t / NT;
    int quad = lane >> 4, nl = lane & 15;
    int n = ntile * 16 + nl;
    bf16_t* dst = (bf16_t*)Bfs + (size_t)idx * 16;
#pragma unroll
    for (int j = 0; j < 8; j++) {
        int k = kstep * 32 + quad * 8 + j;
        float v = W[k * N + n];
        bf16_t h = (bf16_t)v;
        bf16_t l = (bf16_t)(v - (float)h);
        dst[j] = h;
        dst[8 + j] = l;
    }
}
static __device__ __forceinline__ void prep_w3_dev(
        const float* __restrict__ W, short* __restrict__ Bfs, int Nc, int idx) {
    int lane = idx & 63, ks = idx >> 6;
    int quad = lane >> 4, nl = lane & 15;
    bf16_t* dst = (bf16_t*)Bfs + (size_t)idx * 16;
#pragma unroll
    for (int j = 0; j < 8; j++) {
        int k = ks * 32 + quad * 8 + j;
        float v = (nl < Nc) ? W[k * Nc + nl] : 0.f;
        bf16_t h = (bf16_t)v;
        bf16_t l = (bf16_t)(v - (float)h);
        dst[j] = h;
        dst[8 + j] = l;
    }
}
__global__ void prep_all_k(const float* __restrict__ W1, const float* __restrict__ W2,
                           const float* __restrict__ W3, short* __restrict__ Bf1,
                           short* __restrict__ Bf2, short* __restrict__ Bf3) {
    int idx = blockIdx.x * blockDim.x + threadIdx.x;
    if (idx < 4096) prep_w_dev(W1, Bf1, 256, 128, 8, idx);
    else if (idx < 5120) prep_w_dev(W2, Bf2, 128, 64, 4, idx - 4096);
    else if (idx < 5248) prep_w3_dev(W3, Bf3, 10, idx - 5120);
}

// ---------------- split-bf16 MFMA GEMM, fused alpha epilogue v2 ----------------
// Whole-panel staging (R10) + LDS-C-tile epilogue (R14).
template <int BM, int WMT, int WNT, int NWM, bool ABF16, int CHEAD, int K>
__global__ __launch_bounds__(256, 2) void mfma_gemm_k(
        const void* __restrict__ Av, const short* __restrict__ Bfs,
        unsigned short* __restrict__ Cb,
        const float* __restrict__ a_s, const float* __restrict__ a_d,
        float* __restrict__ out_as, float* __restrict__ out_ad,
        int M, int N, int NT) {
    constexpr int NWN = 4 / NWM;
    constexpr int BN = 16 * WNT * NWN;
    constexpr int KP = K + 8;   // +8 bf16: keeps b128 reads at free 2-way banks
    constexpr int BNP = BN + 2; // f32 C-tile pad
    constexpr size_t ASZ = (size_t)BM * KP * 2 * (ABF16 ? 1 : 2);
    constexpr size_t CSZ = (size_t)BM * BNP * 4;
    constexpr size_t SMEM = ASZ > CSZ ? ASZ : CSZ;
    __shared__ __align__(16) char smem[SMEM];
    bf16_t* As_hi = (bf16_t*)smem;
    bf16_t* As_lo = As_hi + (ABF16 ? 0 : (size_t)BM * KP);
    float* Ct = (float*)smem;
    const bf16_t* Bf = (const bf16_t*)Bfs;

    int tid = threadIdx.x;
    int wave = tid >> 6, lane = tid & 63;
    int quad = lane >> 4, l16 = lane & 15;
    int wm = wave % NWM, wn = wave / NWM;
    int row0 = blockIdx.x * BM;
    int ntile0 = blockIdx.y * (BN / 16) + wn * WNT;

    // ---- stage whole panel: all loads issued before any conversion ----
    if constexpr (!ABF16) {
        constexpr int CHUNKS = BM * K * 4 / (16 * 256);  // 16B chunks per thread
        const float* A = (const float*)Av;
        f32x4 tmp[CHUNKS];
#pragma unroll
        for (int c = 0; c < CHUNKS; c++) {
            int ci = c * 256 + tid;
            int fi = ci * 4;
            int row = fi / K, k = fi % K;
            int grow = row0 + row;
            tmp[c] = (f32x4){0.f, 0.f, 0.f, 0.f};
            if (grow < M) tmp[c] = *(const f32x4*)(A + (size_t)grow * K + k);
        }
#pragma unroll
        for (int c = 0; c < CHUNKS; c++) {
            int ci = c * 256 + tid;
            int fi = ci * 4;
            int row = fi / K, k = fi % K;
            bf16x4 h, l;
#pragma unroll
            for (int j = 0; j < 4; j++) {
                bf16_t hh = (bf16_t)tmp[c][j];
                h[j] = hh;
                l[j] = (bf16_t)(tmp[c][j] - (float)hh);
            }
            *(bf16x4*)&As_hi[row * KP + k] = h;
            *(bf16x4*)&As_lo[row * KP + k] = l;
        }
    } else {
        constexpr int CHUNKS = BM * K * 2 / (16 * 256);
        const unsigned short* A = (const unsigned short*)Av;
        u16x8 tmp[CHUNKS];
#pragma unroll
        for (int c = 0; c < CHUNKS; c++) {
            int ci = c * 256 + tid;
            int ei = ci * 8;
            int row = ei / K, k = ei % K;
            int grow = row0 + row;
            tmp[c] = (u16x8){0, 0, 0, 0, 0, 0, 0, 0};
            if (grow < M) tmp[c] = *(const u16x8*)(A + (size_t)grow * K + k);
        }
#pragma unroll
        for (int c = 0; c < CHUNKS; c++) {
            int ci = c * 256 + tid;
            int ei = ci * 8;
            int row = ei / K, k = ei % K;
            *(u16x8*)&As_hi[row * KP + k] = tmp[c];
        }
    }
    __syncthreads();

    // ---- barrier-free compute over all K steps ----
    f32x4 acc[WMT][WNT];
#pragma unroll
    for (int i = 0; i < WMT; i++)
#pragma unroll
        for (int j = 0; j < WNT; j++) acc[i][j] = (f32x4){0.f, 0.f, 0.f, 0.f};

#pragma unroll
    for (int ks = 0; ks < K / 32; ks++) {
        bf16x8 ah[WMT], al[WMT];
#pragma unroll
        for (int i = 0; i < WMT; i++) {
            int rowl = wm * (WMT * 16) + i * 16 + l16;
            ah[i] = *(const bf16x8*)&As_hi[rowl * KP + ks * 32 + quad * 8];
            if (!ABF16) al[i] = *(const bf16x8*)&As_lo[rowl * KP + ks * 32 + quad * 8];
        }
        bf16x8 bh[WNT], bl[WNT];
#pragma unroll
        for (int j = 0; j < WNT; j++) {
            size_t base = ((size_t)(ks * NT + ntile0 + j) * 64 + lane) * 16;
            bh[j] = *(const bf16x8*)&Bf[base];
            bl[j] = *(const bf16x8*)&Bf[base + 8];
        }
#pragma unroll
        for (int i = 0; i < WMT; i++)
#pragma unroll
            for (int j = 0; j < WNT; j++) {
                acc[i][j] = __builtin_amdgcn_mfma_f32_16x16x32_bf16(ah[i], bh[j], acc[i][j], 0, 0, 0);
                if (!ABF16)
                    acc[i][j] = __builtin_amdgcn_mfma_f32_16x16x32_bf16(al[i], bh[j], acc[i][j], 0, 0, 0);
                acc[i][j] = __builtin_amdgcn_mfma_f32_16x16x32_bf16(ah[i], bl[j], acc[i][j], 0, 0, 0);
            }
    }

    // ---- epilogue v2: acc -> LDS f32 C-tile, then alpha + coalesced C ----
    __syncthreads();  // all As reads done before overwrite
#pragma unroll
    for (int i = 0; i < WMT; i++) {
        int rbase = wm * (WMT * 16) + i * 16 + quad * 4;  // block-local row
#pragma unroll
        for (int j = 0; j < WNT; j++) {
            int lcol = (wn * WNT + j) * 16 + l16;          // block-local col
#pragma unroll
            for (int r2 = 0; r2 < 4; r2++)
                Ct[(size_t)(rbase + r2) * BNP + lcol] = acc[i][j][r2];
        }
    }
    __syncthreads();

    // phase 2a: alpha — BM x (BN/CHEAD) outputs, contiguous LDS reads
    constexpr int HB = BN / CHEAD;
    const int colbase = blockIdx.y * BN;
    const int Hh = N / CHEAD;
#pragma unroll
    for (int o = 0; o < (BM * HB + 255) / 256; o++) {
        int idx = o * 256 + tid;
        if (idx < BM * HB) {
            int row = idx & (BM - 1);
            int hd = idx / BM;   // wave-uniform -> scalar a_s/a_d loads
            const float* crow = Ct + (size_t)row * BNP + hd * CHEAD;
            float ss = 0.f, sd = 0.f;
#pragma unroll
            for (int c = 0; c < CHEAD; c++) {
                float v = crow[c];
                ss = fmaf(v, a_s[colbase + hd * CHEAD + c], ss);
                sd = fmaf(v, a_d[colbase + hd * CHEAD + c], sd);
            }
            int grow = row0 + row;
            if (grow < M) {
                out_as[(size_t)grow * Hh + blockIdx.y * HB + hd] = ss;
                out_ad[(size_t)grow * Hh + blockIdx.y * HB + hd] = sd;
            }
        }
    }

    // phase 2b: C store — packed 2xbf16, coalesced 4B/lane
    constexpr int CU2 = BM * BN / 2;  // uint count (multiple of 256 here)
#pragma unroll
    for (int o = 0; o < CU2 / 256; o++) {
        int idx = o * 256 + tid;
        int row = idx / (BN / 2);
        int uc = idx - row * (BN / 2);
        float v0 = Ct[(size_t)row * BNP + uc * 2];
        float v1 = Ct[(size_t)row * BNP + uc * 2 + 1];
        unsigned pk = (unsigned)bf_bits(v0) | ((unsigned)bf_bits(v1) << 16);
        int grow = row0 + row;
        if (grow < M)
            ((unsigned*)Cb)[((size_t)grow * N + colbase) / 2 + uc] = pk;
    }
}

// ---------------- layer-3 MFMA GEMM + fused alpha (K=64, N=10 pad 16) ----------------
__global__ __launch_bounds__(256) void gemm3_k(
        const unsigned short* __restrict__ Ab, const short* __restrict__ Bfs,
        unsigned short* __restrict__ Cb,
        const float* __restrict__ a_s, const float* __restrict__ a_d,
        float* __restrict__ out_as, float* __restrict__ out_ad, int M) {
    const bf16_t* Bf = (const bf16_t*)Bfs;
    int tid = threadIdx.x;
    int wave = tid >> 6, lane = tid & 63;
    int quad = lane >> 4, l16 = lane & 15;
    int grow0 = blockIdx.x * 64 + wave * 16;

    bf16x8 bh[2], bl[2];
#pragma unroll
    for (int ks = 0; ks < 2; ks++) {
        size_t base = (size_t)(ks * 64 + lane) * 16;
        bh[ks] = *(const bf16x8*)&Bf[base];
        bl[ks] = *(const bf16x8*)&Bf[base + 8];
    }

    int arow = grow0 + l16; if (arow >= M) arow = M - 1;  // clamp; outputs guarded
    f32x4 acc = (f32x4){0.f, 0.f, 0.f, 0.f};
#pragma unroll
    for (int ks = 0; ks < 2; ks++) {
        bf16x8 a = *(const bf16x8*)(Ab + (size_t)arow * 64 + ks * 32 + quad * 8);
        acc = __builtin_amdgcn_mfma_f32_16x16x32_bf16(a, bh[ks], acc, 0, 0, 0);
        acc = __builtin_amdgcn_mfma_f32_16x16x32_bf16(a, bl[ks], acc, 0, 0, 0);
    }

    bool colv = l16 < 10;
    float cs = colv ? a_s[l16] : 0.f;
    float cd = colv ? a_d[l16] : 0.f;
    float ps[4], pd[4];
#pragma unroll
    for (int r = 0; r < 4; r++) { ps[r] = acc[r] * cs; pd[r] = acc[r] * cd; }
#pragma unroll
    for (int off = 1; off < 16; off <<= 1) {
#pragma unroll
        for (int r = 0; r < 4; r++) {
            ps[r] += __shfl_xor(ps[r], off, 64);
            pd[r] += __shfl_xor(pd[r], off, 64);
        }
    }
#pragma unroll
    for (int r = 0; r < 4; r++) {
        int grow = grow0 + quad * 4 + r;
        if (grow < M) {
            if (colv) Cb[(size_t)grow * 10 + l16] = bf_bits(acc[r]);
            if (l16 == 0) { out_as[grow] = ps[r]; out_ad[grow] = pd[r]; }
        }
    }
}

// ---------------- single-pass batched aggregation, H=8 C=16 (layer 1) ----------------
// AT the random-gather throughput wall: scheduling-invariant 86 us. Keep.
template <bool DO_ELU>
__global__ void agg16_k(const unsigned short* __restrict__ xpb,
                        const float* __restrict__ asrc, const float* __restrict__ adst,
                        const int* __restrict__ offs, const int* __restrict__ cols,
                        const float* __restrict__ bias, unsigned short* __restrict__ outb,
                        int N) {
    int gtid = blockIdx.x * blockDim.x + threadIdx.x;
    int n = gtid >> 6;
    if (n >= N) return;
    int lane = threadIdx.x & 63;
    int j = lane >> 3, h = lane & 7;
    const int jb = j << 2;  // bpermute byte addr of (j=0, h=j) lane
    int start = offs[n], end = offs[n + 1];
    const unsigned* xp32 = (const unsigned*)xpb;

    // independent loads first
    unsigned uself = xp32[(size_t)n * 64 + lane];
    float ad_l = adst[n * 8 + h];
    float vs = asrc[n * 8 + h] + ad_l;
    vs = LEAKY(vs);

    // weight-role state (head h): seeded with implicit self-loop
    float m_w = vs;
    float s = (j == 0) ? 1.f : 0.f;
    // feature-role state (head j): acc = self row (weight exp(vs-vs)=1)
    float m_f = bperm_f(jb, vs);
    float a0 = __uint_as_float(uself << 16);
    float a1 = __uint_as_float(uself & 0xffff0000u);

    for (int c0 = start; c0 < end; c0 += 16) {
        int e0 = c0 + j, e1 = c0 + 8 + j;
        bool ok0 = e0 < end, ok1 = e1 < end;
        int sl0 = ok0 ? cols[e0] : 0;
        int sl1 = ok1 ? cols[e1] : 0;
        // ---- issue all 16 row gathers (dep only on cols) ----
        unsigned u[16];
#pragma unroll
        for (int t = 0; t < 8; t++) {
            int srcj = __builtin_amdgcn_readlane(sl0, t * 8);
            u[t] = xp32[(size_t)srcj * 64 + lane];
        }
#pragma unroll
        for (int t = 0; t < 8; t++) {
            int srcj = __builtin_amdgcn_readlane(sl1, t * 8);
            u[8 + t] = xp32[(size_t)srcj * 64 + lane];
        }
        // ---- weight math while gathers are in flight ----
        float v0 = -1e30f, v1 = -1e30f;
        if (ok0) { v0 = asrc[sl0 * 8 + h] + ad_l; v0 = LEAKY(v0); }
        if (ok1) { v1 = asrc[sl1 * 8 + h] + ad_l; v1 = LEAKY(v1); }
        float cm = fmaxf(v0, v1);
        cm = fmaxf(cm, __shfl_xor(cm, 8, 64));
        cm = fmaxf(cm, __shfl_xor(cm, 16, 64));
        cm = fmaxf(cm, __shfl_xor(cm, 32, 64));
        float mw_new = fmaxf(m_w, cm);
        float w0 = __expf(v0 - mw_new);  // 0 for invalid slots
        float w1 = __expf(v1 - mw_new);
        s = s * __expf(m_w - mw_new) + w0 + w1;
        m_w = mw_new;
        // feature-role rescale (head j)
        float cmF = bperm_f(jb, cm);
        float mf_new = fmaxf(m_f, cmF);
        float scF = __expf(m_f - mf_new);
        m_f = mf_new;
        a0 *= scF; a1 *= scF;
        float wl[16];
#pragma unroll
        for (int t = 0; t < 8; t++) wl[t] = bperm_f(jb + t * 32, w0);
#pragma unroll
        for (int t = 0; t < 8; t++) wl[8 + t] = bperm_f(jb + t * 32, w1);
        // ---- consume ----
#pragma unroll
        for (int t = 0; t < 16; t++) {
            a0 = fmaf(wl[t], __uint_as_float(u[t] << 16), a0);
            a1 = fmaf(wl[t], __uint_as_float(u[t] & 0xffff0000u), a1);
        }
    }
    // finalize: total s per head, then normalize
    s += __shfl_xor(s, 8, 64);
    s += __shfl_xor(s, 16, 64);
    s += __shfl_xor(s, 32, 64);
    float rs = 1.f / (s + 1e-16f);
    float rsF = bperm_f(jb, rs);
    float o0 = a0 * rsF + bias[2 * lane];
    float o1 = a1 * rsF + bias[2 * lane + 1];
    if (DO_ELU) {
        o0 = o0 > 0.f ? o0 : __expf(o0) - 1.f;
        o1 = o1 > 0.f ? o1 : __expf(o1) - 1.f;
    }
    unsigned packed = (unsigned)bf_bits(o0) | ((unsigned)bf_bits(o1) << 16);
    ((unsigned*)outb)[(size_t)n * 64 + lane] = packed;  // row = 128 shorts = 64 uints
}

// ---------------- single-pass batched aggregation, H=8 C=8 (layer 2) ----------------
template <bool DO_ELU>
__global__ void agg8c8_k(const unsigned short* __restrict__ xpb,
                         const float* __restrict__ asrc, const float* __restrict__ adst,
                         const int* __restrict__ offs, const int* __restrict__ cols,
                         const float* __restrict__ bias, unsigned short* __restrict__ outb,
                         int N) {
    int gtid = blockIdx.x * blockDim.x + threadIdx.x;
    int n = gtid >> 6;
    if (n >= N) return;
    int lane = threadIdx.x & 63;
    int j = lane >> 3, h = lane & 7;
    int start = offs[n], end = offs[n + 1];
    const unsigned* xp32 = (const unsigned*)xpb;

    int fp = lane & 31;      // feature pair {2fp, 2fp+1}
    int hF = fp >> 2;        // feature-role head
    int half = lane >> 5;
    int sbase = half * 32;

    float ad_l = adst[n * 8 + h];
    float vs = asrc[n * 8 + h] + ad_l;
    vs = LEAKY(vs);

    float m_w = vs;
    float s = (j == 0) ? 1.f : 0.f;
    float m_f = bperm_f(hF * 4, vs);
    float a0 = 0.f, a1 = 0.f;
    if (half == 0) {  // self contribution in half 0 only
        unsigned u = xp32[(size_t)n * 32 + fp];
        a0 = __uint_as_float(u << 16);
        a1 = __uint_as_float(u & 0xffff0000u);
    }

    for (int c0 = start; c0 < end; c0 += 16) {
        int e0 = c0 + j, e1 = c0 + 8 + j;
        bool ok0 = e0 < end, ok1 = e1 < end;
        int sl0 = ok0 ? cols[e0] : 0;
        int sl1 = ok1 ? cols[e1] : 0;
        // ---- issue all 8 row gathers per lane-half (dep only on cols) ----
        int sv[8];
#pragma unroll
        for (int t = 0; t < 4; t++) sv[t] = __builtin_amdgcn_ds_bpermute(sbase + t * 64, sl0);
#pragma unroll
        for (int t = 0; t < 4; t++) sv[4 + t] = __builtin_amdgcn_ds_bpermute(sbase + t * 64, sl1);
        unsigned u[8];
#pragma unroll
        for (int t = 0; t < 8; t++) u[t] = xp32[(size_t)sv[t] * 32 + fp];
        // ---- weight math while gathers are in flight ----
        float v0 = -1e30f, v1 = -1e30f;
        if (ok0) { v0 = asrc[sl0 * 8 + h] + ad_l; v0 = LEAKY(v0); }
        if (ok1) { v1 = asrc[sl1 * 8 + h] + ad_l; v1 = LEAKY(v1); }
        float cm = fmaxf(v0, v1);
        cm = fmaxf(cm, __shfl_xor(cm, 8, 64));
        cm = fmaxf(cm, __shfl_xor(cm, 16, 64));
        cm = fmaxf(cm, __shfl_xor(cm, 32, 64));
        float mw_new = fmaxf(m_w, cm);
        float w0 = __expf(v0 - mw_new);
        float w1 = __expf(v1 - mw_new);
        s = s * __expf(m_w - mw_new) + w0 + w1;
        m_w = mw_new;
        float cmF = bperm_f(hF * 4, cm);
        float mf_new = fmaxf(m_f, cmF);
        float scF = __expf(m_f - mf_new);
        m_f = mf_new;
        a0 *= scF; a1 *= scF;
        float wl[8];
#pragma unroll
        for (int t = 0; t < 4; t++) wl[t] = bperm_f(sbase + hF * 4 + t * 64, w0);
#pragma unroll
        for (int t = 0; t < 4; t++) wl[4 + t] = bperm_f(sbase + hF * 4 + t * 64, w1);
        // ---- consume ----
#pragma unroll
        for (int t = 0; t < 8; t++) {
            a0 = fmaf(wl[t], __uint_as_float(u[t] << 16), a0);
            a1 = fmaf(wl[t], __uint_as_float(u[t] & 0xffff0000u), a1);
        }
    }
    s += __shfl_xor(s, 8, 64);
    s += __shfl_xor(s, 16, 64);
    s += __shfl_xor(s, 32, 64);
    float rs = 1.f / (s + 1e-16f);
    float rsF = bperm_f(hF * 4, rs);
    // combine halves (same m_f in both halves), then normalize
    a0 += __shfl_xor(a0, 32, 64);
    a1 += __shfl_xor(a1, 32, 64);
    if (half == 0) {
        float o0 = a0 * rsF + bias[2 * fp];
        float o1 = a1 * rsF + bias[2 * fp + 1];
        if (DO_ELU) {
            o0 = o0 > 0.f ? o0 : __expf(o0) - 1.f;
            o1 = o1 > 0.f ? o1 : __expf(o1) - 1.f;
        }
        unsigned packed = (unsigned)bf_bits(o0) | ((unsigned)bf_bits(o1) << 16);
        ((unsigned*)outb)[(size_t)n * 32 + fp] = packed;  // row = 64 shorts = 32 uints
    }
}

// ---------------- aggregation H=1 C=10 + fused log_softmax (layer 3) ----------------
__global__ void agg1h_k(const unsigned short* __restrict__ xpb,
                        const float* __restrict__ asrc, const float* __restrict__ adst,
                        const int* __restrict__ offs, const int* __restrict__ cols,
                        const float* __restrict__ bias, float* __restrict__ out, int N) {
    int gtid = blockIdx.x * blockDim.x + threadIdx.x;
    int n = gtid >> 6;
    if (n >= N) return;
    int lane = threadIdx.x & 63;
    int start = offs[n], end = offs[n + 1];
    float ad = adst[n];
    float vs = asrc[n] + ad;  // implicit self-loop
    vs = LEAKY(vs);

    float m, s;
    if (lane == 0) { m = vs; s = 1.f; } else { m = -1e30f; s = 0.f; }
    for (int e = start + lane; e < end; e += 64) {
        float v = asrc[cols[e]] + ad;
        v = LEAKY(v);
        float mo = fmaxf(m, v);
        s = s * __expf(m - mo) + __expf(v - mo);
        m = mo;
    }
#pragma unroll
    for (int off = 1; off <= 32; off <<= 1) {
        float mo = __shfl_xor(m, off, 64);
        float so = __shfl_xor(s, off, 64);
        float mn = fmaxf(m, mo);
        s = s * __expf(m - mn) + so * __expf(mo - mn);
        m = mn;
    }
    float rs = 1.f / (s + 1e-16f);
    float wself = __expf(vs - m) * rs;

    int j = lane / 10, c = lane - j * 10;
    float acc = 0.f;
    if (j == 0) acc = wself * bf_to_f(xpb[(size_t)n * 10 + c]);  // self term
    for (int c0 = start; c0 < end; c0 += 6) {
        int e = c0 + j;
        if (j < 6 && e < end) {
            int src = cols[e];
            float v = asrc[src] + ad;
            v = LEAKY(v);
            float w = __expf(v - m) * rs;
            acc = fmaf(w, bf_to_f(xpb[(size_t)src * 10 + c]), acc);
        }
    }
    float tot = acc;
#pragma unroll
    for (int k = 1; k < 6; k++) tot += __shfl(acc, lane + 10 * k, 64);

    // fused log_softmax over the 10 classes (valid in lanes 0-9)
    float z = tot + bias[lane < 10 ? lane : 0];
    float mx = -1e30f;
#pragma unroll
    for (int k = 0; k < 10; k++) mx = fmaxf(mx, __shfl(z, k, 64));
    float se = 0.f;
#pragma unroll
    for (int k = 0; k < 10; k++) se += __expf(__shfl(z, k, 64) - mx);
    if (lane < 10) out[(size_t)n * 10 + lane] = z - (__logf(se) + mx);
}

// ---------------- launch ----------------

static inline size_t alignup(size_t x) { return (x + 255) & ~(size_t)255; }

extern "C" void kernel_launch(void* const* d_in, const int* in_sizes, int n_in,
                              void* d_out, int out_size, void* d_ws, size_t ws_size,
                              hipStream_t stream) {
    const float* x   = (const float*)d_in[0];
    const int*   ei  = (const int*)d_in[1];
    const float* W1  = (const float*)d_in[2];
    const float* a1s = (const float*)d_in[3];
    const float* a1d = (const float*)d_in[4];
    const float* b1  = (const float*)d_in[5];
    const float* W2  = (const float*)d_in[6];
    const float* a2s = (const float*)d_in[7];
    const float* a2d = (const float*)d_in[8];
    const float* b2  = (const float*)d_in[9];
    const float* W3  = (const float*)d_in[10];
    const float* a3s = (const float*)d_in[11];
    const float* a3d = (const float*)d_in[12];
    const float* b3  = (const float*)d_in[13];
    float* out = (float*)d_out;

    const int N = in_sizes[0] / 256;
    const int E = in_sizes[1] / 2;
    const int* src = ei;
    const int* dst = ei + E;
    const int NB = (N + 255) >> 8;  // 391 for N=100000 (<= NB_MAX)

    char* p = (char*)d_ws;
    int* offs    = (int*)p; p += alignup(sizeof(int) * (size_t)(N + 1));
    int* bcur    = (int*)p; p += alignup(sizeof(int) * (size_t)(NB_MAX + 1));
    int* cols    = (int*)p; p += alignup(sizeof(int) * (size_t)E);
    unsigned short* xpb   = (unsigned short*)p; p += alignup(2 * (size_t)N * 128);
    unsigned short* hbufb = (unsigned short*)p; p += alignup(2 * (size_t)N * 128);
    float* xp    = (float*)p; p += alignup(sizeof(float) * (size_t)N * 128);
    float* as_   = (float*)p; p += alignup(sizeof(float) * (size_t)N * 8);
    float* ad_   = (float*)p; p += alignup(sizeof(float) * (size_t)N * 8);
    short* Bf1   = (short*)p; p += alignup(sizeof(short) * 8 * 8 * 64 * 16);  // K=256,N=128
    short* Bf2   = (short*)p; p += alignup(sizeof(short) * 4 * 4 * 64 * 16);  // K=128,N=64
    short* Bf3   = (short*)p; p += alignup(sizeof(short) * 2 * 1 * 64 * 16);  // K=64,N=16(pad)
    // staged bucket regions alias xp: CSR build finishes before anything else
    // uses xp (xp itself is dead since R13's fused gemm3).
    unsigned* staged = (unsigned*)xp;  // NB * BCAP * 4B = 8 MB << 51.2 MB

    const int TB = 256;

    // CSR build: bucketed counting sort (self-loops implicit in agg)
    hipMemsetAsync(bcur, 0, sizeof(int) * (size_t)(NB + 1), stream);
    partition_k<<<(E + 4095) / 4096, 256, 0, stream>>>(src, dst, E, NB, bcur, staged);
    buildcsr_k<<<NB, 256, 0, stream>>>(staged, bcur, offs, cols, N, NB);

    // W pre-pack (fragment order, hi|lo) — single fused launch
    prep_all_k<<<(5248 + TB - 1) / TB, TB, 0, stream>>>(W1, W2, W3, Bf1, Bf2, Bf3);

    // ---- layer 1: 256 -> 128 (H=8, C=16), ELU
    mfma_gemm_k<64, 4, 2, 1, false, 16, 256><<<dim3((N + 63) / 64, 1), 256, 0, stream>>>(
        x, Bf1, xpb, a1s, a1d, as_, ad_, N, 128, 8);
    agg16_k<true><<<(N * 64 + TB - 1) / TB, TB, 0, stream>>>(
        xpb, as_, ad_, offs, cols, b1, hbufb, N);

    // ---- layer 2: 128 -> 64 (H=8, C=8), ELU  (A is bf16 agg output)
    mfma_gemm_k<64, 4, 1, 1, true, 8, 128><<<dim3((N + 63) / 64, 1), 256, 0, stream>>>(
        hbufb, Bf2, xpb, a2s, a2d, as_, ad_, N, 64, 4);
    agg8c8_k<true><<<(N * 64 + TB - 1) / TB, TB, 0, stream>>>(
        xpb, as_, ad_, offs, cols, b2, hbufb, N);

    // ---- layer 3: 64 -> 10 (H=1, C=10) MFMA + fused alpha, then agg + log_softmax
    gemm3_k<<<(N + 63) / 64, 256, 0, stream>>>(
        hbufb, Bf3, xpb, a3s, a3d, as_, ad_, N);
    agg1h_k<<<(N * 64 + TB - 1) / TB, TB, 0, stream>>>(
        xpb, as_, ad_, offs, cols, b3, out, N);
}

// Round 6
// 456.945 us; speedup vs baseline: 1.1818x; 1.0444x over previous
//
#include <hip/hip_runtime.h>
#include <hip/hip_bf16.h>
#include <math.h>

// ---------------------------------------------------------------------------
// GAT 3-layer forward on MI355X.
//   R15:
//   - L1 GEMM: K-split staging (2 phases of K=128) -> LDS 67.6->34.8 KB ->
//     4 blocks/CU (was 2). Same accumulation order (bitwise-identical).
//   - Kernel fusion for concurrency (same-stream serialization removed):
//     part_prep_k = partition + W pre-pack; csr_gemm1_k = buildcsr + L1 GEMM
//     (independent work, block-range split, shared smem union). 10->8
//     dispatches.
//   - Epilogue v2 (R14): acc -> LDS f32 C-tile -> contiguous alpha reads +
//     coalesced packed-bf16 C stores.
//   - agg16/agg8c8: single-pass online-softmax, batched gathers. agg16 AT
//     the random-gather wall (~86 us, scheduling-invariant R9/R11/R12).
// ---------------------------------------------------------------------------

#define LEAKY(v) ((v) > 0.f ? (v) : 0.2f * (v))

typedef __bf16 bf16_t;
typedef __bf16 bf16x8 __attribute__((ext_vector_type(8)));
typedef __bf16 bf16x4 __attribute__((ext_vector_type(4)));
typedef float f32x4 __attribute__((ext_vector_type(4)));
typedef unsigned short u16x8 __attribute__((ext_vector_type(8)));

static __device__ __forceinline__ unsigned short bf_bits(float f) {
    bf16_t b = (bf16_t)f;
    return __builtin_bit_cast(unsigned short, b);
}
static __device__ __forceinline__ float bf_to_f(unsigned short u) {
    return __uint_as_float(((unsigned int)u) << 16);
}
static __device__ __forceinline__ float bperm_f(int byteaddr, float v) {
    return __uint_as_float((unsigned)__builtin_amdgcn_ds_bpermute(byteaddr, (int)__float_as_uint(v)));
}

// ---------------- CSR build: 2-pass bucket sort ----------------
constexpr int NB_MAX = 400;
constexpr int BCAP = 5120;  // capacity per bucket region; mean load 4096

// ---------------- W pre-pack device helpers ----------------
static __device__ __forceinline__ void prep_w_dev(
        const float* __restrict__ W, short* __restrict__ Bfs,
        int K, int N, int NT, int idx) {
    int lane = idx & 63;
    int t = idx >> 6;
    int ntile = t % NT, kstep = t / NT;
    int quad = lane >> 4, nl = lane & 15;
    int n = ntile * 16 + nl;
    bf16_t* dst = (bf16_t*)Bfs + (size_t)idx * 16;
#pragma unroll
    for (int j = 0; j < 8; j++) {
        int k = kstep * 32 + quad * 8 + j;
        float v = W[k * N + n];
        bf16_t h = (bf16_t)v;
        bf16_t l = (bf16_t)(v - (float)h);
        dst[j] = h;
        dst[8 + j] = l;
    }
}
static __device__ __forceinline__ void prep_w3_dev(
        const float* __restrict__ W, short* __restrict__ Bfs, int Nc, int idx) {
    int lane = idx & 63, ks = idx >> 6;
    int quad = lane >> 4, nl = lane & 15;
    bf16_t* dst = (bf16_t*)Bfs + (size_t)idx * 16;
#pragma unroll
    for (int j = 0; j < 8; j++) {
        int k = ks * 32 + quad * 8 + j;
        float v = (nl < Nc) ? W[k * Nc + nl] : 0.f;
        bf16_t h = (bf16_t)v;
        bf16_t l = (bf16_t)(v - (float)h);
        dst[j] = h;
        dst[8 + j] = l;
    }
}

// ---------------- fused: edge partition + W pre-pack ----------------
// Blocks [0, PB): partition edges into bucket regions (block-local grouping).
// Blocks [PB, PB+21): W1/W2/W3 fragment pre-pack (independent work).
__global__ __launch_bounds__(256) void part_prep_k(
        const int* __restrict__ src, const int* __restrict__ dst, int E, int NB,
        int* __restrict__ bcur, unsigned* __restrict__ staged, int PB,
        const float* __restrict__ W1, const float* __restrict__ W2,
        const float* __restrict__ W3, short* __restrict__ Bf1,
        short* __restrict__ Bf2, short* __restrict__ Bf3) {
    __shared__ int hist[NB_MAX];
    __shared__ int bstart[NB_MAX + 1];
    __shared__ int cur[NB_MAX];
    __shared__ int gbase[NB_MAX];
    __shared__ unsigned words[4096];
    __shared__ unsigned short bidl[4096];
    int tid = threadIdx.x;

    if ((int)blockIdx.x >= PB) {  // ---- prep branch ----
        int idx = ((int)blockIdx.x - PB) * 256 + tid;
        if (idx < 4096) prep_w_dev(W1, Bf1, 256, 128, 8, idx);
        else if (idx < 5120) prep_w_dev(W2, Bf2, 128, 64, 4, idx - 4096);
        else if (idx < 5248) prep_w3_dev(W3, Bf3, 10, idx - 5120);
        return;
    }

    int e0 = blockIdx.x * 4096;
    int cnt = E - e0; if (cnt > 4096) cnt = 4096;
    if (cnt <= 0) return;

    for (int b = tid; b < NB; b += 256) hist[b] = 0;
    __syncthreads();
    for (int i = tid; i < cnt; i += 256) atomicAdd(&hist[dst[e0 + i] >> 8], 1);
    __syncthreads();
    // wave-0 parallel exclusive scan over NB entries
    if (tid < 64) {
        int lane = tid;
        int run = 0;
        for (int b0 = 0; b0 < NB; b0 += 64) {
            int bb = b0 + lane;
            int v = (bb < NB) ? hist[bb] : 0;
            int sc = v;
            for (int off = 1; off < 64; off <<= 1) {
                int t2 = __shfl_up(sc, off, 64);
                if (lane >= off) sc += t2;
            }
            if (bb < NB) bstart[bb] = run + sc - v;
            run += __shfl(sc, 63, 64);
        }
        if (lane == 0) bstart[NB] = run;
    }
    __syncthreads();
    for (int b = tid; b < NB; b += 256) {
        cur[b] = bstart[b];
        gbase[b] = hist[b] ? atomicAdd(&bcur[b], hist[b]) : 0;
    }
    __syncthreads();
    // group into LDS by bucket, remember bucket id per slot
    for (int i = tid; i < cnt; i += 256) {
        int s = src[e0 + i], d = dst[e0 + i];
        int b = d >> 8;
        unsigned w = (unsigned)s | ((unsigned)(d & 255) << 17);
        int p = atomicAdd(&cur[b], 1);
        words[p] = w;
        bidl[p] = (unsigned short)b;
    }
    __syncthreads();
    // linear sweep -> coalesced runs into global bucket regions
    for (int i = tid; i < cnt; i += 256) {
        int b = bidl[i];
        staged[(size_t)b * BCAP + gbase[b] + (i - bstart[b])] = words[i];
    }
}

// ---------------- buildcsr body (runs inside fused csr_gemm1_k) ----------------
static __device__ void buildcsr_body(
        char* smem, const unsigned* __restrict__ staged, const int* __restrict__ bcur,
        int* __restrict__ offs, int* __restrict__ cols, int N, int NB, int b) {
    int* h    = (int*)smem;
    int* hs   = h + 256;
    int* curl = hs + 256;
    int* colsl = curl + 256;
    int* base_p = colsl + BCAP;
    int tid = threadIdx.x;
    int n0 = b << 8;
    int ecnt = bcur[b];
    const unsigned* sb = staged + (size_t)b * BCAP;

    h[tid] = 0;
    if (tid < 64) {  // base_g = sum(bcur[0..b))
        int acc2 = 0;
        for (int i = tid; i < b; i += 64) acc2 += bcur[i];
        for (int off = 1; off < 64; off <<= 1) acc2 += __shfl_xor(acc2, off, 64);
        if (tid == 0) *base_p = acc2;
    }
    __syncthreads();
    int base_g = *base_p;
    for (int i = tid; i < ecnt; i += 256) atomicAdd(&h[sb[i] >> 17], 1);
    __syncthreads();
    int val = h[tid];
    hs[tid] = val; __syncthreads();
    for (int off = 1; off < 256; off <<= 1) {
        int t = (tid >= off) ? hs[tid - off] : 0;
        __syncthreads();
        hs[tid] += t;
        __syncthreads();
    }
    int excl = hs[tid] - val;
    curl[tid] = excl;
    if (n0 + tid < N) offs[n0 + tid] = base_g + excl;
    if (b == NB - 1 && tid == 0) offs[N] = base_g + ecnt;
    __syncthreads();
    for (int i = tid; i < ecnt; i += 256) {
        unsigned w = sb[i];
        int p = atomicAdd(&curl[w >> 17], 1);
        colsl[p] = (int)(w & 0x1FFFFu);
    }
    __syncthreads();
    for (int i = tid; i < ecnt; i += 256) cols[base_g + i] = colsl[i];
}

// ---------------- split-bf16 MFMA GEMM body (K-split staging + epilogue v2) ----------------
template <int BM, int WMT, int WNT, int NWM, bool ABF16, int CHEAD, int K, int NPH>
static __device__ __forceinline__ void gemm_body(
        char* smem,
        const void* __restrict__ Av, const short* __restrict__ Bfs,
        unsigned short* __restrict__ Cb,
        const float* __restrict__ a_s, const float* __restrict__ a_d,
        float* __restrict__ out_as, float* __restrict__ out_ad,
        int M, int N, int NT, int bx, int by) {
    constexpr int NWN = 4 / NWM;
    constexpr int BN = 16 * WNT * NWN;
    constexpr int KPH = K / NPH;     // K per staging phase
    constexpr int KPP = KPH + 8;     // +8 bf16 pad: breaks bank aliasing
    constexpr int BNP = BN + 2;      // f32 C-tile pad
    bf16_t* As_hi = (bf16_t*)smem;
    bf16_t* As_lo = As_hi + (ABF16 ? 0 : (size_t)BM * KPP);
    float* Ct = (float*)smem;
    const bf16_t* Bf = (const bf16_t*)Bfs;

    int tid = threadIdx.x;
    int wave = tid >> 6, lane = tid & 63;
    int quad = lane >> 4, l16 = lane & 15;
    int wm = wave % NWM, wn = wave / NWM;
    int row0 = bx * BM;
    int ntile0 = by * (BN / 16) + wn * WNT;

    f32x4 acc[WMT][WNT];
#pragma unroll
    for (int i = 0; i < WMT; i++)
#pragma unroll
        for (int j = 0; j < WNT; j++) acc[i][j] = (f32x4){0.f, 0.f, 0.f, 0.f};

#pragma unroll
    for (int phase = 0; phase < NPH; phase++) {
        if (phase) __syncthreads();  // previous compute's LDS reads done
        // ---- stage this K-phase: all loads issued before conversion ----
        if constexpr (!ABF16) {
            constexpr int CHUNKS = BM * KPH * 4 / (16 * 256);
            const float* A = (const float*)Av;
            f32x4 tmp[CHUNKS];
#pragma unroll
            for (int c = 0; c < CHUNKS; c++) {
                int ci = c * 256 + tid;
                int fi = ci * 4;
                int row = fi / KPH, k = fi % KPH;
                int grow = row0 + row;
                tmp[c] = (f32x4){0.f, 0.f, 0.f, 0.f};
                if (grow < M) tmp[c] = *(const f32x4*)(A + (size_t)grow * K + phase * KPH + k);
            }
#pragma unroll
            for (int c = 0; c < CHUNKS; c++) {
                int ci = c * 256 + tid;
                int fi = ci * 4;
                int row = fi / KPH, k = fi % KPH;
                bf16x4 h, l;
#pragma unroll
                for (int j = 0; j < 4; j++) {
                    bf16_t hh = (bf16_t)tmp[c][j];
                    h[j] = hh;
                    l[j] = (bf16_t)(tmp[c][j] - (float)hh);
                }
                *(bf16x4*)&As_hi[row * KPP + k] = h;
                *(bf16x4*)&As_lo[row * KPP + k] = l;
            }
        } else {
            constexpr int CHUNKS = BM * KPH * 2 / (16 * 256);
            const unsigned short* A = (const unsigned short*)Av;
            u16x8 tmp[CHUNKS];
#pragma unroll
            for (int c = 0; c < CHUNKS; c++) {
                int ci = c * 256 + tid;
                int ei = ci * 8;
                int row = ei / KPH, k = ei % KPH;
                int grow = row0 + row;
                tmp[c] = (u16x8){0, 0, 0, 0, 0, 0, 0, 0};
                if (grow < M) tmp[c] = *(const u16x8*)(A + (size_t)grow * K + phase * KPH + k);
            }
#pragma unroll
            for (int c = 0; c < CHUNKS; c++) {
                int ci = c * 256 + tid;
                int ei = ci * 8;
                int row = ei / KPH, k = ei % KPH;
                *(u16x8*)&As_hi[row * KPP + k] = tmp[c];
            }
        }
        __syncthreads();

        // ---- compute this K-phase (barrier-free) ----
#pragma unroll
        for (int ks = 0; ks < KPH / 32; ks++) {
            int ksg = phase * (KPH / 32) + ks;
            bf16x8 ah[WMT], al[WMT];
#pragma unroll
            for (int i = 0; i < WMT; i++) {
                int rowl = wm * (WMT * 16) + i * 16 + l16;
                ah[i] = *(const bf16x8*)&As_hi[rowl * KPP + ks * 32 + quad * 8];
                if (!ABF16) al[i] = *(const bf16x8*)&As_lo[rowl * KPP + ks * 32 + quad * 8];
            }
            bf16x8 bh[WNT], bl[WNT];
#pragma unroll
            for (int j = 0; j < WNT; j++) {
                size_t base = ((size_t)(ksg * NT + ntile0 + j) * 64 + lane) * 16;
                bh[j] = *(const bf16x8*)&Bf[base];
                bl[j] = *(const bf16x8*)&Bf[base + 8];
            }
#pragma unroll
            for (int i = 0; i < WMT; i++)
#pragma unroll
                for (int j = 0; j < WNT; j++) {
                    acc[i][j] = __builtin_amdgcn_mfma_f32_16x16x32_bf16(ah[i], bh[j], acc[i][j], 0, 0, 0);
                    if (!ABF16)
                        acc[i][j] = __builtin_amdgcn_mfma_f32_16x16x32_bf16(al[i], bh[j], acc[i][j], 0, 0, 0);
                    acc[i][j] = __builtin_amdgcn_mfma_f32_16x16x32_bf16(ah[i], bl[j], acc[i][j], 0, 0, 0);
                }
        }
    }

    // ---- epilogue v2: acc -> LDS f32 C-tile, then alpha + coalesced C ----
    __syncthreads();  // all As reads done before overwrite
#pragma unroll
    for (int i = 0; i < WMT; i++) {
        int rbase = wm * (WMT * 16) + i * 16 + quad * 4;  // block-local row
#pragma unroll
        for (int j = 0; j < WNT; j++) {
            int lcol = (wn * WNT + j) * 16 + l16;          // block-local col
#pragma unroll
            for (int r2 = 0; r2 < 4; r2++)
                Ct[(size_t)(rbase + r2) * BNP + lcol] = acc[i][j][r2];
        }
    }
    __syncthreads();

    // phase 2a: alpha — BM x (BN/CHEAD) outputs, contiguous LDS reads
    constexpr int HB = BN / CHEAD;
    const int colbase = by * BN;
    const int Hh = N / CHEAD;
#pragma unroll
    for (int o = 0; o < (BM * HB + 255) / 256; o++) {
        int idx = o * 256 + tid;
        if (idx < BM * HB) {
            int row = idx & (BM - 1);
            int hd = idx / BM;   // wave-uniform -> scalar a_s/a_d loads
            const float* crow = Ct + (size_t)row * BNP + hd * CHEAD;
            float ss = 0.f, sd = 0.f;
#pragma unroll
            for (int c = 0; c < CHEAD; c++) {
                float v = crow[c];
                ss = fmaf(v, a_s[colbase + hd * CHEAD + c], ss);
                sd = fmaf(v, a_d[colbase + hd * CHEAD + c], sd);
            }
            int grow = row0 + row;
            if (grow < M) {
                out_as[(size_t)grow * Hh + by * HB + hd] = ss;
                out_ad[(size_t)grow * Hh + by * HB + hd] = sd;
            }
        }
    }

    // phase 2b: C store — packed 2xbf16, coalesced 4B/lane
    constexpr int CU2 = BM * BN / 2;  // uint count (multiple of 256 here)
#pragma unroll
    for (int o = 0; o < CU2 / 256; o++) {
        int idx = o * 256 + tid;
        int row = idx / (BN / 2);
        int uc = idx - row * (BN / 2);
        float v0 = Ct[(size_t)row * BNP + uc * 2];
        float v1 = Ct[(size_t)row * BNP + uc * 2 + 1];
        unsigned pk = (unsigned)bf_bits(v0) | ((unsigned)bf_bits(v1) << 16);
        int grow = row0 + row;
        if (grow < M)
            ((unsigned*)Cb)[((size_t)grow * N + colbase) / 2 + uc] = pk;
    }
}

// ---------------- fused: buildcsr + layer-1 GEMM ----------------
// Blocks [0, NB): per-bucket counting sort -> offs/cols.
// Blocks [NB, NB+gridM): L1 GEMM (K=256, 2-phase staging, 34.8 KB LDS).
// Independent work; agg16 (next dispatch) consumes both.
constexpr int SMEM1 = 64 * (128 + 8) * 2 * 2;  // 34816 >= max(ASZ, CSZ, CSR)
__global__ __launch_bounds__(256, 3) void csr_gemm1_k(
        const unsigned* __restrict__ staged, const int* __restrict__ bcur,
        int* __restrict__ offs, int* __restrict__ cols, int Nn, int NB,
        const float* __restrict__ x, const short* __restrict__ Bf1,
        unsigned short* __restrict__ xpb,
        const float* __restrict__ a1s, const float* __restrict__ a1d,
        float* __restrict__ out_as, float* __restrict__ out_ad, int M) {
    __shared__ __align__(16) char smem[SMEM1];
    if ((int)blockIdx.x < NB) {
        buildcsr_body(smem, staged, bcur, offs, cols, Nn, NB, blockIdx.x);
    } else {
        gemm_body<64, 4, 2, 1, false, 16, 256, 2>(
            smem, x, Bf1, xpb, a1s, a1d, out_as, out_ad, M, 128, 8,
            (int)blockIdx.x - NB, 0);
    }
}

// ---------------- layer-2 GEMM (bf16 A, K=128, single phase) ----------------
constexpr int SMEM2 = 64 * (128 + 8) * 2;  // 17408 >= CSZ(64*66*4)
__global__ __launch_bounds__(256, 2) void mfma_gemm2_k(
        const unsigned short* __restrict__ Ab, const short* __restrict__ Bf2,
        unsigned short* __restrict__ Cb,
        const float* __restrict__ a_s, const float* __restrict__ a_d,
        float* __restrict__ out_as, float* __restrict__ out_ad, int M) {
    __shared__ __align__(16) char smem[SMEM2];
    gemm_body<64, 4, 1, 1, true, 8, 128, 1>(
        smem, Ab, Bf2, Cb, a_s, a_d, out_as, out_ad, M, 64, 4, blockIdx.x, 0);
}

// ---------------- layer-3 MFMA GEMM + fused alpha (K=64, N=10 pad 16) ----------------
__global__ __launch_bounds__(256) void gemm3_k(
        const unsigned short* __restrict__ Ab, const short* __restrict__ Bfs,
        unsigned short* __restrict__ Cb,
        const float* __restrict__ a_s, const float* __restrict__ a_d,
        float* __restrict__ out_as, float* __restrict__ out_ad, int M) {
    const bf16_t* Bf = (const bf16_t*)Bfs;
    int tid = threadIdx.x;
    int wave = tid >> 6, lane = tid & 63;
    int quad = lane >> 4, l16 = lane & 15;
    int grow0 = blockIdx.x * 64 + wave * 16;

    bf16x8 bh[2], bl[2];
#pragma unroll
    for (int ks = 0; ks < 2; ks++) {
        size_t base = (size_t)(ks * 64 + lane) * 16;
        bh[ks] = *(const bf16x8*)&Bf[base];
        bl[ks] = *(const bf16x8*)&Bf[base + 8];
    }

    int arow = grow0 + l16; if (arow >= M) arow = M - 1;  // clamp; outputs guarded
    f32x4 acc = (f32x4){0.f, 0.f, 0.f, 0.f};
#pragma unroll
    for (int ks = 0; ks < 2; ks++) {
        bf16x8 a = *(const bf16x8*)(Ab + (size_t)arow * 64 + ks * 32 + quad * 8);
        acc = __builtin_amdgcn_mfma_f32_16x16x32_bf16(a, bh[ks], acc, 0, 0, 0);
        acc = __builtin_amdgcn_mfma_f32_16x16x32_bf16(a, bl[ks], acc, 0, 0, 0);
    }

    bool colv = l16 < 10;
    float cs = colv ? a_s[l16] : 0.f;
    float cd = colv ? a_d[l16] : 0.f;
    float ps[4], pd[4];
#pragma unroll
    for (int r = 0; r < 4; r++) { ps[r] = acc[r] * cs; pd[r] = acc[r] * cd; }
#pragma unroll
    for (int off = 1; off < 16; off <<= 1) {
#pragma unroll
        for (int r = 0; r < 4; r++) {
            ps[r] += __shfl_xor(ps[r], off, 64);
            pd[r] += __shfl_xor(pd[r], off, 64);
        }
    }
#pragma unroll
    for (int r = 0; r < 4; r++) {
        int grow = grow0 + quad * 4 + r;
        if (grow < M) {
            if (colv) Cb[(size_t)grow * 10 + l16] = bf_bits(acc[r]);
            if (l16 == 0) { out_as[grow] = ps[r]; out_ad[grow] = pd[r]; }
        }
    }
}

// ---------------- single-pass batched aggregation, H=8 C=16 (layer 1) ----------------
// AT the random-gather throughput wall: scheduling-invariant 86 us. Keep.
template <bool DO_ELU>
__global__ void agg16_k(const unsigned short* __restrict__ xpb,
                        const float* __restrict__ asrc, const float* __restrict__ adst,
                        const int* __restrict__ offs, const int* __restrict__ cols,
                        const float* __restrict__ bias, unsigned short* __restrict__ outb,
                        int N) {
    int gtid = blockIdx.x * blockDim.x + threadIdx.x;
    int n = gtid >> 6;
    if (n >= N) return;
    int lane = threadIdx.x & 63;
    int j = lane >> 3, h = lane & 7;
    const int jb = j << 2;  // bpermute byte addr of (j=0, h=j) lane
    int start = offs[n], end = offs[n + 1];
    const unsigned* xp32 = (const unsigned*)xpb;

    // independent loads first
    unsigned uself = xp32[(size_t)n * 64 + lane];
    float ad_l = adst[n * 8 + h];
    float vs = asrc[n * 8 + h] + ad_l;
    vs = LEAKY(vs);

    // weight-role state (head h): seeded with implicit self-loop
    float m_w = vs;
    float s = (j == 0) ? 1.f : 0.f;
    // feature-role state (head j): acc = self row (weight exp(vs-vs)=1)
    float m_f = bperm_f(jb, vs);
    float a0 = __uint_as_float(uself << 16);
    float a1 = __uint_as_float(uself & 0xffff0000u);

    for (int c0 = start; c0 < end; c0 += 16) {
        int e0 = c0 + j, e1 = c0 + 8 + j;
        bool ok0 = e0 < end, ok1 = e1 < end;
        int sl0 = ok0 ? cols[e0] : 0;
        int sl1 = ok1 ? cols[e1] : 0;
        // ---- issue all 16 row gathers (dep only on cols) ----
        unsigned u[16];
#pragma unroll
        for (int t = 0; t < 8; t++) {
            int srcj = __builtin_amdgcn_readlane(sl0, t * 8);
            u[t] = xp32[(size_t)srcj * 64 + lane];
        }
#pragma unroll
        for (int t = 0; t < 8; t++) {
            int srcj = __builtin_amdgcn_readlane(sl1, t * 8);
            u[8 + t] = xp32[(size_t)srcj * 64 + lane];
        }
        // ---- weight math while gathers are in flight ----
        float v0 = -1e30f, v1 = -1e30f;
        if (ok0) { v0 = asrc[sl0 * 8 + h] + ad_l; v0 = LEAKY(v0); }
        if (ok1) { v1 = asrc[sl1 * 8 + h] + ad_l; v1 = LEAKY(v1); }
        float cm = fmaxf(v0, v1);
        cm = fmaxf(cm, __shfl_xor(cm, 8, 64));
        cm = fmaxf(cm, __shfl_xor(cm, 16, 64));
        cm = fmaxf(cm, __shfl_xor(cm, 32, 64));
        float mw_new = fmaxf(m_w, cm);
        float w0 = __expf(v0 - mw_new);  // 0 for invalid slots
        float w1 = __expf(v1 - mw_new);
        s = s * __expf(m_w - mw_new) + w0 + w1;
        m_w = mw_new;
        // feature-role rescale (head j)
        float cmF = bperm_f(jb, cm);
        float mf_new = fmaxf(m_f, cmF);
        float scF = __expf(m_f - mf_new);
        m_f = mf_new;
        a0 *= scF; a1 *= scF;
        float wl[16];
#pragma unroll
        for (int t = 0; t < 8; t++) wl[t] = bperm_f(jb + t * 32, w0);
#pragma unroll
        for (int t = 0; t < 8; t++) wl[8 + t] = bperm_f(jb + t * 32, w1);
        // ---- consume ----
#pragma unroll
        for (int t = 0; t < 16; t++) {
            a0 = fmaf(wl[t], __uint_as_float(u[t] << 16), a0);
            a1 = fmaf(wl[t], __uint_as_float(u[t] & 0xffff0000u), a1);
        }
    }
    // finalize: total s per head, then normalize
    s += __shfl_xor(s, 8, 64);
    s += __shfl_xor(s, 16, 64);
    s += __shfl_xor(s, 32, 64);
    float rs = 1.f / (s + 1e-16f);
    float rsF = bperm_f(jb, rs);
    float o0 = a0 * rsF + bias[2 * lane];
    float o1 = a1 * rsF + bias[2 * lane + 1];
    if (DO_ELU) {
        o0 = o0 > 0.f ? o0 : __expf(o0) - 1.f;
        o1 = o1 > 0.f ? o1 : __expf(o1) - 1.f;
    }
    unsigned packed = (unsigned)bf_bits(o0) | ((unsigned)bf_bits(o1) << 16);
    ((unsigned*)outb)[(size_t)n * 64 + lane] = packed;  // row = 128 shorts = 64 uints
}

// ---------------- single-pass batched aggregation, H=8 C=8 (layer 2) ----------------
template <bool DO_ELU>
__global__ void agg8c8_k(const unsigned short* __restrict__ xpb,
                         const float* __restrict__ asrc, const float* __restrict__ adst,
                         const int* __restrict__ offs, const int* __restrict__ cols,
                         const float* __restrict__ bias, unsigned short* __restrict__ outb,
                         int N) {
    int gtid = blockIdx.x * blockDim.x + threadIdx.x;
    int n = gtid >> 6;
    if (n >= N) return;
    int lane = threadIdx.x & 63;
    int j = lane >> 3, h = lane & 7;
    int start = offs[n], end = offs[n + 1];
    const unsigned* xp32 = (const unsigned*)xpb;

    int fp = lane & 31;      // feature pair {2fp, 2fp+1}
    int hF = fp >> 2;        // feature-role head
    int half = lane >> 5;
    int sbase = half * 32;

    float ad_l = adst[n * 8 + h];
    float vs = asrc[n * 8 + h] + ad_l;
    vs = LEAKY(vs);

    float m_w = vs;
    float s = (j == 0) ? 1.f : 0.f;
    float m_f = bperm_f(hF * 4, vs);
    float a0 = 0.f, a1 = 0.f;
    if (half == 0) {  // self contribution in half 0 only
        unsigned u = xp32[(size_t)n * 32 + fp];
        a0 = __uint_as_float(u << 16);
        a1 = __uint_as_float(u & 0xffff0000u);
    }

    for (int c0 = start; c0 < end; c0 += 16) {
        int e0 = c0 + j, e1 = c0 + 8 + j;
        bool ok0 = e0 < end, ok1 = e1 < end;
        int sl0 = ok0 ? cols[e0] : 0;
        int sl1 = ok1 ? cols[e1] : 0;
        // ---- issue all 8 row gathers per lane-half (dep only on cols) ----
        int sv[8];
#pragma unroll
        for (int t = 0; t < 4; t++) sv[t] = __builtin_amdgcn_ds_bpermute(sbase + t * 64, sl0);
#pragma unroll
        for (int t = 0; t < 4; t++) sv[4 + t] = __builtin_amdgcn_ds_bpermute(sbase + t * 64, sl1);
        unsigned u[8];
#pragma unroll
        for (int t = 0; t < 8; t++) u[t] = xp32[(size_t)sv[t] * 32 + fp];
        // ---- weight math while gathers are in flight ----
        float v0 = -1e30f, v1 = -1e30f;
        if (ok0) { v0 = asrc[sl0 * 8 + h] + ad_l; v0 = LEAKY(v0); }
        if (ok1) { v1 = asrc[sl1 * 8 + h] + ad_l; v1 = LEAKY(v1); }
        float cm = fmaxf(v0, v1);
        cm = fmaxf(cm, __shfl_xor(cm, 8, 64));
        cm = fmaxf(cm, __shfl_xor(cm, 16, 64));
        cm = fmaxf(cm, __shfl_xor(cm, 32, 64));
        float mw_new = fmaxf(m_w, cm);
        float w0 = __expf(v0 - mw_new);
        float w1 = __expf(v1 - mw_new);
        s = s * __expf(m_w - mw_new) + w0 + w1;
        m_w = mw_new;
        float cmF = bperm_f(hF * 4, cm);
        float mf_new = fmaxf(m_f, cmF);
        float scF = __expf(m_f - mf_new);
        m_f = mf_new;
        a0 *= scF; a1 *= scF;
        float wl[8];
#pragma unroll
        for (int t = 0; t < 4; t++) wl[t] = bperm_f(sbase + hF * 4 + t * 64, w0);
#pragma unroll
        for (int t = 0; t < 4; t++) wl[4 + t] = bperm_f(sbase + hF * 4 + t * 64, w1);
        // ---- consume ----
#pragma unroll
        for (int t = 0; t < 8; t++) {
            a0 = fmaf(wl[t], __uint_as_float(u[t] << 16), a0);
            a1 = fmaf(wl[t], __uint_as_float(u[t] & 0xffff0000u), a1);
        }
    }
    s += __shfl_xor(s, 8, 64);
    s += __shfl_xor(s, 16, 64);
    s += __shfl_xor(s, 32, 64);
    float rs = 1.f / (s + 1e-16f);
    float rsF = bperm_f(hF * 4, rs);
    // combine halves (same m_f in both halves), then normalize
    a0 += __shfl_xor(a0, 32, 64);
    a1 += __shfl_xor(a1, 32, 64);
    if (half == 0) {
        float o0 = a0 * rsF + bias[2 * fp];
        float o1 = a1 * rsF + bias[2 * fp + 1];
        if (DO_ELU) {
            o0 = o0 > 0.f ? o0 : __expf(o0) - 1.f;
            o1 = o1 > 0.f ? o1 : __expf(o1) - 1.f;
        }
        unsigned packed = (unsigned)bf_bits(o0) | ((unsigned)bf_bits(o1) << 16);
        ((unsigned*)outb)[(size_t)n * 32 + fp] = packed;  // row = 64 shorts = 32 uints
    }
}

// ---------------- aggregation H=1 C=10 + fused log_softmax (layer 3) ----------------
__global__ void agg1h_k(const unsigned short* __restrict__ xpb,
                        const float* __restrict__ asrc, const float* __restrict__ adst,
                        const int* __restrict__ offs, const int* __restrict__ cols,
                        const float* __restrict__ bias, float* __restrict__ out, int N) {
    int gtid = blockIdx.x * blockDim.x + threadIdx.x;
    int n = gtid >> 6;
    if (n >= N) return;
    int lane = threadIdx.x & 63;
    int start = offs[n], end = offs[n + 1];
    float ad = adst[n];
    float vs = asrc[n] + ad;  // implicit self-loop
    vs = LEAKY(vs);

    float m, s;
    if (lane == 0) { m = vs; s = 1.f; } else { m = -1e30f; s = 0.f; }
    for (int e = start + lane; e < end; e += 64) {
        float v = asrc[cols[e]] + ad;
        v = LEAKY(v);
        float mo = fmaxf(m, v);
        s = s * __expf(m - mo) + __expf(v - mo);
        m = mo;
    }
#pragma unroll
    for (int off = 1; off <= 32; off <<= 1) {
        float mo = __shfl_xor(m, off, 64);
        float so = __shfl_xor(s, off, 64);
        float mn = fmaxf(m, mo);
        s = s * __expf(m - mn) + so * __expf(mo - mn);
        m = mn;
    }
    float rs = 1.f / (s + 1e-16f);
    float wself = __expf(vs - m) * rs;

    int j = lane / 10, c = lane - j * 10;
    float acc = 0.f;
    if (j == 0) acc = wself * bf_to_f(xpb[(size_t)n * 10 + c]);  // self term
    for (int c0 = start; c0 < end; c0 += 6) {
        int e = c0 + j;
        if (j < 6 && e < end) {
            int src = cols[e];
            float v = asrc[src] + ad;
            v = LEAKY(v);
            float w = __expf(v - m) * rs;
            acc = fmaf(w, bf_to_f(xpb[(size_t)src * 10 + c]), acc);
        }
    }
    float tot = acc;
#pragma unroll
    for (int k = 1; k < 6; k++) tot += __shfl(acc, lane + 10 * k, 64);

    // fused log_softmax over the 10 classes (valid in lanes 0-9)
    float z = tot + bias[lane < 10 ? lane : 0];
    float mx = -1e30f;
#pragma unroll
    for (int k = 0; k < 10; k++) mx = fmaxf(mx, __shfl(z, k, 64));
    float se = 0.f;
#pragma unroll
    for (int k = 0; k < 10; k++) se += __expf(__shfl(z, k, 64) - mx);
    if (lane < 10) out[(size_t)n * 10 + lane] = z - (__logf(se) + mx);
}

// ---------------- launch ----------------

static inline size_t alignup(size_t x) { return (x + 255) & ~(size_t)255; }

extern "C" void kernel_launch(void* const* d_in, const int* in_sizes, int n_in,
                              void* d_out, int out_size, void* d_ws, size_t ws_size,
                              hipStream_t stream) {
    const float* x   = (const float*)d_in[0];
    const int*   ei  = (const int*)d_in[1];
    const float* W1  = (const float*)d_in[2];
    const float* a1s = (const float*)d_in[3];
    const float* a1d = (const float*)d_in[4];
    const float* b1  = (const float*)d_in[5];
    const float* W2  = (const float*)d_in[6];
    const float* a2s = (const float*)d_in[7];
    const float* a2d = (const float*)d_in[8];
    const float* b2  = (const float*)d_in[9];
    const float* W3  = (const float*)d_in[10];
    const float* a3s = (const float*)d_in[11];
    const float* a3d = (const float*)d_in[12];
    const float* b3  = (const float*)d_in[13];
    float* out = (float*)d_out;

    const int N = in_sizes[0] / 256;
    const int E = in_sizes[1] / 2;
    const int* src = ei;
    const int* dst = ei + E;
    const int NB = (N + 255) >> 8;  // 391 for N=100000 (<= NB_MAX)
    const int PB = (E + 4095) / 4096;

    char* p = (char*)d_ws;
    int* offs    = (int*)p; p += alignup(sizeof(int) * (size_t)(N + 1));
    int* bcur    = (int*)p; p += alignup(sizeof(int) * (size_t)(NB_MAX + 1));
    int* cols    = (int*)p; p += alignup(sizeof(int) * (size_t)E);
    unsigned short* xpb   = (unsigned short*)p; p += alignup(2 * (size_t)N * 128);
    unsigned short* hbufb = (unsigned short*)p; p += alignup(2 * (size_t)N * 128);
    float* xp    = (float*)p; p += alignup(sizeof(float) * (size_t)N * 128);
    float* as_   = (float*)p; p += alignup(sizeof(float) * (size_t)N * 8);
    float* ad_   = (float*)p; p += alignup(sizeof(float) * (size_t)N * 8);
    short* Bf1   = (short*)p; p += alignup(sizeof(short) * 8 * 8 * 64 * 16);  // K=256,N=128
    short* Bf2   = (short*)p; p += alignup(sizeof(short) * 4 * 4 * 64 * 16);  // K=128,N=64
    short* Bf3   = (short*)p; p += alignup(sizeof(short) * 2 * 1 * 64 * 16);  // K=64,N=16(pad)
    // staged bucket regions alias xp (xp is dead since R13's fused gemm3);
    // CSR build (csr_gemm1_k blocks < NB) only reads staged while gemm blocks
    // write xpb/as_/ad_ — distinct buffers.
    unsigned* staged = (unsigned*)xp;  // NB * BCAP * 4B = 8 MB << 51.2 MB

    const int TB = 256;

    // CSR pass 1 + W pre-pack (fused, independent work)
    hipMemsetAsync(bcur, 0, sizeof(int) * (size_t)(NB + 1), stream);
    part_prep_k<<<PB + 21, 256, 0, stream>>>(
        src, dst, E, NB, bcur, staged, PB, W1, W2, W3, Bf1, Bf2, Bf3);

    // ---- CSR pass 2 (blocks 0..NB-1) + layer-1 GEMM (rest), fused
    csr_gemm1_k<<<NB + (N + 63) / 64, 256, 0, stream>>>(
        staged, bcur, offs, cols, N, NB, x, Bf1, xpb, a1s, a1d, as_, ad_, N);
    agg16_k<true><<<(N * 64 + TB - 1) / TB, TB, 0, stream>>>(
        xpb, as_, ad_, offs, cols, b1, hbufb, N);

    // ---- layer 2: 128 -> 64 (H=8, C=8), ELU  (A is bf16 agg output)
    mfma_gemm2_k<<<(N + 63) / 64, 256, 0, stream>>>(
        hbufb, Bf2, xpb, a2s, a2d, as_, ad_, N);
    agg8c8_k<true><<<(N * 64 + TB - 1) / TB, TB, 0, stream>>>(
        xpb, as_, ad_, offs, cols, b2, hbufb, N);

    // ---- layer 3: 64 -> 10 (H=1, C=10) MFMA + fused alpha, then agg + log_softmax
    gemm3_k<<<(N + 63) / 64, 256, 0, stream>>>(
        hbufb, Bf3, xpb, a3s, a3d, as_, ad_, N);
    agg1h_k<<<(N * 64 + TB - 1) / TB, TB, 0, stream>>>(
        xpb, as_, ad_, offs, cols, b3, out, N);
}

// Round 8
// 453.363 us; speedup vs baseline: 1.1911x; 1.0079x over previous
//
#include <hip/hip_runtime.h>
#include <hip/hip_bf16.h>
#include <math.h>

// ---------------------------------------------------------------------------
// GAT 3-layer forward on MI355X.
//   R16 (resubmit after container infra failure): agg16/agg8c8 gather
//   batching PINNED with sched_barrier(0) after the gather-issue loop.
//   Evidence: R9/R12 both ran at VGPR=36 -> the compiler re-sank R12's
//   "batched" loads to use sites; the batch never executed. Kernel is
//   mixed-bound (VALU ~55us, L2-fill 264MB ~42us) running as a SUM (86us)
//   due to serial gather latency in the chunk chain. Pinning should
//   overlap them (falsifiable: VGPR must jump to ~55-64).
//   R15: K-split L1 staging (34.8KB LDS, 4 blk/CU); part+prep and csr+gemm1
//   fusions. R14: LDS-C-tile epilogue. R13: gemm3 MFMA fused alpha.
// ---------------------------------------------------------------------------

#define LEAKY(v) ((v) > 0.f ? (v) : 0.2f * (v))

typedef __bf16 bf16_t;
typedef __bf16 bf16x8 __attribute__((ext_vector_type(8)));
typedef __bf16 bf16x4 __attribute__((ext_vector_type(4)));
typedef float f32x4 __attribute__((ext_vector_type(4)));
typedef unsigned short u16x8 __attribute__((ext_vector_type(8)));

static __device__ __forceinline__ unsigned short bf_bits(float f) {
    bf16_t b = (bf16_t)f;
    return __builtin_bit_cast(unsigned short, b);
}
static __device__ __forceinline__ float bf_to_f(unsigned short u) {
    return __uint_as_float(((unsigned int)u) << 16);
}
static __device__ __forceinline__ float bperm_f(int byteaddr, float v) {
    return __uint_as_float((unsigned)__builtin_amdgcn_ds_bpermute(byteaddr, (int)__float_as_uint(v)));
}

// ---------------- CSR build: 2-pass bucket sort ----------------
constexpr int NB_MAX = 400;
constexpr int BCAP = 5120;  // capacity per bucket region; mean load 4096

// ---------------- W pre-pack device helpers ----------------
static __device__ __forceinline__ void prep_w_dev(
        const float* __restrict__ W, short* __restrict__ Bfs,
        int K, int N, int NT, int idx) {
    int lane = idx & 63;
    int t = idx >> 6;
    int ntile = t % NT, kstep = t / NT;
    int quad = lane >> 4, nl = lane & 15;
    int n = ntile * 16 + nl;
    bf16_t* dst = (bf16_t*)Bfs + (size_t)idx * 16;
#pragma unroll
    for (int j = 0; j < 8; j++) {
        int k = kstep * 32 + quad * 8 + j;
        float v = W[k * N + n];
        bf16_t h = (bf16_t)v;
        bf16_t l = (bf16_t)(v - (float)h);
        dst[j] = h;
        dst[8 + j] = l;
    }
}
static __device__ __forceinline__ void prep_w3_dev(
        const float* __restrict__ W, short* __restrict__ Bfs, int Nc, int idx) {
    int lane = idx & 63, ks = idx >> 6;
    int quad = lane >> 4, nl = lane & 15;
    bf16_t* dst = (bf16_t*)Bfs + (size_t)idx * 16;
#pragma unroll
    for (int j = 0; j < 8; j++) {
        int k = ks * 32 + quad * 8 + j;
        float v = (nl < Nc) ? W[k * Nc + nl] : 0.f;
        bf16_t h = (bf16_t)v;
        bf16_t l = (bf16_t)(v - (float)h);
        dst[j] = h;
        dst[8 + j] = l;
    }
}

// ---------------- fused: edge partition + W pre-pack ----------------
__global__ __launch_bounds__(256) void part_prep_k(
        const int* __restrict__ src, const int* __restrict__ dst, int E, int NB,
        int* __restrict__ bcur, unsigned* __restrict__ staged, int PB,
        const float* __restrict__ W1, const float* __restrict__ W2,
        const float* __restrict__ W3, short* __restrict__ Bf1,
        short* __restrict__ Bf2, short* __restrict__ Bf3) {
    __shared__ int hist[NB_MAX];
    __shared__ int bstart[NB_MAX + 1];
    __shared__ int cur[NB_MAX];
    __shared__ int gbase[NB_MAX];
    __shared__ unsigned words[4096];
    __shared__ unsigned short bidl[4096];
    int tid = threadIdx.x;

    if ((int)blockIdx.x >= PB) {  // ---- prep branch ----
        int idx = ((int)blockIdx.x - PB) * 256 + tid;
        if (idx < 4096) prep_w_dev(W1, Bf1, 256, 128, 8, idx);
        else if (idx < 5120) prep_w_dev(W2, Bf2, 128, 64, 4, idx - 4096);
        else if (idx < 5248) prep_w3_dev(W3, Bf3, 10, idx - 5120);
        return;
    }

    int e0 = blockIdx.x * 4096;
    int cnt = E - e0; if (cnt > 4096) cnt = 4096;
    if (cnt <= 0) return;

    for (int b = tid; b < NB; b += 256) hist[b] = 0;
    __syncthreads();
    for (int i = tid; i < cnt; i += 256) atomicAdd(&hist[dst[e0 + i] >> 8], 1);
    __syncthreads();
    // wave-0 parallel exclusive scan over NB entries
    if (tid < 64) {
        int lane = tid;
        int run = 0;
        for (int b0 = 0; b0 < NB; b0 += 64) {
            int bb = b0 + lane;
            int v = (bb < NB) ? hist[bb] : 0;
            int sc = v;
            for (int off = 1; off < 64; off <<= 1) {
                int t2 = __shfl_up(sc, off, 64);
                if (lane >= off) sc += t2;
            }
            if (bb < NB) bstart[bb] = run + sc - v;
            run += __shfl(sc, 63, 64);
        }
        if (lane == 0) bstart[NB] = run;
    }
    __syncthreads();
    for (int b = tid; b < NB; b += 256) {
        cur[b] = bstart[b];
        gbase[b] = hist[b] ? atomicAdd(&bcur[b], hist[b]) : 0;
    }
    __syncthreads();
    // group into LDS by bucket, remember bucket id per slot
    for (int i = tid; i < cnt; i += 256) {
        int s = src[e0 + i], d = dst[e0 + i];
        int b = d >> 8;
        unsigned w = (unsigned)s | ((unsigned)(d & 255) << 17);
        int p = atomicAdd(&cur[b], 1);
        words[p] = w;
        bidl[p] = (unsigned short)b;
    }
    __syncthreads();
    // linear sweep -> coalesced runs into global bucket regions
    for (int i = tid; i < cnt; i += 256) {
        int b = bidl[i];
        staged[(size_t)b * BCAP + gbase[b] + (i - bstart[b])] = words[i];
    }
}

// ---------------- buildcsr body (runs inside fused csr_gemm1_k) ----------------
static __device__ void buildcsr_body(
        char* smem, const unsigned* __restrict__ staged, const int* __restrict__ bcur,
        int* __restrict__ offs, int* __restrict__ cols, int N, int NB, int b) {
    int* h    = (int*)smem;
    int* hs   = h + 256;
    int* curl = hs + 256;
    int* colsl = curl + 256;
    int* base_p = colsl + BCAP;
    int tid = threadIdx.x;
    int n0 = b << 8;
    int ecnt = bcur[b];
    const unsigned* sb = staged + (size_t)b * BCAP;

    h[tid] = 0;
    if (tid < 64) {  // base_g = sum(bcur[0..b))
        int acc2 = 0;
        for (int i = tid; i < b; i += 64) acc2 += bcur[i];
        for (int off = 1; off < 64; off <<= 1) acc2 += __shfl_xor(acc2, off, 64);
        if (tid == 0) *base_p = acc2;
    }
    __syncthreads();
    int base_g = *base_p;
    for (int i = tid; i < ecnt; i += 256) atomicAdd(&h[sb[i] >> 17], 1);
    __syncthreads();
    int val = h[tid];
    hs[tid] = val; __syncthreads();
    for (int off = 1; off < 256; off <<= 1) {
        int t = (tid >= off) ? hs[tid - off] : 0;
        __syncthreads();
        hs[tid] += t;
        __syncthreads();
    }
    int excl = hs[tid] - val;
    curl[tid] = excl;
    if (n0 + tid < N) offs[n0 + tid] = base_g + excl;
    if (b == NB - 1 && tid == 0) offs[N] = base_g + ecnt;
    __syncthreads();
    for (int i = tid; i < ecnt; i += 256) {
        unsigned w = sb[i];
        int p = atomicAdd(&curl[w >> 17], 1);
        colsl[p] = (int)(w & 0x1FFFFu);
    }
    __syncthreads();
    for (int i = tid; i < ecnt; i += 256) cols[base_g + i] = colsl[i];
}

// ---------------- split-bf16 MFMA GEMM body (K-split staging + epilogue v2) ----------------
template <int BM, int WMT, int WNT, int NWM, bool ABF16, int CHEAD, int K, int NPH>
static __device__ __forceinline__ void gemm_body(
        char* smem,
        const void* __restrict__ Av, const short* __restrict__ Bfs,
        unsigned short* __restrict__ Cb,
        const float* __restrict__ a_s, const float* __restrict__ a_d,
        float* __restrict__ out_as, float* __restrict__ out_ad,
        int M, int N, int NT, int bx, int by) {
    constexpr int NWN = 4 / NWM;
    constexpr int BN = 16 * WNT * NWN;
    constexpr int KPH = K / NPH;     // K per staging phase
    constexpr int KPP = KPH + 8;     // +8 bf16 pad: breaks bank aliasing
    constexpr int BNP = BN + 2;      // f32 C-tile pad
    bf16_t* As_hi = (bf16_t*)smem;
    bf16_t* As_lo = As_hi + (ABF16 ? 0 : (size_t)BM * KPP);
    float* Ct = (float*)smem;
    const bf16_t* Bf = (const bf16_t*)Bfs;

    int tid = threadIdx.x;
    int wave = tid >> 6, lane = tid & 63;
    int quad = lane >> 4, l16 = lane & 15;
    int wm = wave % NWM, wn = wave / NWM;
    int row0 = bx * BM;
    int ntile0 = by * (BN / 16) + wn * WNT;

    f32x4 acc[WMT][WNT];
#pragma unroll
    for (int i = 0; i < WMT; i++)
#pragma unroll
        for (int j = 0; j < WNT; j++) acc[i][j] = (f32x4){0.f, 0.f, 0.f, 0.f};

#pragma unroll
    for (int phase = 0; phase < NPH; phase++) {
        if (phase) __syncthreads();  // previous compute's LDS reads done
        // ---- stage this K-phase: all loads issued before conversion ----
        if constexpr (!ABF16) {
            constexpr int CHUNKS = BM * KPH * 4 / (16 * 256);
            const float* A = (const float*)Av;
            f32x4 tmp[CHUNKS];
#pragma unroll
            for (int c = 0; c < CHUNKS; c++) {
                int ci = c * 256 + tid;
                int fi = ci * 4;
                int row = fi / KPH, k = fi % KPH;
                int grow = row0 + row;
                tmp[c] = (f32x4){0.f, 0.f, 0.f, 0.f};
                if (grow < M) tmp[c] = *(const f32x4*)(A + (size_t)grow * K + phase * KPH + k);
            }
#pragma unroll
            for (int c = 0; c < CHUNKS; c++) {
                int ci = c * 256 + tid;
                int fi = ci * 4;
                int row = fi / KPH, k = fi % KPH;
                bf16x4 h, l;
#pragma unroll
                for (int j = 0; j < 4; j++) {
                    bf16_t hh = (bf16_t)tmp[c][j];
                    h[j] = hh;
                    l[j] = (bf16_t)(tmp[c][j] - (float)hh);
                }
                *(bf16x4*)&As_hi[row * KPP + k] = h;
                *(bf16x4*)&As_lo[row * KPP + k] = l;
            }
        } else {
            constexpr int CHUNKS = BM * KPH * 2 / (16 * 256);
            const unsigned short* A = (const unsigned short*)Av;
            u16x8 tmp[CHUNKS];
#pragma unroll
            for (int c = 0; c < CHUNKS; c++) {
                int ci = c * 256 + tid;
                int ei = ci * 8;
                int row = ei / KPH, k = ei % KPH;
                int grow = row0 + row;
                tmp[c] = (u16x8){0, 0, 0, 0, 0, 0, 0, 0};
                if (grow < M) tmp[c] = *(const u16x8*)(A + (size_t)grow * K + phase * KPH + k);
            }
#pragma unroll
            for (int c = 0; c < CHUNKS; c++) {
                int ci = c * 256 + tid;
                int ei = ci * 8;
                int row = ei / KPH, k = ei % KPH;
                *(u16x8*)&As_hi[row * KPP + k] = tmp[c];
            }
        }
        __syncthreads();

        // ---- compute this K-phase (barrier-free) ----
#pragma unroll
        for (int ks = 0; ks < KPH / 32; ks++) {
            int ksg = phase * (KPH / 32) + ks;
            bf16x8 ah[WMT], al[WMT];
#pragma unroll
            for (int i = 0; i < WMT; i++) {
                int rowl = wm * (WMT * 16) + i * 16 + l16;
                ah[i] = *(const bf16x8*)&As_hi[rowl * KPP + ks * 32 + quad * 8];
                if (!ABF16) al[i] = *(const bf16x8*)&As_lo[rowl * KPP + ks * 32 + quad * 8];
            }
            bf16x8 bh[WNT], bl[WNT];
#pragma unroll
            for (int j = 0; j < WNT; j++) {
                size_t base = ((size_t)(ksg * NT + ntile0 + j) * 64 + lane) * 16;
                bh[j] = *(const bf16x8*)&Bf[base];
                bl[j] = *(const bf16x8*)&Bf[base + 8];
            }
#pragma unroll
            for (int i = 0; i < WMT; i++)
#pragma unroll
                for (int j = 0; j < WNT; j++) {
                    acc[i][j] = __builtin_amdgcn_mfma_f32_16x16x32_bf16(ah[i], bh[j], acc[i][j], 0, 0, 0);
                    if (!ABF16)
                        acc[i][j] = __builtin_amdgcn_mfma_f32_16x16x32_bf16(al[i], bh[j], acc[i][j], 0, 0, 0);
                    acc[i][j] = __builtin_amdgcn_mfma_f32_16x16x32_bf16(ah[i], bl[j], acc[i][j], 0, 0, 0);
                }
        }
    }

    // ---- epilogue v2: acc -> LDS f32 C-tile, then alpha + coalesced C ----
    __syncthreads();  // all As reads done before overwrite
#pragma unroll
    for (int i = 0; i < WMT; i++) {
        int rbase = wm * (WMT * 16) + i * 16 + quad * 4;  // block-local row
#pragma unroll
        for (int j = 0; j < WNT; j++) {
            int lcol = (wn * WNT + j) * 16 + l16;          // block-local col
#pragma unroll
            for (int r2 = 0; r2 < 4; r2++)
                Ct[(size_t)(rbase + r2) * BNP + lcol] = acc[i][j][r2];
        }
    }
    __syncthreads();

    // phase 2a: alpha — BM x (BN/CHEAD) outputs, contiguous LDS reads
    constexpr int HB = BN / CHEAD;
    const int colbase = by * BN;
    const int Hh = N / CHEAD;
#pragma unroll
    for (int o = 0; o < (BM * HB + 255) / 256; o++) {
        int idx = o * 256 + tid;
        if (idx < BM * HB) {
            int row = idx & (BM - 1);
            int hd = idx / BM;   // wave-uniform -> scalar a_s/a_d loads
            const float* crow = Ct + (size_t)row * BNP + hd * CHEAD;
            float ss = 0.f, sd = 0.f;
#pragma unroll
            for (int c = 0; c < CHEAD; c++) {
                float v = crow[c];
                ss = fmaf(v, a_s[colbase + hd * CHEAD + c], ss);
                sd = fmaf(v, a_d[colbase + hd * CHEAD + c], sd);
            }
            int grow = row0 + row;
            if (grow < M) {
                out_as[(size_t)grow * Hh + by * HB + hd] = ss;
                out_ad[(size_t)grow * Hh + by * HB + hd] = sd;
            }
        }
    }

    // phase 2b: C store — packed 2xbf16, coalesced 4B/lane
    constexpr int CU2 = BM * BN / 2;  // uint count (multiple of 256 here)
#pragma unroll
    for (int o = 0; o < CU2 / 256; o++) {
        int idx = o * 256 + tid;
        int row = idx / (BN / 2);
        int uc = idx - row * (BN / 2);
        float v0 = Ct[(size_t)row * BNP + uc * 2];
        float v1 = Ct[(size_t)row * BNP + uc * 2 + 1];
        unsigned pk = (unsigned)bf_bits(v0) | ((unsigned)bf_bits(v1) << 16);
        int grow = row0 + row;
        if (grow < M)
            ((unsigned*)Cb)[((size_t)grow * N + colbase) / 2 + uc] = pk;
    }
}

// ---------------- fused: buildcsr + layer-1 GEMM ----------------
constexpr int SMEM1 = 64 * (128 + 8) * 2 * 2;  // 34816 >= max(ASZ, CSZ, CSR)
__global__ __launch_bounds__(256, 3) void csr_gemm1_k(
        const unsigned* __restrict__ staged, const int* __restrict__ bcur,
        int* __restrict__ offs, int* __restrict__ cols, int Nn, int NB,
        const float* __restrict__ x, const short* __restrict__ Bf1,
        unsigned short* __restrict__ xpb,
        const float* __restrict__ a1s, const float* __restrict__ a1d,
        float* __restrict__ out_as, float* __restrict__ out_ad, int M) {
    __shared__ __align__(16) char smem[SMEM1];
    if ((int)blockIdx.x < NB) {
        buildcsr_body(smem, staged, bcur, offs, cols, Nn, NB, blockIdx.x);
    } else {
        gemm_body<64, 4, 2, 1, false, 16, 256, 2>(
            smem, x, Bf1, xpb, a1s, a1d, out_as, out_ad, M, 128, 8,
            (int)blockIdx.x - NB, 0);
    }
}

// ---------------- layer-2 GEMM (bf16 A, K=128, single phase) ----------------
constexpr int SMEM2 = 64 * (128 + 8) * 2;  // 17408 >= CSZ(64*66*4)
__global__ __launch_bounds__(256, 2) void mfma_gemm2_k(
        const unsigned short* __restrict__ Ab, const short* __restrict__ Bf2,
        unsigned short* __restrict__ Cb,
        const float* __restrict__ a_s, const float* __restrict__ a_d,
        float* __restrict__ out_as, float* __restrict__ out_ad, int M) {
    __shared__ __align__(16) char smem[SMEM2];
    gemm_body<64, 4, 1, 1, true, 8, 128, 1>(
        smem, Ab, Bf2, Cb, a_s, a_d, out_as, out_ad, M, 64, 4, blockIdx.x, 0);
}

// ---------------- layer-3 MFMA GEMM + fused alpha (K=64, N=10 pad 16) ----------------
__global__ __launch_bounds__(256) void gemm3_k(
        const unsigned short* __restrict__ Ab, const short* __restrict__ Bfs,
        unsigned short* __restrict__ Cb,
        const float* __restrict__ a_s, const float* __restrict__ a_d,
        float* __restrict__ out_as, float* __restrict__ out_ad, int M) {
    const bf16_t* Bf = (const bf16_t*)Bfs;
    int tid = threadIdx.x;
    int wave = tid >> 6, lane = tid & 63;
    int quad = lane >> 4, l16 = lane & 15;
    int grow0 = blockIdx.x * 64 + wave * 16;

    bf16x8 bh[2], bl[2];
#pragma unroll
    for (int ks = 0; ks < 2; ks++) {
        size_t base = (size_t)(ks * 64 + lane) * 16;
        bh[ks] = *(const bf16x8*)&Bf[base];
        bl[ks] = *(const bf16x8*)&Bf[base + 8];
    }

    int arow = grow0 + l16; if (arow >= M) arow = M - 1;  // clamp; outputs guarded
    f32x4 acc = (f32x4){0.f, 0.f, 0.f, 0.f};
#pragma unroll
    for (int ks = 0; ks < 2; ks++) {
        bf16x8 a = *(const bf16x8*)(Ab + (size_t)arow * 64 + ks * 32 + quad * 8);
        acc = __builtin_amdgcn_mfma_f32_16x16x32_bf16(a, bh[ks], acc, 0, 0, 0);
        acc = __builtin_amdgcn_mfma_f32_16x16x32_bf16(a, bl[ks], acc, 0, 0, 0);
    }

    bool colv = l16 < 10;
    float cs = colv ? a_s[l16] : 0.f;
    float cd = colv ? a_d[l16] : 0.f;
    float ps[4], pd[4];
#pragma unroll
    for (int r = 0; r < 4; r++) { ps[r] = acc[r] * cs; pd[r] = acc[r] * cd; }
#pragma unroll
    for (int off = 1; off < 16; off <<= 1) {
#pragma unroll
        for (int r = 0; r < 4; r++) {
            ps[r] += __shfl_xor(ps[r], off, 64);
            pd[r] += __shfl_xor(pd[r], off, 64);
        }
    }
#pragma unroll
    for (int r = 0; r < 4; r++) {
        int grow = grow0 + quad * 4 + r;
        if (grow < M) {
            if (colv) Cb[(size_t)grow * 10 + l16] = bf_bits(acc[r]);
            if (l16 == 0) { out_as[grow] = ps[r]; out_ad[grow] = pd[r]; }
        }
    }
}

// ---------------- single-pass batched aggregation, H=8 C=16 (layer 1) ----------------
// R16: sched_barrier(0) pins the 16-gather batch ahead of the weight math.
template <bool DO_ELU>
__global__ void agg16_k(const unsigned short* __restrict__ xpb,
                        const float* __restrict__ asrc, const float* __restrict__ adst,
                        const int* __restrict__ offs, const int* __restrict__ cols,
                        const float* __restrict__ bias, unsigned short* __restrict__ outb,
                        int N) {
    int gtid = blockIdx.x * blockDim.x + threadIdx.x;
    int n = gtid >> 6;
    if (n >= N) return;
    int lane = threadIdx.x & 63;
    int j = lane >> 3, h = lane & 7;
    const int jb = j << 2;  // bpermute byte addr of (j=0, h=j) lane
    int start = offs[n], end = offs[n + 1];
    const unsigned* xp32 = (const unsigned*)xpb;

    // independent loads first
    unsigned uself = xp32[(size_t)n * 64 + lane];
    float ad_l = adst[n * 8 + h];
    float vs = asrc[n * 8 + h] + ad_l;
    vs = LEAKY(vs);

    // weight-role state (head h): seeded with implicit self-loop
    float m_w = vs;
    float s = (j == 0) ? 1.f : 0.f;
    // feature-role state (head j): acc = self row (weight exp(vs-vs)=1)
    float m_f = bperm_f(jb, vs);
    float a0 = __uint_as_float(uself << 16);
    float a1 = __uint_as_float(uself & 0xffff0000u);

    for (int c0 = start; c0 < end; c0 += 16) {
        int e0 = c0 + j, e1 = c0 + 8 + j;
        bool ok0 = e0 < end, ok1 = e1 < end;
        int sl0 = ok0 ? cols[e0] : 0;
        int sl1 = ok1 ? cols[e1] : 0;
        // ---- issue all 16 row gathers (dep only on cols) ----
        unsigned u[16];
#pragma unroll
        for (int t = 0; t < 8; t++) {
            int srcj = __builtin_amdgcn_readlane(sl0, t * 8);
            u[t] = xp32[(size_t)srcj * 64 + lane];
        }
#pragma unroll
        for (int t = 0; t < 8; t++) {
            int srcj = __builtin_amdgcn_readlane(sl1, t * 8);
            u[8 + t] = xp32[(size_t)srcj * 64 + lane];
        }
        // R16: pin — nothing moves across; all 16 loads issue here, weight
        // math below overlaps their flight; waitcnt lands at the fmas.
        __builtin_amdgcn_sched_barrier(0);
        // ---- weight math while gathers are in flight ----
        float v0 = -1e30f, v1 = -1e30f;
        if (ok0) { v0 = asrc[sl0 * 8 + h] + ad_l; v0 = LEAKY(v0); }
        if (ok1) { v1 = asrc[sl1 * 8 + h] + ad_l; v1 = LEAKY(v1); }
        float cm = fmaxf(v0, v1);
        cm = fmaxf(cm, __shfl_xor(cm, 8, 64));
        cm = fmaxf(cm, __shfl_xor(cm, 16, 64));
        cm = fmaxf(cm, __shfl_xor(cm, 32, 64));
        float mw_new = fmaxf(m_w, cm);
        float w0 = __expf(v0 - mw_new);  // 0 for invalid slots
        float w1 = __expf(v1 - mw_new);
        s = s * __expf(m_w - mw_new) + w0 + w1;
        m_w = mw_new;
        // feature-role rescale (head j)
        float cmF = bperm_f(jb, cm);
        float mf_new = fmaxf(m_f, cmF);
        float scF = __expf(m_f - mf_new);
        m_f = mf_new;
        a0 *= scF; a1 *= scF;
        float wl[16];
#pragma unroll
        for (int t = 0; t < 8; t++) wl[t] = bperm_f(jb + t * 32, w0);
#pragma unroll
        for (int t = 0; t < 8; t++) wl[8 + t] = bperm_f(jb + t * 32, w1);
        // ---- consume ----
#pragma unroll
        for (int t = 0; t < 16; t++) {
            a0 = fmaf(wl[t], __uint_as_float(u[t] << 16), a0);
            a1 = fmaf(wl[t], __uint_as_float(u[t] & 0xffff0000u), a1);
        }
    }
    // finalize: total s per head, then normalize
    s += __shfl_xor(s, 8, 64);
    s += __shfl_xor(s, 16, 64);
    s += __shfl_xor(s, 32, 64);
    float rs = 1.f / (s + 1e-16f);
    float rsF = bperm_f(jb, rs);
    float o0 = a0 * rsF + bias[2 * lane];
    float o1 = a1 * rsF + bias[2 * lane + 1];
    if (DO_ELU) {
        o0 = o0 > 0.f ? o0 : __expf(o0) - 1.f;
        o1 = o1 > 0.f ? o1 : __expf(o1) - 1.f;
    }
    unsigned packed = (unsigned)bf_bits(o0) | ((unsigned)bf_bits(o1) << 16);
    ((unsigned*)outb)[(size_t)n * 64 + lane] = packed;  // row = 128 shorts = 64 uints
}

// ---------------- single-pass batched aggregation, H=8 C=8 (layer 2) ----------------
template <bool DO_ELU>
__global__ void agg8c8_k(const unsigned short* __restrict__ xpb,
                         const float* __restrict__ asrc, const float* __restrict__ adst,
                         const int* __restrict__ offs, const int* __restrict__ cols,
                         const float* __restrict__ bias, unsigned short* __restrict__ outb,
                         int N) {
    int gtid = blockIdx.x * blockDim.x + threadIdx.x;
    int n = gtid >> 6;
    if (n >= N) return;
    int lane = threadIdx.x & 63;
    int j = lane >> 3, h = lane & 7;
    int start = offs[n], end = offs[n + 1];
    const unsigned* xp32 = (const unsigned*)xpb;

    int fp = lane & 31;      // feature pair {2fp, 2fp+1}
    int hF = fp >> 2;        // feature-role head
    int half = lane >> 5;
    int sbase = half * 32;

    float ad_l = adst[n * 8 + h];
    float vs = asrc[n * 8 + h] + ad_l;
    vs = LEAKY(vs);

    float m_w = vs;
    float s = (j == 0) ? 1.f : 0.f;
    float m_f = bperm_f(hF * 4, vs);
    float a0 = 0.f, a1 = 0.f;
    if (half == 0) {  // self contribution in half 0 only
        unsigned u = xp32[(size_t)n * 32 + fp];
        a0 = __uint_as_float(u << 16);
        a1 = __uint_as_float(u & 0xffff0000u);
    }

    for (int c0 = start; c0 < end; c0 += 16) {
        int e0 = c0 + j, e1 = c0 + 8 + j;
        bool ok0 = e0 < end, ok1 = e1 < end;
        int sl0 = ok0 ? cols[e0] : 0;
        int sl1 = ok1 ? cols[e1] : 0;
        // ---- issue all 8 row gathers per lane-half (dep only on cols) ----
        int sv[8];
#pragma unroll
        for (int t = 0; t < 4; t++) sv[t] = __builtin_amdgcn_ds_bpermute(sbase + t * 64, sl0);
#pragma unroll
        for (int t = 0; t < 4; t++) sv[4 + t] = __builtin_amdgcn_ds_bpermute(sbase + t * 64, sl1);
        unsigned u[8];
#pragma unroll
        for (int t = 0; t < 8; t++) u[t] = xp32[(size_t)sv[t] * 32 + fp];
        // R16: pin — all 8 gathers issue before weight math.
        __builtin_amdgcn_sched_barrier(0);
        // ---- weight math while gathers are in flight ----
        float v0 = -1e30f, v1 = -1e30f;
        if (ok0) { v0 = asrc[sl0 * 8 + h] + ad_l; v0 = LEAKY(v0); }
        if (ok1) { v1 = asrc[sl1 * 8 + h] + ad_l; v1 = LEAKY(v1); }
        float cm = fmaxf(v0, v1);
        cm = fmaxf(cm, __shfl_xor(cm, 8, 64));
        cm = fmaxf(cm, __shfl_xor(cm, 16, 64));
        cm = fmaxf(cm, __shfl_xor(cm, 32, 64));
        float mw_new = fmaxf(m_w, cm);
        float w0 = __expf(v0 - mw_new);
        float w1 = __expf(v1 - mw_new);
        s = s * __expf(m_w - mw_new) + w0 + w1;
        m_w = mw_new;
        float cmF = bperm_f(hF * 4, cm);
        float mf_new = fmaxf(m_f, cmF);
        float scF = __expf(m_f - mf_new);
        m_f = mf_new;
        a0 *= scF; a1 *= scF;
        float wl[8];
#pragma unroll
        for (int t = 0; t < 4; t++) wl[t] = bperm_f(sbase + hF * 4 + t * 64, w0);
#pragma unroll
        for (int t = 0; t < 4; t++) wl[4 + t] = bperm_f(sbase + hF * 4 + t * 64, w1);
        // ---- consume ----
#pragma unroll
        for (int t = 0; t < 8; t++) {
            a0 = fmaf(wl[t], __uint_as_float(u[t] << 16), a0);
            a1 = fmaf(wl[t], __uint_as_float(u[t] & 0xffff0000u), a1);
        }
    }
    s += __shfl_xor(s, 8, 64);
    s += __shfl_xor(s, 16, 64);
    s += __shfl_xor(s, 32, 64);
    float rs = 1.f / (s + 1e-16f);
    float rsF = bperm_f(hF * 4, rs);
    // combine halves (same m_f in both halves), then normalize
    a0 += __shfl_xor(a0, 32, 64);
    a1 += __shfl_xor(a1, 32, 64);
    if (half == 0) {
        float o0 = a0 * rsF + bias[2 * fp];
        float o1 = a1 * rsF + bias[2 * fp + 1];
        if (DO_ELU) {
            o0 = o0 > 0.f ? o0 : __expf(o0) - 1.f;
            o1 = o1 > 0.f ? o1 : __expf(o1) - 1.f;
        }
        unsigned packed = (unsigned)bf_bits(o0) | ((unsigned)bf_bits(o1) << 16);
        ((unsigned*)outb)[(size_t)n * 32 + fp] = packed;  // row = 64 shorts = 32 uints
    }
}

// ---------------- aggregation H=1 C=10 + fused log_softmax (layer 3) ----------------
__global__ void agg1h_k(const unsigned short* __restrict__ xpb,
                        const float* __restrict__ asrc, const float* __restrict__ adst,
                        const int* __restrict__ offs, const int* __restrict__ cols,
                        const float* __restrict__ bias, float* __restrict__ out, int N) {
    int gtid = blockIdx.x * blockDim.x + threadIdx.x;
    int n = gtid >> 6;
    if (n >= N) return;
    int lane = threadIdx.x & 63;
    int start = offs[n], end = offs[n + 1];
    float ad = adst[n];
    float vs = asrc[n] + ad;  // implicit self-loop
    vs = LEAKY(vs);

    float m, s;
    if (lane == 0) { m = vs; s = 1.f; } else { m = -1e30f; s = 0.f; }
    for (int e = start + lane; e < end; e += 64) {
        float v = asrc[cols[e]] + ad;
        v = LEAKY(v);
        float mo = fmaxf(m, v);
        s = s * __expf(m - mo) + __expf(v - mo);
        m = mo;
    }
#pragma unroll
    for (int off = 1; off <= 32; off <<= 1) {
        float mo = __shfl_xor(m, off, 64);
        float so = __shfl_xor(s, off, 64);
        float mn = fmaxf(m, mo);
        s = s * __expf(m - mn) + so * __expf(mo - mn);
        m = mn;
    }
    float rs = 1.f / (s + 1e-16f);
    float wself = __expf(vs - m) * rs;

    int j = lane / 10, c = lane - j * 10;
    float acc = 0.f;
    if (j == 0) acc = wself * bf_to_f(xpb[(size_t)n * 10 + c]);  // self term
    for (int c0 = start; c0 < end; c0 += 6) {
        int e = c0 + j;
        if (j < 6 && e < end) {
            int src = cols[e];
            float v = asrc[src] + ad;
            v = LEAKY(v);
            float w = __expf(v - m) * rs;
            acc = fmaf(w, bf_to_f(xpb[(size_t)src * 10 + c]), acc);
        }
    }
    float tot = acc;
#pragma unroll
    for (int k = 1; k < 6; k++) tot += __shfl(acc, lane + 10 * k, 64);

    // fused log_softmax over the 10 classes (valid in lanes 0-9)
    float z = tot + bias[lane < 10 ? lane : 0];
    float mx = -1e30f;
#pragma unroll
    for (int k = 0; k < 10; k++) mx = fmaxf(mx, __shfl(z, k, 64));
    float se = 0.f;
#pragma unroll
    for (int k = 0; k < 10; k++) se += __expf(__shfl(z, k, 64) - mx);
    if (lane < 10) out[(size_t)n * 10 + lane] = z - (__logf(se) + mx);
}

// ---------------- launch ----------------

static inline size_t alignup(size_t x) { return (x + 255) & ~(size_t)255; }

extern "C" void kernel_launch(void* const* d_in, const int* in_sizes, int n_in,
                              void* d_out, int out_size, void* d_ws, size_t ws_size,
                              hipStream_t stream) {
    const float* x   = (const float*)d_in[0];
    const int*   ei  = (const int*)d_in[1];
    const float* W1  = (const float*)d_in[2];
    const float* a1s = (const float*)d_in[3];
    const float* a1d = (const float*)d_in[4];
    const float* b1  = (const float*)d_in[5];
    const float* W2  = (const float*)d_in[6];
    const float* a2s = (const float*)d_in[7];
    const float* a2d = (const float*)d_in[8];
    const float* b2  = (const float*)d_in[9];
    const float* W3  = (const float*)d_in[10];
    const float* a3s = (const float*)d_in[11];
    const float* a3d = (const float*)d_in[12];
    const float* b3  = (const float*)d_in[13];
    float* out = (float*)d_out;

    const int N = in_sizes[0] / 256;
    const int E = in_sizes[1] / 2;
    const int* src = ei;
    const int* dst = ei + E;
    const int NB = (N + 255) >> 8;  // 391 for N=100000 (<= NB_MAX)
    const int PB = (E + 4095) / 4096;

    char* p = (char*)d_ws;
    int* offs    = (int*)p; p += alignup(sizeof(int) * (size_t)(N + 1));
    int* bcur    = (int*)p; p += alignup(sizeof(int) * (size_t)(NB_MAX + 1));
    int* cols    = (int*)p; p += alignup(sizeof(int) * (size_t)E);
    unsigned short* xpb   = (unsigned short*)p; p += alignup(2 * (size_t)N * 128);
    unsigned short* hbufb = (unsigned short*)p; p += alignup(2 * (size_t)N * 128);
    float* xp    = (float*)p; p += alignup(sizeof(float) * (size_t)N * 128);
    float* as_   = (float*)p; p += alignup(sizeof(float) * (size_t)N * 8);
    float* ad_   = (float*)p; p += alignup(sizeof(float) * (size_t)N * 8);
    short* Bf1   = (short*)p; p += alignup(sizeof(short) * 8 * 8 * 64 * 16);  // K=256,N=128
    short* Bf2   = (short*)p; p += alignup(sizeof(short) * 4 * 4 * 64 * 16);  // K=128,N=64
    short* Bf3   = (short*)p; p += alignup(sizeof(short) * 2 * 1 * 64 * 16);  // K=64,N=16(pad)
    // staged bucket regions alias xp (xp is dead since R13's fused gemm3);
    // CSR build (csr_gemm1_k blocks < NB) only reads staged while gemm blocks
    // write xpb/as_/ad_ — distinct buffers.
    unsigned* staged = (unsigned*)xp;  // NB * BCAP * 4B = 8 MB << 51.2 MB

    const int TB = 256;

    // CSR pass 1 + W pre-pack (fused, independent work)
    hipMemsetAsync(bcur, 0, sizeof(int) * (size_t)(NB + 1), stream);
    part_prep_k<<<PB + 21, 256, 0, stream>>>(
        src, dst, E, NB, bcur, staged, PB, W1, W2, W3, Bf1, Bf2, Bf3);

    // ---- CSR pass 2 (blocks 0..NB-1) + layer-1 GEMM (rest), fused
    csr_gemm1_k<<<NB + (N + 63) / 64, 256, 0, stream>>>(
        staged, bcur, offs, cols, N, NB, x, Bf1, xpb, a1s, a1d, as_, ad_, N);
    agg16_k<true><<<(N * 64 + TB - 1) / TB, TB, 0, stream>>>(
        xpb, as_, ad_, offs, cols, b1, hbufb, N);

    // ---- layer 2: 128 -> 64 (H=8, C=8), ELU  (A is bf16 agg output)
    mfma_gemm2_k<<<(N + 63) / 64, 256, 0, stream>>>(
        hbufb, Bf2, xpb, a2s, a2d, as_, ad_, N);
    agg8c8_k<true><<<(N * 64 + TB - 1) / TB, TB, 0, stream>>>(
        xpb, as_, ad_, offs, cols, b2, hbufb, N);

    // ---- layer 3: 64 -> 10 (H=1, C=10) MFMA + fused alpha, then agg + log_softmax
    gemm3_k<<<(N + 63) / 64, 256, 0, stream>>>(
        hbufb, Bf3, xpb, a3s, a3d, as_, ad_, N);
    agg1h_k<<<(N * 64 + TB - 1) / TB, TB, 0, stream>>>(
        xpb, as_, ad_, offs, cols, b3, out, N);
}